// Round 2
// baseline (1208.258 us; speedup 1.0000x reference)
//
#include <hip/hip_runtime.h>

// Problem constants
#define B_    8
#define N_    2048      // coarse points
#define M_    8192      // fine points
#define C_    512       // x channels
#define CSK   256       // x_skip channels
#define CIN   768       // C_ + CSK
#define H1C   512       // hidden 1 channels
#define H2C   256       // hidden 2 (output) channels
#define NCOL  65536     // B_*M_  (columns of H1/H2)
#define GCOL  16384     // B_*N_  (columns of G)

// ---------------------------------------------------------------------------
// Kernel 1: 3-NN + interpolation weights.
// grid (M_/256, B_), block 256. Stages pos[b] (2048x3 f32 = 24 KB) in LDS.
// ---------------------------------------------------------------------------
__global__ __launch_bounds__(256) void knn_kernel(const float* __restrict__ pos,
                                                  const float* __restrict__ pos_skip,
                                                  int* __restrict__ idx_out,
                                                  float* __restrict__ w_out) {
    __shared__ float rp[N_ * 3];
    const int b = blockIdx.y;
    const int tid = threadIdx.x;
    for (int t = tid; t < N_ * 3; t += 256) rp[t] = pos[(size_t)b * N_ * 3 + t];
    __syncthreads();

    const int m = blockIdx.x * 256 + tid;
    const size_t qoff = ((size_t)b * M_ + m) * 3;
    const float qx = pos_skip[qoff], qy = pos_skip[qoff + 1], qz = pos_skip[qoff + 2];

    float d0 = 1e30f, d1 = 1e30f, d2 = 1e30f;
    int i0 = 0, i1 = 0, i2 = 0;
    for (int n = 0; n < N_; ++n) {
        const float dx = qx - rp[n * 3 + 0];
        const float dy = qy - rp[n * 3 + 1];
        const float dz = qz - rp[n * 3 + 2];
        const float d = dx * dx + dy * dy + dz * dz;
        if (d < d2) {
            if (d < d1) {
                d2 = d1; i2 = i1;
                if (d < d0) { d1 = d0; i1 = i0; d0 = d; i0 = n; }
                else        { d1 = d;  i1 = n; }
            } else { d2 = d; i2 = n; }
        }
    }
    const float r0 = 1.0f / (sqrtf(d0) + 1e-8f);
    const float r1 = 1.0f / (sqrtf(d1) + 1e-8f);
    const float r2 = 1.0f / (sqrtf(d2) + 1e-8f);
    const float inv = 1.0f / (r0 + r1 + r2);
    const size_t o = ((size_t)b * M_ + m) * 3;
    idx_out[o] = i0; idx_out[o + 1] = i1; idx_out[o + 2] = i2;
    w_out[o] = r0 * inv; w_out[o + 1] = r1 * inv; w_out[o + 2] = r2 * inv;
}

// ---------------------------------------------------------------------------
// Kernel 2: G[o, b*N_+n] = sum_c W1[o,c] * x[b,c,n]   (first 512 cols of W1)
// 64x64 tile, BK=16, 256 threads, 4x4 per thread.
// grid (GCOL/64, H1C/64)
// ---------------------------------------------------------------------------
__global__ __launch_bounds__(256) void gemm_G(const float* __restrict__ W1,
                                              const float* __restrict__ x,
                                              float* __restrict__ G) {
    __shared__ __align__(16) float As[16][68];
    __shared__ __align__(16) float Bs[16][68];
    const int tid = threadIdx.x;
    const int tx = tid & 15, ty = tid >> 4;
    const int row0 = blockIdx.y * 64;
    const int col0 = blockIdx.x * 64;
    const int b = col0 >> 11;            // /N_
    const int n0 = col0 & (N_ - 1);
    const int ar = tid >> 2, ac = (tid & 3) << 2;
    const int bkr = tid >> 4, bc = (tid & 15) << 2;
    float acc[4][4] = {{0.f}};

    for (int k0 = 0; k0 < C_; k0 += 16) {
        const float4 av = *(const float4*)(W1 + (size_t)(row0 + ar) * CIN + k0 + ac);
        As[ac + 0][ar] = av.x; As[ac + 1][ar] = av.y;
        As[ac + 2][ar] = av.z; As[ac + 3][ar] = av.w;
        const float4 bv = *(const float4*)(x + (size_t)b * C_ * N_ + (size_t)(k0 + bkr) * N_ + n0 + bc);
        *(float4*)&Bs[bkr][bc] = bv;
        __syncthreads();
#pragma unroll
        for (int k = 0; k < 16; ++k) {
            float a[4], bb[4];
            *(float4*)a  = *(const float4*)&As[k][ty << 2];
            *(float4*)bb = *(const float4*)&Bs[k][tx << 2];
#pragma unroll
            for (int i = 0; i < 4; ++i)
#pragma unroll
                for (int j = 0; j < 4; ++j)
                    acc[i][j] = fmaf(a[i], bb[j], acc[i][j]);
        }
        __syncthreads();
    }
#pragma unroll
    for (int i = 0; i < 4; ++i) {
        const int o = row0 + (ty << 2) + i;
        *(float4*)(G + (size_t)o * GCOL + col0 + (tx << 2)) =
            make_float4(acc[i][0], acc[i][1], acc[i][2], acc[i][3]);
    }
}

// ---------------------------------------------------------------------------
// Kernel 3: H1[o, b*M_+m] = sum_c W1[o,512+c]*x_skip[b,c,m]
//                         + sum_k w[b,m,k] * G[o, b*N_ + idx[b,m,k]]
// grid (NCOL/64, H1C/64)
// ---------------------------------------------------------------------------
__global__ __launch_bounds__(256) void gemm_H1(const float* __restrict__ W1,
                                               const float* __restrict__ xs,
                                               const float* __restrict__ G,
                                               const int* __restrict__ idx,
                                               const float* __restrict__ w,
                                               float* __restrict__ H1) {
    __shared__ __align__(16) float As[16][68];
    __shared__ __align__(16) float Bs[16][68];
    __shared__ int   sIdx[64][3];
    __shared__ float sW[64][3];
    const int tid = threadIdx.x;
    const int tx = tid & 15, ty = tid >> 4;
    const int row0 = blockIdx.y * 64;
    const int col0 = blockIdx.x * 64;
    const int b = col0 >> 13;            // /M_
    const int m0 = col0 & (M_ - 1);
    const int ar = tid >> 2, ac = (tid & 3) << 2;
    const int bkr = tid >> 4, bc = (tid & 15) << 2;

    if (tid < 192) {
        const int mm = tid / 3, kk = tid - mm * 3;
        const size_t gi = ((size_t)b * M_ + m0 + mm) * 3 + kk;
        sIdx[mm][kk] = idx[gi];
        sW[mm][kk]   = w[gi];
    }
    float acc[4][4] = {{0.f}};

    for (int k0 = 0; k0 < CSK; k0 += 16) {
        const float4 av = *(const float4*)(W1 + (size_t)(row0 + ar) * CIN + C_ + k0 + ac);
        As[ac + 0][ar] = av.x; As[ac + 1][ar] = av.y;
        As[ac + 2][ar] = av.z; As[ac + 3][ar] = av.w;
        const float4 bv = *(const float4*)(xs + (size_t)b * CSK * M_ + (size_t)(k0 + bkr) * M_ + m0 + bc);
        *(float4*)&Bs[bkr][bc] = bv;
        __syncthreads();
#pragma unroll
        for (int k = 0; k < 16; ++k) {
            float a[4], bb[4];
            *(float4*)a  = *(const float4*)&As[k][ty << 2];
            *(float4*)bb = *(const float4*)&Bs[k][tx << 2];
#pragma unroll
            for (int i = 0; i < 4; ++i)
#pragma unroll
                for (int j = 0; j < 4; ++j)
                    acc[i][j] = fmaf(a[i], bb[j], acc[i][j]);
        }
        __syncthreads();
    }

    // epilogue: add 3-NN interpolation of G, then store
#pragma unroll
    for (int i = 0; i < 4; ++i) {
        const int o = row0 + (ty << 2) + i;
        const float* Grow = G + (size_t)o * GCOL + b * N_;
#pragma unroll
        for (int j = 0; j < 4; ++j) {
            const int cc = (tx << 2) + j;
            float v = acc[i][j];
            v = fmaf(sW[cc][0], Grow[sIdx[cc][0]], v);
            v = fmaf(sW[cc][1], Grow[sIdx[cc][1]], v);
            v = fmaf(sW[cc][2], Grow[sIdx[cc][2]], v);
            acc[i][j] = v;
        }
        *(float4*)(H1 + (size_t)o * NCOL + col0 + (tx << 2)) =
            make_float4(acc[i][0], acc[i][1], acc[i][2], acc[i][3]);
    }
}

// ---------------------------------------------------------------------------
// Kernel 4: BN1 stats -> per-channel scale/shift. One block per channel.
// H1 row c is contiguous (NCOL floats).
// ---------------------------------------------------------------------------
__global__ __launch_bounds__(256) void bn_stats1(const float* __restrict__ H1,
                                                 const float* __restrict__ gamma,
                                                 const float* __restrict__ beta,
                                                 float* __restrict__ scale,
                                                 float* __restrict__ shift) {
    const int c = blockIdx.x;
    const float* row = H1 + (size_t)c * NCOL;
    float s = 0.f, q = 0.f;
    for (int t = threadIdx.x; t < NCOL; t += 256) {
        const float v = row[t];
        s += v; q += v * v;
    }
    __shared__ float rs[256], rq[256];
    rs[threadIdx.x] = s; rq[threadIdx.x] = q;
    __syncthreads();
    for (int st = 128; st > 0; st >>= 1) {
        if (threadIdx.x < st) {
            rs[threadIdx.x] += rs[threadIdx.x + st];
            rq[threadIdx.x] += rq[threadIdx.x + st];
        }
        __syncthreads();
    }
    if (threadIdx.x == 0) {
        const float mean = rs[0] * (1.0f / NCOL);
        const float var  = fmaxf(rq[0] * (1.0f / NCOL) - mean * mean, 0.f);
        const float is   = rsqrtf(var + 1e-5f);
        const float sc   = gamma[c] * is;
        scale[c] = sc;
        shift[c] = beta[c] - mean * sc;
    }
}

// ---------------------------------------------------------------------------
// Kernel 5: H2raw[b,p,m] = sum_o W2[p,o] * leaky(H1[o, b*M_+m]*scale1[o]+shift1[o])
// writes raw (pre-BN2) values directly into d_out in [B,H2C,M] layout.
// grid (NCOL/64, H2C/64)
// ---------------------------------------------------------------------------
__global__ __launch_bounds__(256) void gemm_H2(const float* __restrict__ W2,
                                               const float* __restrict__ H1,
                                               const float* __restrict__ sc1,
                                               const float* __restrict__ sh1,
                                               float* __restrict__ out) {
    __shared__ __align__(16) float As[16][68];
    __shared__ __align__(16) float Bs[16][68];
    const int tid = threadIdx.x;
    const int tx = tid & 15, ty = tid >> 4;
    const int row0 = blockIdx.y * 64;
    const int col0 = blockIdx.x * 64;
    const int b = col0 >> 13;
    const int m0 = col0 & (M_ - 1);
    const int ar = tid >> 2, ac = (tid & 3) << 2;
    const int bkr = tid >> 4, bc = (tid & 15) << 2;
    float acc[4][4] = {{0.f}};

    for (int k0 = 0; k0 < C_; k0 += 16) {
        const float4 av = *(const float4*)(W2 + (size_t)(row0 + ar) * C_ + k0 + ac);
        As[ac + 0][ar] = av.x; As[ac + 1][ar] = av.y;
        As[ac + 2][ar] = av.z; As[ac + 3][ar] = av.w;
        const int kr = k0 + bkr;
        float4 bv = *(const float4*)(H1 + (size_t)kr * NCOL + col0 + bc);
        const float s = sc1[kr], h = sh1[kr];
        bv.x = fmaf(bv.x, s, h); bv.x = bv.x >= 0.f ? bv.x : 0.2f * bv.x;
        bv.y = fmaf(bv.y, s, h); bv.y = bv.y >= 0.f ? bv.y : 0.2f * bv.y;
        bv.z = fmaf(bv.z, s, h); bv.z = bv.z >= 0.f ? bv.z : 0.2f * bv.z;
        bv.w = fmaf(bv.w, s, h); bv.w = bv.w >= 0.f ? bv.w : 0.2f * bv.w;
        *(float4*)&Bs[bkr][bc] = bv;
        __syncthreads();
#pragma unroll
        for (int k = 0; k < 16; ++k) {
            float a[4], bb[4];
            *(float4*)a  = *(const float4*)&As[k][ty << 2];
            *(float4*)bb = *(const float4*)&Bs[k][tx << 2];
#pragma unroll
            for (int i = 0; i < 4; ++i)
#pragma unroll
                for (int j = 0; j < 4; ++j)
                    acc[i][j] = fmaf(a[i], bb[j], acc[i][j]);
        }
        __syncthreads();
    }
#pragma unroll
    for (int i = 0; i < 4; ++i) {
        const int o = row0 + (ty << 2) + i;   // output channel p
        *(float4*)(out + (size_t)b * (H2C * M_) + (size_t)o * M_ + m0 + (tx << 2)) =
            make_float4(acc[i][0], acc[i][1], acc[i][2], acc[i][3]);
    }
}

// ---------------------------------------------------------------------------
// Kernel 6: BN2 stats over d_out's [B,H2C,M] layout. One block per channel.
// ---------------------------------------------------------------------------
__global__ __launch_bounds__(256) void bn_stats2(const float* __restrict__ raw,
                                                 const float* __restrict__ gamma,
                                                 const float* __restrict__ beta,
                                                 float* __restrict__ scale,
                                                 float* __restrict__ shift) {
    const int c = blockIdx.x;
    float s = 0.f, q = 0.f;
    for (int t = threadIdx.x; t < NCOL; t += 256) {
        const int bb = t >> 13;          // /M_
        const int mm = t & (M_ - 1);
        const float v = raw[(size_t)bb * (H2C * M_) + (size_t)c * M_ + mm];
        s += v; q += v * v;
    }
    __shared__ float rs[256], rq[256];
    rs[threadIdx.x] = s; rq[threadIdx.x] = q;
    __syncthreads();
    for (int st = 128; st > 0; st >>= 1) {
        if (threadIdx.x < st) {
            rs[threadIdx.x] += rs[threadIdx.x + st];
            rq[threadIdx.x] += rq[threadIdx.x + st];
        }
        __syncthreads();
    }
    if (threadIdx.x == 0) {
        const float mean = rs[0] * (1.0f / NCOL);
        const float var  = fmaxf(rq[0] * (1.0f / NCOL) - mean * mean, 0.f);
        const float is   = rsqrtf(var + 1e-5f);
        const float sc   = gamma[c] * is;
        scale[c] = sc;
        shift[c] = beta[c] - mean * sc;
    }
}

// ---------------------------------------------------------------------------
// Kernel 7: in-place BN2 affine + leaky on d_out.
// ---------------------------------------------------------------------------
__global__ __launch_bounds__(256) void bn_apply2(float* __restrict__ out,
                                                 const float* __restrict__ sc,
                                                 const float* __restrict__ sh) {
    const size_t i = (size_t)blockIdx.x * 256 + threadIdx.x;
    const int p = (int)((i >> 13) & (H2C - 1));
    float v = out[i];
    v = fmaf(v, sc[p], sh[p]);
    out[i] = v >= 0.f ? v : 0.2f * v;
}

// ---------------------------------------------------------------------------
extern "C" void kernel_launch(void* const* d_in, const int* in_sizes, int n_in,
                              void* d_out, int out_size, void* d_ws, size_t ws_size,
                              hipStream_t stream) {
    const float* pos      = (const float*)d_in[0];
    const float* pos_skip = (const float*)d_in[1];
    const float* x        = (const float*)d_in[2];
    const float* x_skip   = (const float*)d_in[3];
    const float* W1       = (const float*)d_in[4];
    const float* gamma1   = (const float*)d_in[5];
    const float* beta1    = (const float*)d_in[6];
    const float* W2       = (const float*)d_in[7];
    const float* gamma2   = (const float*)d_in[8];
    const float* beta2    = (const float*)d_in[9];
    float* out = (float*)d_out;

    // workspace carve-up (~170 MB total)
    char* ws = (char*)d_ws;
    size_t off = 0;
    auto alloc = [&](size_t bytes) {
        void* p = ws + off;
        off = (off + bytes + 255) & ~(size_t)255;
        return p;
    };
    int*   idx = (int*)  alloc((size_t)NCOL * 3 * sizeof(int));
    float* w   = (float*)alloc((size_t)NCOL * 3 * sizeof(float));
    float* G   = (float*)alloc((size_t)H1C * GCOL * sizeof(float));   // 33.5 MB
    float* H1  = (float*)alloc((size_t)H1C * NCOL * sizeof(float));   // 134 MB
    float* sc1 = (float*)alloc(H1C * sizeof(float));
    float* sh1 = (float*)alloc(H1C * sizeof(float));
    float* sc2 = (float*)alloc(H2C * sizeof(float));
    float* sh2 = (float*)alloc(H2C * sizeof(float));

    knn_kernel<<<dim3(M_ / 256, B_), 256, 0, stream>>>(pos, pos_skip, idx, w);
    gemm_G    <<<dim3(GCOL / 64, H1C / 64), 256, 0, stream>>>(W1, x, G);
    gemm_H1   <<<dim3(NCOL / 64, H1C / 64), 256, 0, stream>>>(W1, x_skip, G, idx, w, H1);
    bn_stats1 <<<H1C, 256, 0, stream>>>(H1, gamma1, beta1, sc1, sh1);
    gemm_H2   <<<dim3(NCOL / 64, H2C / 64), 256, 0, stream>>>(W2, H1, sc1, sh1, out);
    bn_stats2 <<<H2C, 256, 0, stream>>>(out, gamma2, beta2, sc2, sh2);
    bn_apply2 <<<(NCOL * H2C) / 256, 256, 0, stream>>>(out, sc2, sh2);
}

// Round 4
// 607.104 us; speedup vs baseline: 1.9902x; 1.9902x over previous
//
#include <hip/hip_runtime.h>
#include <stdint.h>

// Problem constants
#define B_    8
#define N_    2048
#define M_    8192
#define C_    512
#define CSK   256
#define CIN   768
#define H1C   512
#define H2C   256
#define NCOL  65536     // B_*M_
typedef unsigned short u16;
typedef __attribute__((ext_vector_type(8))) short  s16x8;
typedef __attribute__((ext_vector_type(4))) float  f32x4;

// ---- bf16 helpers (RNE) ----
__device__ inline u16 f2bf(float f) {
    unsigned u = __float_as_uint(f);
    unsigned r = (u + 0x7fffu + ((u >> 16) & 1u)) >> 16;
    return (u16)r;
}
__device__ inline float bflo(unsigned u) { return __uint_as_float(u << 16); }
__device__ inline float bfhi(unsigned u) { return __uint_as_float(u & 0xffff0000u); }

// ---------------------------------------------------------------------------
// f32 -> bf16 bulk convert (n multiple of 4)
// ---------------------------------------------------------------------------
__global__ __launch_bounds__(256) void cvt_bf16_k(const float* __restrict__ in,
                                                  u16* __restrict__ out, int n4) {
    const int i = blockIdx.x * 256 + threadIdx.x;
    if (i >= n4) return;
    const float4 v = *(const float4*)(in + (size_t)i * 4);
    u16 o[4] = {f2bf(v.x), f2bf(v.y), f2bf(v.z), f2bf(v.w)};
    *(uint2*)(out + (size_t)i * 4) = *(uint2*)o;
}

// ---------------------------------------------------------------------------
// 3-NN + interpolation weights
// ---------------------------------------------------------------------------
__global__ __launch_bounds__(256) void knn_kernel(const float* __restrict__ pos,
                                                  const float* __restrict__ pos_skip,
                                                  int* __restrict__ idx_out,
                                                  float* __restrict__ w_out) {
    __shared__ float rp[N_ * 3];
    const int b = blockIdx.y;
    const int tid = threadIdx.x;
    for (int t = tid; t < N_ * 3; t += 256) rp[t] = pos[(size_t)b * N_ * 3 + t];
    __syncthreads();

    const int m = blockIdx.x * 256 + tid;
    const size_t qoff = ((size_t)b * M_ + m) * 3;
    const float qx = pos_skip[qoff], qy = pos_skip[qoff + 1], qz = pos_skip[qoff + 2];

    float d0 = 1e30f, d1 = 1e30f, d2 = 1e30f;
    int i0 = 0, i1 = 0, i2 = 0;
    for (int n = 0; n < N_; ++n) {
        const float dx = qx - rp[n * 3 + 0];
        const float dy = qy - rp[n * 3 + 1];
        const float dz = qz - rp[n * 3 + 2];
        const float d = dx * dx + dy * dy + dz * dz;
        if (d < d2) {
            if (d < d1) {
                d2 = d1; i2 = i1;
                if (d < d0) { d1 = d0; i1 = i0; d0 = d; i0 = n; }
                else        { d1 = d;  i1 = n; }
            } else { d2 = d; i2 = n; }
        }
    }
    const float r0 = 1.0f / (sqrtf(d0) + 1e-8f);
    const float r1 = 1.0f / (sqrtf(d1) + 1e-8f);
    const float r2 = 1.0f / (sqrtf(d2) + 1e-8f);
    const float inv = 1.0f / (r0 + r1 + r2);
    const size_t o = ((size_t)b * M_ + m) * 3;
    idx_out[o] = i0; idx_out[o + 1] = i1; idx_out[o + 2] = i2;
    w_out[o] = r0 * inv; w_out[o + 1] = r1 * inv; w_out[o + 2] = r2 * inv;
}

// ---------------------------------------------------------------------------
// x [b][c][n] f32 -> xT [b][n][c] bf16   (32x32 LDS tile transpose)
// ---------------------------------------------------------------------------
__global__ __launch_bounds__(256) void transpose_x(const float* __restrict__ x,
                                                   u16* __restrict__ xT) {
    __shared__ float t[32][33];
    const int tx = threadIdx.x & 31, ty = threadIdx.x >> 5;   // ty 0..7
    const int n0 = blockIdx.x * 32, c0 = blockIdx.y * 32, b = blockIdx.z;
#pragma unroll
    for (int r = 0; r < 4; ++r) {
        const int c = c0 + ty + r * 8;
        t[ty + r * 8][tx] = x[((size_t)b * C_ + c) * N_ + n0 + tx];
    }
    __syncthreads();
#pragma unroll
    for (int r = 0; r < 4; ++r) {
        const int n = n0 + ty + r * 8;
        xT[((size_t)b * N_ + n) * C_ + c0 + tx] = f2bf(t[tx][ty + r * 8]);
    }
}

// ---------------------------------------------------------------------------
// x_skip [b][c][m] f32 -> Feats[b*M+m][512+c] bf16
// ---------------------------------------------------------------------------
__global__ __launch_bounds__(256) void feats_skip(const float* __restrict__ xs,
                                                  u16* __restrict__ Feats) {
    __shared__ float t[32][33];
    const int tx = threadIdx.x & 31, ty = threadIdx.x >> 5;
    const int m0 = blockIdx.x * 32, c0 = blockIdx.y * 32, b = blockIdx.z;
#pragma unroll
    for (int r = 0; r < 4; ++r) {
        const int c = c0 + ty + r * 8;
        t[ty + r * 8][tx] = xs[((size_t)b * CSK + c) * M_ + m0 + tx];
    }
    __syncthreads();
#pragma unroll
    for (int r = 0; r < 4; ++r) {
        const int m = m0 + ty + r * 8;
        Feats[((size_t)b * M_ + m) * CIN + C_ + c0 + tx] = f2bf(t[tx][ty + r * 8]);
    }
}

// ---------------------------------------------------------------------------
// Feats[col][0..511] = sum_k w[k] * xT[b][idx_k][:]   (wave reads full rows)
// grid (M_/64, B_), block 256 (4 waves, 16 m's each)
// ---------------------------------------------------------------------------
__device__ inline unsigned interp_pk(unsigned a, unsigned b, unsigned c,
                                     float w0, float w1, float w2) {
    const float lo = w0 * bflo(a) + w1 * bflo(b) + w2 * bflo(c);
    const float hi = w0 * bfhi(a) + w1 * bfhi(b) + w2 * bfhi(c);
    return (unsigned)f2bf(lo) | ((unsigned)f2bf(hi) << 16);
}
__global__ __launch_bounds__(256) void feats_interp(const u16* __restrict__ xT,
                                                    const int* __restrict__ idx,
                                                    const float* __restrict__ w,
                                                    u16* __restrict__ Feats) {
    const int b = blockIdx.y;
    const int lane = threadIdx.x & 63, wv = threadIdx.x >> 6;
    for (int t = 0; t < 16; ++t) {
        const int m = blockIdx.x * 64 + wv * 16 + t;
        const size_t col = (size_t)b * M_ + m;
        const int i0 = idx[col * 3], i1 = idx[col * 3 + 1], i2 = idx[col * 3 + 2];
        const float w0 = w[col * 3], w1 = w[col * 3 + 1], w2 = w[col * 3 + 2];
        const uint4 a = *(const uint4*)(xT + ((size_t)b * N_ + i0) * C_ + lane * 8);
        const uint4 c = *(const uint4*)(xT + ((size_t)b * N_ + i1) * C_ + lane * 8);
        const uint4 d = *(const uint4*)(xT + ((size_t)b * N_ + i2) * C_ + lane * 8);
        uint4 r;
        r.x = interp_pk(a.x, c.x, d.x, w0, w1, w2);
        r.y = interp_pk(a.y, c.y, d.y, w0, w1, w2);
        r.z = interp_pk(a.z, c.z, d.z, w0, w1, w2);
        r.w = interp_pk(a.w, c.w, d.w, w0, w1, w2);
        *(uint4*)(Feats + col * CIN + lane * 8) = r;
    }
}

// ---------------------------------------------------------------------------
// MFMA GEMM, m97 structure: 128x128 tile, BK=32, 4 waves, global_load_lds w16.
// A [Mdim][K] bf16 (stride LD), B [Ndim][K] bf16 (stride LD).
// SWAP=true : D stored transposed as bf16 C[col][o], ldc = H1C (for H1^T)
// SWAP=false: D stored f32 into out[b][p][m] (col = b*M_+m)
// ---------------------------------------------------------------------------
__device__ inline void stage_tile(u16* lds, const u16* gbase, int ld,
                                  int lane, int wv) {
#pragma unroll
    for (int jj = 0; jj < 2; ++jj) {
        const int chunk = jj * 4 + wv;                 // 0..7, 1KB each
        const int row = chunk * 16 + (lane >> 2);      // 0..127
        const int bir = (lane & 3) * 16;               // byte in 64B row
        const char* g = (const char*)gbase + (size_t)row * (ld * 2) + bir;
        __builtin_amdgcn_global_load_lds(
            (const __attribute__((address_space(1))) void*)g,
            (__attribute__((address_space(3))) void*)((char*)lds + chunk * 1024),
            16, 0, 0);
    }
}

template<int KTOT, int LD, bool SWAP>
__global__ __launch_bounds__(256) void mfma_gemm(const u16* __restrict__ A,
                                                 const u16* __restrict__ Bm,
                                                 void* __restrict__ Cout) {
    __shared__ __attribute__((aligned(16))) u16 As[128 * 32];
    __shared__ __attribute__((aligned(16))) u16 Bs[128 * 32];
    const int tid = threadIdx.x;
    const int lane = tid & 63, wv = tid >> 6;
    const int wr = wv >> 1, wc = wv & 1;
    const int l15 = lane & 15, l4 = lane >> 4;
    const int rowM0 = blockIdx.y * 128, colN0 = blockIdx.x * 128;
    f32x4 acc[4][4] = {};
    const u16* Ab = A  + (size_t)rowM0 * LD;
    const u16* Bb = Bm + (size_t)colN0 * LD;

    for (int k0 = 0; k0 < KTOT; k0 += 32) {
        stage_tile(As, Ab + k0, LD, lane, wv);
        stage_tile(Bs, Bb + k0, LD, lane, wv);
        __syncthreads();
        s16x8 af[4], bfr[4];
#pragma unroll
        for (int i = 0; i < 4; ++i)
            af[i] = *(const s16x8*)&As[(wr * 64 + i * 16 + l15) * 32 + l4 * 8];
#pragma unroll
        for (int j = 0; j < 4; ++j)
            bfr[j] = *(const s16x8*)&Bs[(wc * 64 + j * 16 + l15) * 32 + l4 * 8];
#pragma unroll
        for (int i = 0; i < 4; ++i)
#pragma unroll
            for (int j = 0; j < 4; ++j) {
                if constexpr (SWAP)
                    acc[i][j] = __builtin_amdgcn_mfma_f32_16x16x32_bf16(bfr[j], af[i], acc[i][j], 0, 0, 0);
                else
                    acc[i][j] = __builtin_amdgcn_mfma_f32_16x16x32_bf16(af[i], bfr[j], acc[i][j], 0, 0, 0);
            }
        __syncthreads();
    }

    if constexpr (SWAP) {
        // D[col][o] -> H1^T bf16 [NCOL][H1C]
        u16* C = (u16*)Cout;
#pragma unroll
        for (int i = 0; i < 4; ++i) {
            const int o = rowM0 + wr * 64 + i * 16 + l15;
#pragma unroll
            for (int j = 0; j < 4; ++j) {
                const int colb = colN0 + wc * 64 + j * 16 + l4 * 4;
#pragma unroll
                for (int r = 0; r < 4; ++r)
                    C[(size_t)(colb + r) * H1C + o] = f2bf(acc[i][j][r]);
            }
        }
    } else {
        // D[p][col] -> out f32 [B][H2C][M]
        float* C = (float*)Cout;
#pragma unroll
        for (int j = 0; j < 4; ++j) {
            const int colj = colN0 + wc * 64 + j * 16;
            const int b = colj >> 13, mm = colj & (M_ - 1);
            float* base = C + (size_t)b * (H2C * M_) + mm + l15;
#pragma unroll
            for (int i = 0; i < 4; ++i) {
                const int p = rowM0 + wr * 64 + i * 16 + l4 * 4;
#pragma unroll
                for (int r = 0; r < 4; ++r)
                    base[(size_t)(p + r) * M_] = acc[i][j][r];
            }
        }
    }
}

// ---------------------------------------------------------------------------
// BN1 stats, stage 1: partial sums over col-chunks of H1^T [NCOL][512] bf16.
// grid 128 blocks; block b covers cols [b*512, b*512+512).
// ---------------------------------------------------------------------------
__global__ __launch_bounds__(256) void bn1_partial(const u16* __restrict__ H1,
                                                   float* __restrict__ ps,
                                                   float* __restrict__ pq) {
    const int lane = threadIdx.x & 63, wv = threadIdx.x >> 6;
    float s[8] = {0.f}, q[8] = {0.f};
    for (int cc = wv; cc < 512; cc += 4) {
        const size_t col = (size_t)blockIdx.x * 512 + cc;
        const uint4 v = *(const uint4*)(H1 + col * H1C + lane * 8);
        const unsigned u[4] = {v.x, v.y, v.z, v.w};
#pragma unroll
        for (int e = 0; e < 4; ++e) {
            const float f0 = bflo(u[e]), f1 = bfhi(u[e]);
            s[e * 2] += f0;  q[e * 2] += f0 * f0;
            s[e * 2 + 1] += f1; q[e * 2 + 1] += f1 * f1;
        }
    }
    __shared__ float ls[4][512], lq[4][512];
#pragma unroll
    for (int e = 0; e < 8; ++e) { ls[wv][lane * 8 + e] = s[e]; lq[wv][lane * 8 + e] = q[e]; }
    __syncthreads();
    for (int o = threadIdx.x; o < 512; o += 256) {
        const float S = ls[0][o] + ls[1][o] + ls[2][o] + ls[3][o];
        const float Q = lq[0][o] + lq[1][o] + lq[2][o] + lq[3][o];
        ps[(size_t)blockIdx.x * 512 + o] = S;
        pq[(size_t)blockIdx.x * 512 + o] = Q;
    }
}

__global__ __launch_bounds__(256) void bn1_final(const float* __restrict__ ps,
                                                 const float* __restrict__ pq,
                                                 const float* __restrict__ gamma,
                                                 const float* __restrict__ beta,
                                                 float* __restrict__ sc,
                                                 float* __restrict__ sh) {
    for (int o = threadIdx.x; o < 512; o += 256) {
        float S = 0.f, Q = 0.f;
        for (int p = 0; p < 128; ++p) { S += ps[p * 512 + o]; Q += pq[p * 512 + o]; }
        const float mean = S * (1.0f / NCOL);
        const float var  = fmaxf(Q * (1.0f / NCOL) - mean * mean, 0.f);
        const float is   = rsqrtf(var + 1e-5f);
        const float s    = gamma[o] * is;
        sc[o] = s;
        sh[o] = beta[o] - mean * s;
    }
}

// ---------------------------------------------------------------------------
// In-place BN1 affine + leaky on H1^T (bf16)
// ---------------------------------------------------------------------------
__global__ __launch_bounds__(256) void bn1_apply(u16* __restrict__ H1,
                                                 const float* __restrict__ sc,
                                                 const float* __restrict__ sh) {
    const size_t g = (size_t)blockIdx.x * 256 + threadIdx.x;
    const int og = (int)(g & 63) * 8;
    const size_t col = g >> 6;
    u16* p = H1 + col * H1C + og;
    uint4 v = *(const uint4*)p;
    unsigned u[4] = {v.x, v.y, v.z, v.w};
    const float4 s0 = *(const float4*)(sc + og), s1 = *(const float4*)(sc + og + 4);
    const float4 h0 = *(const float4*)(sh + og), h1 = *(const float4*)(sh + og + 4);
    const float scv[8] = {s0.x, s0.y, s0.z, s0.w, s1.x, s1.y, s1.z, s1.w};
    const float shv[8] = {h0.x, h0.y, h0.z, h0.w, h1.x, h1.y, h1.z, h1.w};
    unsigned r[4];
#pragma unroll
    for (int e = 0; e < 4; ++e) {
        float f0 = fmaf(bflo(u[e]), scv[e * 2], shv[e * 2]);
        float f1 = fmaf(bfhi(u[e]), scv[e * 2 + 1], shv[e * 2 + 1]);
        f0 = f0 >= 0.f ? f0 : 0.2f * f0;
        f1 = f1 >= 0.f ? f1 : 0.2f * f1;
        r[e] = (unsigned)f2bf(f0) | ((unsigned)f2bf(f1) << 16);
    }
    *(uint4*)p = make_uint4(r[0], r[1], r[2], r[3]);
}

// ---------------------------------------------------------------------------
// BN2 stats + apply on d_out [B][H2C][M] f32
// ---------------------------------------------------------------------------
__global__ __launch_bounds__(256) void bn_stats2(const float* __restrict__ raw,
                                                 const float* __restrict__ gamma,
                                                 const float* __restrict__ beta,
                                                 float* __restrict__ scale,
                                                 float* __restrict__ shift) {
    const int c = blockIdx.x;
    float s = 0.f, q = 0.f;
    for (int t = threadIdx.x; t < NCOL; t += 256) {
        const int bb = t >> 13;
        const int mm = t & (M_ - 1);
        const float v = raw[(size_t)bb * (H2C * M_) + (size_t)c * M_ + mm];
        s += v; q += v * v;
    }
    __shared__ float rs[256], rq[256];
    rs[threadIdx.x] = s; rq[threadIdx.x] = q;
    __syncthreads();
    for (int st = 128; st > 0; st >>= 1) {
        if (threadIdx.x < st) {
            rs[threadIdx.x] += rs[threadIdx.x + st];
            rq[threadIdx.x] += rq[threadIdx.x + st];
        }
        __syncthreads();
    }
    if (threadIdx.x == 0) {
        const float mean = rs[0] * (1.0f / NCOL);
        const float var  = fmaxf(rq[0] * (1.0f / NCOL) - mean * mean, 0.f);
        const float is   = rsqrtf(var + 1e-5f);
        const float sc   = gamma[c] * is;
        scale[c] = sc;
        shift[c] = beta[c] - mean * sc;
    }
}

__global__ __launch_bounds__(256) void bn_apply2(float* __restrict__ out,
                                                 const float* __restrict__ sc,
                                                 const float* __restrict__ sh) {
    const size_t i = (size_t)blockIdx.x * 256 + threadIdx.x;
    const int p = (int)((i >> 13) & (H2C - 1));
    float v = out[i];
    v = fmaf(v, sc[p], sh[p]);
    out[i] = v >= 0.f ? v : 0.2f * v;
}

// ---------------------------------------------------------------------------
extern "C" void kernel_launch(void* const* d_in, const int* in_sizes, int n_in,
                              void* d_out, int out_size, void* d_ws, size_t ws_size,
                              hipStream_t stream) {
    const float* pos      = (const float*)d_in[0];
    const float* pos_skip = (const float*)d_in[1];
    const float* x        = (const float*)d_in[2];
    const float* x_skip   = (const float*)d_in[3];
    const float* W1       = (const float*)d_in[4];
    const float* gamma1   = (const float*)d_in[5];
    const float* beta1    = (const float*)d_in[6];
    const float* W2       = (const float*)d_in[7];
    const float* gamma2   = (const float*)d_in[8];
    const float* beta2    = (const float*)d_in[9];
    float* out = (float*)d_out;

    char* ws = (char*)d_ws;
    size_t off = 0;
    auto alloc = [&](size_t bytes) {
        void* p = ws + off;
        off = (off + bytes + 255) & ~(size_t)255;
        return p;
    };
    int*   idx   = (int*)  alloc((size_t)NCOL * 3 * sizeof(int));
    float* w     = (float*)alloc((size_t)NCOL * 3 * sizeof(float));
    u16*   xT    = (u16*)  alloc((size_t)B_ * N_ * C_ * sizeof(u16));     // 16.8 MB
    u16*   W1b   = (u16*)  alloc((size_t)H1C * CIN * sizeof(u16));
    u16*   W2b   = (u16*)  alloc((size_t)H2C * H1C * sizeof(u16));
    u16*   Feats = (u16*)  alloc((size_t)NCOL * CIN * sizeof(u16));       // 100.7 MB
    u16*   H1    = (u16*)  alloc((size_t)NCOL * H1C * sizeof(u16));       // 67.1 MB
    float* ps    = (float*)alloc(128 * 512 * sizeof(float));
    float* pq    = (float*)alloc(128 * 512 * sizeof(float));
    float* sc1   = (float*)alloc(H1C * sizeof(float));
    float* sh1   = (float*)alloc(H1C * sizeof(float));
    float* sc2   = (float*)alloc(H2C * sizeof(float));
    float* sh2   = (float*)alloc(H2C * sizeof(float));

    cvt_bf16_k<<<(H1C * CIN / 4 + 255) / 256, 256, 0, stream>>>(W1, W1b, H1C * CIN / 4);
    cvt_bf16_k<<<(H2C * H1C / 4 + 255) / 256, 256, 0, stream>>>(W2, W2b, H2C * H1C / 4);
    knn_kernel<<<dim3(M_ / 256, B_), 256, 0, stream>>>(pos, pos_skip, idx, w);
    transpose_x<<<dim3(N_ / 32, C_ / 32, B_), 256, 0, stream>>>(x, xT);
    feats_interp<<<dim3(M_ / 64, B_), 256, 0, stream>>>(xT, idx, w, Feats);
    feats_skip<<<dim3(M_ / 32, CSK / 32, B_), 256, 0, stream>>>(x_skip, Feats);
    // GEMM1: H1^T[col][o] = Feats[col][:] . W1b[o][:]   (swapped-store MFMA)
    mfma_gemm<CIN, CIN, true><<<dim3(NCOL / 128, H1C / 128), 256, 0, stream>>>(W1b, Feats, H1);
    bn1_partial<<<128, 256, 0, stream>>>(H1, ps, pq);
    bn1_final<<<1, 256, 0, stream>>>(ps, pq, gamma1, beta1, sc1, sh1);
    bn1_apply<<<(int)(((size_t)NCOL * H1C / 8) / 256), 256, 0, stream>>>(H1, sc1, sh1);
    // GEMM2: out[b][p][m] = W2b[p][:] . H1act^T[col][:]
    mfma_gemm<H1C, H1C, false><<<dim3(NCOL / 128, H2C / 128), 256, 0, stream>>>(W2b, H1, out);
    bn_stats2<<<H2C, 256, 0, stream>>>(out, gamma2, beta2, sc2, sh2);
    bn_apply2<<<(int)(((size_t)NCOL * H2C) / 256), 256, 0, stream>>>(out, sc2, sh2);
}

// Round 5
// 573.575 us; speedup vs baseline: 2.1065x; 1.0585x over previous
//
#include <hip/hip_runtime.h>
#include <stdint.h>

// Problem constants
#define B_    8
#define N_    2048
#define M_    8192
#define C_    512
#define CSK   256
#define CIN   768
#define H1C   512
#define H2C   256
#define NCOL  65536     // B_*M_
typedef unsigned short u16;
typedef __attribute__((ext_vector_type(8))) short  s16x8;
typedef __attribute__((ext_vector_type(4))) float  f32x4;

// ---- bf16 helpers (RNE) ----
__device__ inline u16 f2bf(float f) {
    unsigned u = __float_as_uint(f);
    unsigned r = (u + 0x7fffu + ((u >> 16) & 1u)) >> 16;
    return (u16)r;
}
__device__ inline float bflo(unsigned u) { return __uint_as_float(u << 16); }
__device__ inline float bfhi(unsigned u) { return __uint_as_float(u & 0xffff0000u); }

// ---------------------------------------------------------------------------
// f32 -> bf16 bulk convert (n multiple of 4)
// ---------------------------------------------------------------------------
__global__ __launch_bounds__(256) void cvt_bf16_k(const float* __restrict__ in,
                                                  u16* __restrict__ out, int n4) {
    const int i = blockIdx.x * 256 + threadIdx.x;
    if (i >= n4) return;
    const float4 v = *(const float4*)(in + (size_t)i * 4);
    u16 o[4] = {f2bf(v.x), f2bf(v.y), f2bf(v.z), f2bf(v.w)};
    *(uint2*)(out + (size_t)i * 4) = *(uint2*)o;
}

// ---------------------------------------------------------------------------
// 3-NN + interpolation weights.
// 4 lanes per query: each scans 512 refs (SoA LDS, float4 loads), local top-3,
// then shfl_xor merge. Block 256 = 64 queries; grid (M_/64, B_) = 1024 blocks.
// ---------------------------------------------------------------------------
__device__ inline void ins3(float d, int n,
                            float& d0, int& i0, float& d1, int& i1,
                            float& d2, int& i2) {
    if (d < d2) {
        if (d < d1) {
            d2 = d1; i2 = i1;
            if (d < d0) { d1 = d0; i1 = i0; d0 = d; i0 = n; }
            else        { d1 = d;  i1 = n; }
        } else { d2 = d; i2 = n; }
    }
}

__global__ __launch_bounds__(256) void knn_kernel(const float* __restrict__ pos,
                                                  const float* __restrict__ pos_skip,
                                                  int* __restrict__ idx_out,
                                                  float* __restrict__ w_out) {
    __shared__ float rpx[N_], rpy[N_], rpz[N_];
    const int b = blockIdx.y;
    const int tid = threadIdx.x;
    for (int t = tid; t < N_ * 3; t += 256) {
        const float v = pos[(size_t)b * N_ * 3 + t];
        const int n = t / 3, k = t - n * 3;
        if (k == 0) rpx[n] = v; else if (k == 1) rpy[n] = v; else rpz[n] = v;
    }
    __syncthreads();

    const int q = tid >> 2;          // query slot within block
    const int part = tid & 3;        // ref-chunk 0..3
    const int m = blockIdx.x * 64 + q;
    const size_t qoff = ((size_t)b * M_ + m) * 3;
    const float qx = pos_skip[qoff], qy = pos_skip[qoff + 1], qz = pos_skip[qoff + 2];

    float d0 = 1e30f, d1 = 1e30f, d2 = 1e30f;
    int i0 = 0, i1 = 0, i2 = 0;
    const int base = part * 512;
    for (int n = base; n < base + 512; n += 4) {
        const float4 xx = *(const float4*)&rpx[n];
        const float4 yy = *(const float4*)&rpy[n];
        const float4 zz = *(const float4*)&rpz[n];
        float dd[4];
        {
            const float dx = qx - xx.x, dy = qy - yy.x, dz = qz - zz.x;
            dd[0] = dx * dx + dy * dy + dz * dz;
        }
        {
            const float dx = qx - xx.y, dy = qy - yy.y, dz = qz - zz.y;
            dd[1] = dx * dx + dy * dy + dz * dz;
        }
        {
            const float dx = qx - xx.z, dy = qy - yy.z, dz = qz - zz.z;
            dd[2] = dx * dx + dy * dy + dz * dz;
        }
        {
            const float dx = qx - xx.w, dy = qy - yy.w, dz = qz - zz.w;
            dd[3] = dx * dx + dy * dy + dz * dz;
        }
        ins3(dd[0], n + 0, d0, i0, d1, i1, d2, i2);
        ins3(dd[1], n + 1, d0, i0, d1, i1, d2, i2);
        ins3(dd[2], n + 2, d0, i0, d1, i1, d2, i2);
        ins3(dd[3], n + 3, d0, i0, d1, i1, d2, i2);
    }

    // merge top-3 across the 4 lanes of this query (xor 1, then 2)
#pragma unroll
    for (int xm = 1; xm <= 2; xm <<= 1) {
        const float od0 = __shfl_xor(d0, xm), od1 = __shfl_xor(d1, xm), od2 = __shfl_xor(d2, xm);
        const int   oi0 = __shfl_xor(i0, xm), oi1 = __shfl_xor(i1, xm), oi2 = __shfl_xor(i2, xm);
        ins3(od0, oi0, d0, i0, d1, i1, d2, i2);
        ins3(od1, oi1, d0, i0, d1, i1, d2, i2);
        ins3(od2, oi2, d0, i0, d1, i1, d2, i2);
    }

    if (part == 0) {
        const float r0 = 1.0f / (sqrtf(d0) + 1e-8f);
        const float r1 = 1.0f / (sqrtf(d1) + 1e-8f);
        const float r2 = 1.0f / (sqrtf(d2) + 1e-8f);
        const float inv = 1.0f / (r0 + r1 + r2);
        const size_t o = ((size_t)b * M_ + m) * 3;
        idx_out[o] = i0; idx_out[o + 1] = i1; idx_out[o + 2] = i2;
        w_out[o] = r0 * inv; w_out[o + 1] = r1 * inv; w_out[o + 2] = r2 * inv;
    }
}

// ---------------------------------------------------------------------------
// x [b][c][n] f32 -> xT [b][n][c] bf16   (32x32 LDS tile transpose)
// ---------------------------------------------------------------------------
__global__ __launch_bounds__(256) void transpose_x(const float* __restrict__ x,
                                                   u16* __restrict__ xT) {
    __shared__ float t[32][33];
    const int tx = threadIdx.x & 31, ty = threadIdx.x >> 5;   // ty 0..7
    const int n0 = blockIdx.x * 32, c0 = blockIdx.y * 32, b = blockIdx.z;
#pragma unroll
    for (int r = 0; r < 4; ++r) {
        const int c = c0 + ty + r * 8;
        t[ty + r * 8][tx] = x[((size_t)b * C_ + c) * N_ + n0 + tx];
    }
    __syncthreads();
#pragma unroll
    for (int r = 0; r < 4; ++r) {
        const int n = n0 + ty + r * 8;
        xT[((size_t)b * N_ + n) * C_ + c0 + tx] = f2bf(t[tx][ty + r * 8]);
    }
}

// ---------------------------------------------------------------------------
// x_skip [b][c][m] f32 -> Feats[b*M+m][512+c] bf16
// ---------------------------------------------------------------------------
__global__ __launch_bounds__(256) void feats_skip(const float* __restrict__ xs,
                                                  u16* __restrict__ Feats) {
    __shared__ float t[32][33];
    const int tx = threadIdx.x & 31, ty = threadIdx.x >> 5;
    const int m0 = blockIdx.x * 32, c0 = blockIdx.y * 32, b = blockIdx.z;
#pragma unroll
    for (int r = 0; r < 4; ++r) {
        const int c = c0 + ty + r * 8;
        t[ty + r * 8][tx] = xs[((size_t)b * CSK + c) * M_ + m0 + tx];
    }
    __syncthreads();
#pragma unroll
    for (int r = 0; r < 4; ++r) {
        const int m = m0 + ty + r * 8;
        Feats[((size_t)b * M_ + m) * CIN + C_ + c0 + tx] = f2bf(t[tx][ty + r * 8]);
    }
}

// ---------------------------------------------------------------------------
// Feats[col][0..511] = sum_k w[k] * xT[b][idx_k][:]   (wave reads full rows)
// grid (M_/64, B_), block 256 (4 waves, 16 m's each)
// ---------------------------------------------------------------------------
__device__ inline unsigned interp_pk(unsigned a, unsigned b, unsigned c,
                                     float w0, float w1, float w2) {
    const float lo = w0 * bflo(a) + w1 * bflo(b) + w2 * bflo(c);
    const float hi = w0 * bfhi(a) + w1 * bfhi(b) + w2 * bfhi(c);
    return (unsigned)f2bf(lo) | ((unsigned)f2bf(hi) << 16);
}
__global__ __launch_bounds__(256) void feats_interp(const u16* __restrict__ xT,
                                                    const int* __restrict__ idx,
                                                    const float* __restrict__ w,
                                                    u16* __restrict__ Feats) {
    const int b = blockIdx.y;
    const int lane = threadIdx.x & 63, wv = threadIdx.x >> 6;
    for (int t = 0; t < 16; ++t) {
        const int m = blockIdx.x * 64 + wv * 16 + t;
        const size_t col = (size_t)b * M_ + m;
        const int i0 = idx[col * 3], i1 = idx[col * 3 + 1], i2 = idx[col * 3 + 2];
        const float w0 = w[col * 3], w1 = w[col * 3 + 1], w2 = w[col * 3 + 2];
        const uint4 a = *(const uint4*)(xT + ((size_t)b * N_ + i0) * C_ + lane * 8);
        const uint4 c = *(const uint4*)(xT + ((size_t)b * N_ + i1) * C_ + lane * 8);
        const uint4 d = *(const uint4*)(xT + ((size_t)b * N_ + i2) * C_ + lane * 8);
        uint4 r;
        r.x = interp_pk(a.x, c.x, d.x, w0, w1, w2);
        r.y = interp_pk(a.y, c.y, d.y, w0, w1, w2);
        r.z = interp_pk(a.z, c.z, d.z, w0, w1, w2);
        r.w = interp_pk(a.w, c.w, d.w, w0, w1, w2);
        *(uint4*)(Feats + col * CIN + lane * 8) = r;
    }
}

// ---------------------------------------------------------------------------
// MFMA GEMM, m97 structure: 128x128 tile, BK=32, 4 waves, global_load_lds w16.
// A [Mdim][K] bf16 (stride LD), B [Ndim][K] bf16 (stride LD).
// SWAP=true : D stored transposed as bf16 C[col][o], ldc = H1C (for H1^T)
// SWAP=false: D stored f32 into out[b][p][m] (col = b*M_+m)
// ---------------------------------------------------------------------------
__device__ inline void stage_tile(u16* lds, const u16* gbase, int ld,
                                  int lane, int wv) {
#pragma unroll
    for (int jj = 0; jj < 2; ++jj) {
        const int chunk = jj * 4 + wv;                 // 0..7, 1KB each
        const int row = chunk * 16 + (lane >> 2);      // 0..127
        const int bir = (lane & 3) * 16;               // byte in 64B row
        const char* g = (const char*)gbase + (size_t)row * (ld * 2) + bir;
        __builtin_amdgcn_global_load_lds(
            (const __attribute__((address_space(1))) void*)g,
            (__attribute__((address_space(3))) void*)((char*)lds + chunk * 1024),
            16, 0, 0);
    }
}

template<int KTOT, int LD, bool SWAP>
__global__ __launch_bounds__(256) void mfma_gemm(const u16* __restrict__ A,
                                                 const u16* __restrict__ Bm,
                                                 void* __restrict__ Cout) {
    __shared__ __attribute__((aligned(16))) u16 As[128 * 32];
    __shared__ __attribute__((aligned(16))) u16 Bs[128 * 32];
    const int tid = threadIdx.x;
    const int lane = tid & 63, wv = tid >> 6;
    const int wr = wv >> 1, wc = wv & 1;
    const int l15 = lane & 15, l4 = lane >> 4;
    const int rowM0 = blockIdx.y * 128, colN0 = blockIdx.x * 128;
    f32x4 acc[4][4] = {};
    const u16* Ab = A  + (size_t)rowM0 * LD;
    const u16* Bb = Bm + (size_t)colN0 * LD;

    for (int k0 = 0; k0 < KTOT; k0 += 32) {
        stage_tile(As, Ab + k0, LD, lane, wv);
        stage_tile(Bs, Bb + k0, LD, lane, wv);
        __syncthreads();
        s16x8 af[4], bfr[4];
#pragma unroll
        for (int i = 0; i < 4; ++i)
            af[i] = *(const s16x8*)&As[(wr * 64 + i * 16 + l15) * 32 + l4 * 8];
#pragma unroll
        for (int j = 0; j < 4; ++j)
            bfr[j] = *(const s16x8*)&Bs[(wc * 64 + j * 16 + l15) * 32 + l4 * 8];
#pragma unroll
        for (int i = 0; i < 4; ++i)
#pragma unroll
            for (int j = 0; j < 4; ++j) {
                if constexpr (SWAP)
                    acc[i][j] = __builtin_amdgcn_mfma_f32_16x16x32_bf16(bfr[j], af[i], acc[i][j], 0, 0, 0);
                else
                    acc[i][j] = __builtin_amdgcn_mfma_f32_16x16x32_bf16(af[i], bfr[j], acc[i][j], 0, 0, 0);
            }
        __syncthreads();
    }

    if constexpr (SWAP) {
        // D[col][o] -> H1^T bf16 [NCOL][H1C]
        u16* C = (u16*)Cout;
#pragma unroll
        for (int i = 0; i < 4; ++i) {
            const int o = rowM0 + wr * 64 + i * 16 + l15;
#pragma unroll
            for (int j = 0; j < 4; ++j) {
                const int colb = colN0 + wc * 64 + j * 16 + l4 * 4;
#pragma unroll
                for (int r = 0; r < 4; ++r)
                    C[(size_t)(colb + r) * H1C + o] = f2bf(acc[i][j][r]);
            }
        }
    } else {
        // D[p][col] -> out f32 [B][H2C][M]
        float* C = (float*)Cout;
#pragma unroll
        for (int j = 0; j < 4; ++j) {
            const int colj = colN0 + wc * 64 + j * 16;
            const int b = colj >> 13, mm = colj & (M_ - 1);
            float* base = C + (size_t)b * (H2C * M_) + mm + l15;
#pragma unroll
            for (int i = 0; i < 4; ++i) {
                const int p = rowM0 + wr * 64 + i * 16 + l4 * 4;
#pragma unroll
                for (int r = 0; r < 4; ++r)
                    base[(size_t)(p + r) * M_] = acc[i][j][r];
            }
        }
    }
}

// ---------------------------------------------------------------------------
// BN1 stats, stage 1: partial sums over col-chunks of H1^T [NCOL][512] bf16.
// ---------------------------------------------------------------------------
__global__ __launch_bounds__(256) void bn1_partial(const u16* __restrict__ H1,
                                                   float* __restrict__ ps,
                                                   float* __restrict__ pq) {
    const int lane = threadIdx.x & 63, wv = threadIdx.x >> 6;
    float s[8] = {0.f}, q[8] = {0.f};
    for (int cc = wv; cc < 512; cc += 4) {
        const size_t col = (size_t)blockIdx.x * 512 + cc;
        const uint4 v = *(const uint4*)(H1 + col * H1C + lane * 8);
        const unsigned u[4] = {v.x, v.y, v.z, v.w};
#pragma unroll
        for (int e = 0; e < 4; ++e) {
            const float f0 = bflo(u[e]), f1 = bfhi(u[e]);
            s[e * 2] += f0;  q[e * 2] += f0 * f0;
            s[e * 2 + 1] += f1; q[e * 2 + 1] += f1 * f1;
        }
    }
    __shared__ float ls[4][512], lq[4][512];
#pragma unroll
    for (int e = 0; e < 8; ++e) { ls[wv][lane * 8 + e] = s[e]; lq[wv][lane * 8 + e] = q[e]; }
    __syncthreads();
    for (int o = threadIdx.x; o < 512; o += 256) {
        const float S = ls[0][o] + ls[1][o] + ls[2][o] + ls[3][o];
        const float Q = lq[0][o] + lq[1][o] + lq[2][o] + lq[3][o];
        ps[(size_t)blockIdx.x * 512 + o] = S;
        pq[(size_t)blockIdx.x * 512 + o] = Q;
    }
}

__global__ __launch_bounds__(256) void bn1_final(const float* __restrict__ ps,
                                                 const float* __restrict__ pq,
                                                 const float* __restrict__ gamma,
                                                 const float* __restrict__ beta,
                                                 float* __restrict__ sc,
                                                 float* __restrict__ sh) {
    for (int o = threadIdx.x; o < 512; o += 256) {
        float S = 0.f, Q = 0.f;
        for (int p = 0; p < 128; ++p) { S += ps[p * 512 + o]; Q += pq[p * 512 + o]; }
        const float mean = S * (1.0f / NCOL);
        const float var  = fmaxf(Q * (1.0f / NCOL) - mean * mean, 0.f);
        const float is   = rsqrtf(var + 1e-5f);
        const float s    = gamma[o] * is;
        sc[o] = s;
        sh[o] = beta[o] - mean * s;
    }
}

// ---------------------------------------------------------------------------
// In-place BN1 affine + leaky on H1^T (bf16)
// ---------------------------------------------------------------------------
__global__ __launch_bounds__(256) void bn1_apply(u16* __restrict__ H1,
                                                 const float* __restrict__ sc,
                                                 const float* __restrict__ sh) {
    const size_t g = (size_t)blockIdx.x * 256 + threadIdx.x;
    const int og = (int)(g & 63) * 8;
    const size_t col = g >> 6;
    u16* p = H1 + col * H1C + og;
    uint4 v = *(const uint4*)p;
    unsigned u[4] = {v.x, v.y, v.z, v.w};
    const float4 s0 = *(const float4*)(sc + og), s1 = *(const float4*)(sc + og + 4);
    const float4 h0 = *(const float4*)(sh + og), h1 = *(const float4*)(sh + og + 4);
    const float scv[8] = {s0.x, s0.y, s0.z, s0.w, s1.x, s1.y, s1.z, s1.w};
    const float shv[8] = {h0.x, h0.y, h0.z, h0.w, h1.x, h1.y, h1.z, h1.w};
    unsigned r[4];
#pragma unroll
    for (int e = 0; e < 4; ++e) {
        float f0 = fmaf(bflo(u[e]), scv[e * 2], shv[e * 2]);
        float f1 = fmaf(bfhi(u[e]), scv[e * 2 + 1], shv[e * 2 + 1]);
        f0 = f0 >= 0.f ? f0 : 0.2f * f0;
        f1 = f1 >= 0.f ? f1 : 0.2f * f1;
        r[e] = (unsigned)f2bf(f0) | ((unsigned)f2bf(f1) << 16);
    }
    *(uint4*)p = make_uint4(r[0], r[1], r[2], r[3]);
}

// ---------------------------------------------------------------------------
// BN2 stats + apply on d_out [B][H2C][M] f32
// ---------------------------------------------------------------------------
__global__ __launch_bounds__(256) void bn_stats2(const float* __restrict__ raw,
                                                 const float* __restrict__ gamma,
                                                 const float* __restrict__ beta,
                                                 float* __restrict__ scale,
                                                 float* __restrict__ shift) {
    const int c = blockIdx.x;
    float s = 0.f, q = 0.f;
    for (int t = threadIdx.x; t < NCOL; t += 256) {
        const int bb = t >> 13;
        const int mm = t & (M_ - 1);
        const float v = raw[(size_t)bb * (H2C * M_) + (size_t)c * M_ + mm];
        s += v; q += v * v;
    }
    __shared__ float rs[256], rq[256];
    rs[threadIdx.x] = s; rq[threadIdx.x] = q;
    __syncthreads();
    for (int st = 128; st > 0; st >>= 1) {
        if (threadIdx.x < st) {
            rs[threadIdx.x] += rs[threadIdx.x + st];
            rq[threadIdx.x] += rq[threadIdx.x + st];
        }
        __syncthreads();
    }
    if (threadIdx.x == 0) {
        const float mean = rs[0] * (1.0f / NCOL);
        const float var  = fmaxf(rq[0] * (1.0f / NCOL) - mean * mean, 0.f);
        const float is   = rsqrtf(var + 1e-5f);
        const float sc   = gamma[c] * is;
        scale[c] = sc;
        shift[c] = beta[c] - mean * sc;
    }
}

__global__ __launch_bounds__(256) void bn_apply2(float* __restrict__ out,
                                                 const float* __restrict__ sc,
                                                 const float* __restrict__ sh) {
    const size_t i = (size_t)blockIdx.x * 256 + threadIdx.x;
    const int p = (int)((i >> 13) & (H2C - 1));
    float v = out[i];
    v = fmaf(v, sc[p], sh[p]);
    out[i] = v >= 0.f ? v : 0.2f * v;
}

// ---------------------------------------------------------------------------
extern "C" void kernel_launch(void* const* d_in, const int* in_sizes, int n_in,
                              void* d_out, int out_size, void* d_ws, size_t ws_size,
                              hipStream_t stream) {
    const float* pos      = (const float*)d_in[0];
    const float* pos_skip = (const float*)d_in[1];
    const float* x        = (const float*)d_in[2];
    const float* x_skip   = (const float*)d_in[3];
    const float* W1       = (const float*)d_in[4];
    const float* gamma1   = (const float*)d_in[5];
    const float* beta1    = (const float*)d_in[6];
    const float* W2       = (const float*)d_in[7];
    const float* gamma2   = (const float*)d_in[8];
    const float* beta2    = (const float*)d_in[9];
    float* out = (float*)d_out;

    char* ws = (char*)d_ws;
    size_t off = 0;
    auto alloc = [&](size_t bytes) {
        void* p = ws + off;
        off = (off + bytes + 255) & ~(size_t)255;
        return p;
    };
    int*   idx   = (int*)  alloc((size_t)NCOL * 3 * sizeof(int));
    float* w     = (float*)alloc((size_t)NCOL * 3 * sizeof(float));
    u16*   xT    = (u16*)  alloc((size_t)B_ * N_ * C_ * sizeof(u16));     // 16.8 MB
    u16*   W1b   = (u16*)  alloc((size_t)H1C * CIN * sizeof(u16));
    u16*   W2b   = (u16*)  alloc((size_t)H2C * H1C * sizeof(u16));
    u16*   Feats = (u16*)  alloc((size_t)NCOL * CIN * sizeof(u16));       // 100.7 MB
    u16*   H1    = (u16*)  alloc((size_t)NCOL * H1C * sizeof(u16));       // 67.1 MB
    float* ps    = (float*)alloc(128 * 512 * sizeof(float));
    float* pq    = (float*)alloc(128 * 512 * sizeof(float));
    float* sc1   = (float*)alloc(H1C * sizeof(float));
    float* sh1   = (float*)alloc(H1C * sizeof(float));
    float* sc2   = (float*)alloc(H2C * sizeof(float));
    float* sh2   = (float*)alloc(H2C * sizeof(float));

    cvt_bf16_k<<<(H1C * CIN / 4 + 255) / 256, 256, 0, stream>>>(W1, W1b, H1C * CIN / 4);
    cvt_bf16_k<<<(H2C * H1C / 4 + 255) / 256, 256, 0, stream>>>(W2, W2b, H2C * H1C / 4);
    knn_kernel<<<dim3(M_ / 64, B_), 256, 0, stream>>>(pos, pos_skip, idx, w);
    transpose_x<<<dim3(N_ / 32, C_ / 32, B_), 256, 0, stream>>>(x, xT);
    feats_interp<<<dim3(M_ / 64, B_), 256, 0, stream>>>(xT, idx, w, Feats);
    feats_skip<<<dim3(M_ / 32, CSK / 32, B_), 256, 0, stream>>>(x_skip, Feats);
    // GEMM1: H1^T[col][o] = Feats[col][:] . W1b[o][:]   (swapped-store MFMA)
    mfma_gemm<CIN, CIN, true><<<dim3(NCOL / 128, H1C / 128), 256, 0, stream>>>(W1b, Feats, H1);
    bn1_partial<<<128, 256, 0, stream>>>(H1, ps, pq);
    bn1_final<<<1, 256, 0, stream>>>(ps, pq, gamma1, beta1, sc1, sh1);
    bn1_apply<<<(int)(((size_t)NCOL * H1C / 8) / 256), 256, 0, stream>>>(H1, sc1, sh1);
    // GEMM2: out[b][p][m] = W2b[p][:] . H1act^T[col][:]
    mfma_gemm<H1C, H1C, false><<<dim3(NCOL / 128, H2C / 128), 256, 0, stream>>>(W2b, H1, out);
    bn_stats2<<<H2C, 256, 0, stream>>>(out, gamma2, beta2, sc2, sh2);
    bn_apply2<<<(int)(((size_t)NCOL * H2C) / 256), 256, 0, stream>>>(out, sc2, sh2);
}

// Round 6
// 441.001 us; speedup vs baseline: 2.7398x; 1.3006x over previous
//
#include <hip/hip_runtime.h>
#include <stdint.h>

// Problem constants
#define B_    8
#define N_    2048
#define M_    8192
#define C_    512
#define CSK   256
#define CIN   768
#define H1C   512
#define H2C   256
#define NCOL  65536     // B_*M_
typedef unsigned short u16;
typedef __attribute__((ext_vector_type(8))) short  s16x8;
typedef __attribute__((ext_vector_type(4))) float  f32x4;

// ---- bf16 helpers (RNE) ----
__device__ inline u16 f2bf(float f) {
    unsigned u = __float_as_uint(f);
    unsigned r = (u + 0x7fffu + ((u >> 16) & 1u)) >> 16;
    return (u16)r;
}
__device__ inline float bflo(unsigned u) { return __uint_as_float(u << 16); }
__device__ inline float bfhi(unsigned u) { return __uint_as_float(u & 0xffff0000u); }

// ---------------------------------------------------------------------------
// f32 -> bf16 bulk convert (n multiple of 4)
// ---------------------------------------------------------------------------
__global__ __launch_bounds__(256) void cvt_bf16_k(const float* __restrict__ in,
                                                  u16* __restrict__ out, int n4) {
    const int i = blockIdx.x * 256 + threadIdx.x;
    if (i >= n4) return;
    const float4 v = *(const float4*)(in + (size_t)i * 4);
    u16 o[4] = {f2bf(v.x), f2bf(v.y), f2bf(v.z), f2bf(v.w)};
    *(uint2*)(out + (size_t)i * 4) = *(uint2*)o;
}

// ---------------------------------------------------------------------------
// 3-NN: 8 lanes/query. Part p reads float4 at rp*[4p + 32i] -> bank 4p,
// all 32 banks covered, conflict-free; 8 same-part lanes broadcast.
// Branchless top-3 insert (cmp+cndmask, no divergence).
// Block 256 = 32 queries; grid (M_/32, B_) = 2048 blocks.
// ---------------------------------------------------------------------------
__device__ inline void ins3(float d, int n,
                            float& d0, int& i0, float& d1, int& i1,
                            float& d2, int& i2) {
    const bool lt0 = d < d0, lt1 = d < d1, lt2 = d < d2;
    const float nd2 = lt1 ? d1 : (lt2 ? d : d2);
    const int   ni2 = lt1 ? i1 : (lt2 ? n : i2);
    const float nd1 = lt0 ? d0 : (lt1 ? d : d1);
    const int   ni1 = lt0 ? i0 : (lt1 ? n : i1);
    const float nd0 = lt0 ? d : d0;
    const int   ni0 = lt0 ? n : i0;
    d0 = nd0; d1 = nd1; d2 = nd2; i0 = ni0; i1 = ni1; i2 = ni2;
}

__global__ __launch_bounds__(256) void knn_kernel(const float* __restrict__ pos,
                                                  const float* __restrict__ pos_skip,
                                                  int* __restrict__ idx_out,
                                                  float* __restrict__ w_out) {
    __shared__ float rpx[N_], rpy[N_], rpz[N_];
    const int b = blockIdx.y;
    const int tid = threadIdx.x;
    for (int t = tid; t < N_ * 3; t += 256) {
        const float v = pos[(size_t)b * N_ * 3 + t];
        const int n = t / 3, k = t - n * 3;
        if (k == 0) rpx[n] = v; else if (k == 1) rpy[n] = v; else rpz[n] = v;
    }
    __syncthreads();

    const int q = tid >> 3;          // query slot within block (0..31)
    const int part = tid & 7;        // ref sub-stream 0..7
    const int m = blockIdx.x * 32 + q;
    const size_t qoff = ((size_t)b * M_ + m) * 3;
    const float qx = pos_skip[qoff], qy = pos_skip[qoff + 1], qz = pos_skip[qoff + 2];

    float d0 = 1e30f, d1 = 1e30f, d2 = 1e30f;
    int i0 = 0, i1 = 0, i2 = 0;
#pragma unroll 4
    for (int i = 0; i < 64; ++i) {
        const int n = part * 4 + i * 32;
        const float4 xx = *(const float4*)&rpx[n];
        const float4 yy = *(const float4*)&rpy[n];
        const float4 zz = *(const float4*)&rpz[n];
        float dd[4];
        {
            const float dx = qx - xx.x, dy = qy - yy.x, dz = qz - zz.x;
            dd[0] = dx * dx + dy * dy + dz * dz;
        }
        {
            const float dx = qx - xx.y, dy = qy - yy.y, dz = qz - zz.y;
            dd[1] = dx * dx + dy * dy + dz * dz;
        }
        {
            const float dx = qx - xx.z, dy = qy - yy.z, dz = qz - zz.z;
            dd[2] = dx * dx + dy * dy + dz * dz;
        }
        {
            const float dx = qx - xx.w, dy = qy - yy.w, dz = qz - zz.w;
            dd[3] = dx * dx + dy * dy + dz * dz;
        }
        ins3(dd[0], n + 0, d0, i0, d1, i1, d2, i2);
        ins3(dd[1], n + 1, d0, i0, d1, i1, d2, i2);
        ins3(dd[2], n + 2, d0, i0, d1, i1, d2, i2);
        ins3(dd[3], n + 3, d0, i0, d1, i1, d2, i2);
    }

    // merge top-3 across the 8 lanes of this query (xor 1, 2, 4)
#pragma unroll
    for (int xm = 1; xm <= 4; xm <<= 1) {
        const float od0 = __shfl_xor(d0, xm), od1 = __shfl_xor(d1, xm), od2 = __shfl_xor(d2, xm);
        const int   oi0 = __shfl_xor(i0, xm), oi1 = __shfl_xor(i1, xm), oi2 = __shfl_xor(i2, xm);
        ins3(od0, oi0, d0, i0, d1, i1, d2, i2);
        ins3(od1, oi1, d0, i0, d1, i1, d2, i2);
        ins3(od2, oi2, d0, i0, d1, i1, d2, i2);
    }

    if (part == 0) {
        const float r0 = 1.0f / (sqrtf(d0) + 1e-8f);
        const float r1 = 1.0f / (sqrtf(d1) + 1e-8f);
        const float r2 = 1.0f / (sqrtf(d2) + 1e-8f);
        const float inv = 1.0f / (r0 + r1 + r2);
        const size_t o = ((size_t)b * M_ + m) * 3;
        idx_out[o] = i0; idx_out[o + 1] = i1; idx_out[o + 2] = i2;
        w_out[o] = r0 * inv; w_out[o + 1] = r1 * inv; w_out[o + 2] = r2 * inv;
    }
}

// ---------------------------------------------------------------------------
// x [b][c][n] f32 -> xT [b][n][c] bf16   (32x32 LDS tile transpose)
// ---------------------------------------------------------------------------
__global__ __launch_bounds__(256) void transpose_x(const float* __restrict__ x,
                                                   u16* __restrict__ xT) {
    __shared__ float t[32][33];
    const int tx = threadIdx.x & 31, ty = threadIdx.x >> 5;   // ty 0..7
    const int n0 = blockIdx.x * 32, c0 = blockIdx.y * 32, b = blockIdx.z;
#pragma unroll
    for (int r = 0; r < 4; ++r) {
        const int c = c0 + ty + r * 8;
        t[ty + r * 8][tx] = x[((size_t)b * C_ + c) * N_ + n0 + tx];
    }
    __syncthreads();
#pragma unroll
    for (int r = 0; r < 4; ++r) {
        const int n = n0 + ty + r * 8;
        xT[((size_t)b * N_ + n) * C_ + c0 + tx] = f2bf(t[tx][ty + r * 8]);
    }
}

// ---------------------------------------------------------------------------
// x_skip [b][c][m] f32 -> Feats[b*M+m][512+c] bf16
// ---------------------------------------------------------------------------
__global__ __launch_bounds__(256) void feats_skip(const float* __restrict__ xs,
                                                  u16* __restrict__ Feats) {
    __shared__ float t[32][33];
    const int tx = threadIdx.x & 31, ty = threadIdx.x >> 5;
    const int m0 = blockIdx.x * 32, c0 = blockIdx.y * 32, b = blockIdx.z;
#pragma unroll
    for (int r = 0; r < 4; ++r) {
        const int c = c0 + ty + r * 8;
        t[ty + r * 8][tx] = xs[((size_t)b * CSK + c) * M_ + m0 + tx];
    }
    __syncthreads();
#pragma unroll
    for (int r = 0; r < 4; ++r) {
        const int m = m0 + ty + r * 8;
        Feats[((size_t)b * M_ + m) * CIN + C_ + c0 + tx] = f2bf(t[tx][ty + r * 8]);
    }
}

// ---------------------------------------------------------------------------
// Feats[col][0..511] = sum_k w[k] * xT[b][idx_k][:]   (wave reads full rows)
// grid (M_/64, B_), block 256 (4 waves, 16 m's each)
// ---------------------------------------------------------------------------
__device__ inline unsigned interp_pk(unsigned a, unsigned b, unsigned c,
                                     float w0, float w1, float w2) {
    const float lo = w0 * bflo(a) + w1 * bflo(b) + w2 * bflo(c);
    const float hi = w0 * bfhi(a) + w1 * bfhi(b) + w2 * bfhi(c);
    return (unsigned)f2bf(lo) | ((unsigned)f2bf(hi) << 16);
}
__global__ __launch_bounds__(256) void feats_interp(const u16* __restrict__ xT,
                                                    const int* __restrict__ idx,
                                                    const float* __restrict__ w,
                                                    u16* __restrict__ Feats) {
    const int b = blockIdx.y;
    const int lane = threadIdx.x & 63, wv = threadIdx.x >> 6;
    for (int t = 0; t < 16; ++t) {
        const int m = blockIdx.x * 64 + wv * 16 + t;
        const size_t col = (size_t)b * M_ + m;
        const int i0 = idx[col * 3], i1 = idx[col * 3 + 1], i2 = idx[col * 3 + 2];
        const float w0 = w[col * 3], w1 = w[col * 3 + 1], w2 = w[col * 3 + 2];
        const uint4 a = *(const uint4*)(xT + ((size_t)b * N_ + i0) * C_ + lane * 8);
        const uint4 c = *(const uint4*)(xT + ((size_t)b * N_ + i1) * C_ + lane * 8);
        const uint4 d = *(const uint4*)(xT + ((size_t)b * N_ + i2) * C_ + lane * 8);
        uint4 r;
        r.x = interp_pk(a.x, c.x, d.x, w0, w1, w2);
        r.y = interp_pk(a.y, c.y, d.y, w0, w1, w2);
        r.z = interp_pk(a.z, c.z, d.z, w0, w1, w2);
        r.w = interp_pk(a.w, c.w, d.w, w0, w1, w2);
        *(uint4*)(Feats + col * CIN + lane * 8) = r;
    }
}

// ---------------------------------------------------------------------------
// MFMA GEMM, m97 structure: 128x128 tile, BK=32, 4 waves, global_load_lds w16.
// A [Mdim][K] bf16 (stride LD), B [Ndim][K] bf16 (stride LD).
// SWAP=true : D stored transposed as bf16 C[col][o], ldc = H1C (for H1^T)
// SWAP=false: D stored f32 into out[b][p][m] (col = b*M_+m)
// ---------------------------------------------------------------------------
__device__ inline void stage_tile(u16* lds, const u16* gbase, int ld,
                                  int lane, int wv) {
#pragma unroll
    for (int jj = 0; jj < 2; ++jj) {
        const int chunk = jj * 4 + wv;                 // 0..7, 1KB each
        const int row = chunk * 16 + (lane >> 2);      // 0..127
        const int bir = (lane & 3) * 16;               // byte in 64B row
        const char* g = (const char*)gbase + (size_t)row * (ld * 2) + bir;
        __builtin_amdgcn_global_load_lds(
            (const __attribute__((address_space(1))) void*)g,
            (__attribute__((address_space(3))) void*)((char*)lds + chunk * 1024),
            16, 0, 0);
    }
}

template<int KTOT, int LD, bool SWAP>
__global__ __launch_bounds__(256) void mfma_gemm(const u16* __restrict__ A,
                                                 const u16* __restrict__ Bm,
                                                 void* __restrict__ Cout) {
    __shared__ __attribute__((aligned(16))) u16 As[128 * 32];
    __shared__ __attribute__((aligned(16))) u16 Bs[128 * 32];
    const int tid = threadIdx.x;
    const int lane = tid & 63, wv = tid >> 6;
    const int wr = wv >> 1, wc = wv & 1;
    const int l15 = lane & 15, l4 = lane >> 4;
    const int rowM0 = blockIdx.y * 128, colN0 = blockIdx.x * 128;
    f32x4 acc[4][4] = {};
    const u16* Ab = A  + (size_t)rowM0 * LD;
    const u16* Bb = Bm + (size_t)colN0 * LD;

    for (int k0 = 0; k0 < KTOT; k0 += 32) {
        stage_tile(As, Ab + k0, LD, lane, wv);
        stage_tile(Bs, Bb + k0, LD, lane, wv);
        __syncthreads();
        s16x8 af[4], bfr[4];
#pragma unroll
        for (int i = 0; i < 4; ++i)
            af[i] = *(const s16x8*)&As[(wr * 64 + i * 16 + l15) * 32 + l4 * 8];
#pragma unroll
        for (int j = 0; j < 4; ++j)
            bfr[j] = *(const s16x8*)&Bs[(wc * 64 + j * 16 + l15) * 32 + l4 * 8];
#pragma unroll
        for (int i = 0; i < 4; ++i)
#pragma unroll
            for (int j = 0; j < 4; ++j) {
                if constexpr (SWAP)
                    acc[i][j] = __builtin_amdgcn_mfma_f32_16x16x32_bf16(bfr[j], af[i], acc[i][j], 0, 0, 0);
                else
                    acc[i][j] = __builtin_amdgcn_mfma_f32_16x16x32_bf16(af[i], bfr[j], acc[i][j], 0, 0, 0);
            }
        __syncthreads();
    }

    if constexpr (SWAP) {
        // D[col][o] -> H1^T bf16 [NCOL][H1C]
        u16* C = (u16*)Cout;
#pragma unroll
        for (int i = 0; i < 4; ++i) {
            const int o = rowM0 + wr * 64 + i * 16 + l15;
#pragma unroll
            for (int j = 0; j < 4; ++j) {
                const int colb = colN0 + wc * 64 + j * 16 + l4 * 4;
#pragma unroll
                for (int r = 0; r < 4; ++r)
                    C[(size_t)(colb + r) * H1C + o] = f2bf(acc[i][j][r]);
            }
        }
    } else {
        // D[p][col] -> out f32 [B][H2C][M]
        float* C = (float*)Cout;
#pragma unroll
        for (int j = 0; j < 4; ++j) {
            const int colj = colN0 + wc * 64 + j * 16;
            const int b = colj >> 13, mm = colj & (M_ - 1);
            float* base = C + (size_t)b * (H2C * M_) + mm + l15;
#pragma unroll
            for (int i = 0; i < 4; ++i) {
                const int p = rowM0 + wr * 64 + i * 16 + l4 * 4;
#pragma unroll
                for (int r = 0; r < 4; ++r)
                    base[(size_t)(p + r) * M_] = acc[i][j][r];
            }
        }
    }
}

// ---------------------------------------------------------------------------
// BN1 stats, stage 1: partial sums over col-chunks of H1^T [NCOL][512] bf16.
// ---------------------------------------------------------------------------
__global__ __launch_bounds__(256) void bn1_partial(const u16* __restrict__ H1,
                                                   float* __restrict__ ps,
                                                   float* __restrict__ pq) {
    const int lane = threadIdx.x & 63, wv = threadIdx.x >> 6;
    float s[8] = {0.f}, q[8] = {0.f};
    for (int cc = wv; cc < 512; cc += 4) {
        const size_t col = (size_t)blockIdx.x * 512 + cc;
        const uint4 v = *(const uint4*)(H1 + col * H1C + lane * 8);
        const unsigned u[4] = {v.x, v.y, v.z, v.w};
#pragma unroll
        for (int e = 0; e < 4; ++e) {
            const float f0 = bflo(u[e]), f1 = bfhi(u[e]);
            s[e * 2] += f0;  q[e * 2] += f0 * f0;
            s[e * 2 + 1] += f1; q[e * 2 + 1] += f1 * f1;
        }
    }
    __shared__ float ls[4][512], lq[4][512];
#pragma unroll
    for (int e = 0; e < 8; ++e) { ls[wv][lane * 8 + e] = s[e]; lq[wv][lane * 8 + e] = q[e]; }
    __syncthreads();
    for (int o = threadIdx.x; o < 512; o += 256) {
        const float S = ls[0][o] + ls[1][o] + ls[2][o] + ls[3][o];
        const float Q = lq[0][o] + lq[1][o] + lq[2][o] + lq[3][o];
        ps[(size_t)blockIdx.x * 512 + o] = S;
        pq[(size_t)blockIdx.x * 512 + o] = Q;
    }
}

__global__ __launch_bounds__(256) void bn1_final(const float* __restrict__ ps,
                                                 const float* __restrict__ pq,
                                                 const float* __restrict__ gamma,
                                                 const float* __restrict__ beta,
                                                 float* __restrict__ sc,
                                                 float* __restrict__ sh) {
    for (int o = threadIdx.x; o < 512; o += 256) {
        float S = 0.f, Q = 0.f;
        for (int p = 0; p < 128; ++p) { S += ps[p * 512 + o]; Q += pq[p * 512 + o]; }
        const float mean = S * (1.0f / NCOL);
        const float var  = fmaxf(Q * (1.0f / NCOL) - mean * mean, 0.f);
        const float is   = rsqrtf(var + 1e-5f);
        const float s    = gamma[o] * is;
        sc[o] = s;
        sh[o] = beta[o] - mean * s;
    }
}

// ---------------------------------------------------------------------------
// In-place BN1 affine + leaky on H1^T (bf16)
// ---------------------------------------------------------------------------
__global__ __launch_bounds__(256) void bn1_apply(u16* __restrict__ H1,
                                                 const float* __restrict__ sc,
                                                 const float* __restrict__ sh) {
    const size_t g = (size_t)blockIdx.x * 256 + threadIdx.x;
    const int og = (int)(g & 63) * 8;
    const size_t col = g >> 6;
    u16* p = H1 + col * H1C + og;
    uint4 v = *(const uint4*)p;
    unsigned u[4] = {v.x, v.y, v.z, v.w};
    const float4 s0 = *(const float4*)(sc + og), s1 = *(const float4*)(sc + og + 4);
    const float4 h0 = *(const float4*)(sh + og), h1 = *(const float4*)(sh + og + 4);
    const float scv[8] = {s0.x, s0.y, s0.z, s0.w, s1.x, s1.y, s1.z, s1.w};
    const float shv[8] = {h0.x, h0.y, h0.z, h0.w, h1.x, h1.y, h1.z, h1.w};
    unsigned r[4];
#pragma unroll
    for (int e = 0; e < 4; ++e) {
        float f0 = fmaf(bflo(u[e]), scv[e * 2], shv[e * 2]);
        float f1 = fmaf(bfhi(u[e]), scv[e * 2 + 1], shv[e * 2 + 1]);
        f0 = f0 >= 0.f ? f0 : 0.2f * f0;
        f1 = f1 >= 0.f ? f1 : 0.2f * f1;
        r[e] = (unsigned)f2bf(f0) | ((unsigned)f2bf(f1) << 16);
    }
    *(uint4*)p = make_uint4(r[0], r[1], r[2], r[3]);
}

// ---------------------------------------------------------------------------
// BN2 stats + apply on d_out [B][H2C][M] f32
// ---------------------------------------------------------------------------
__global__ __launch_bounds__(256) void bn_stats2(const float* __restrict__ raw,
                                                 const float* __restrict__ gamma,
                                                 const float* __restrict__ beta,
                                                 float* __restrict__ scale,
                                                 float* __restrict__ shift) {
    const int c = blockIdx.x;
    float s = 0.f, q = 0.f;
    for (int t = threadIdx.x; t < NCOL; t += 256) {
        const int bb = t >> 13;
        const int mm = t & (M_ - 1);
        const float v = raw[(size_t)bb * (H2C * M_) + (size_t)c * M_ + mm];
        s += v; q += v * v;
    }
    __shared__ float rs[256], rq[256];
    rs[threadIdx.x] = s; rq[threadIdx.x] = q;
    __syncthreads();
    for (int st = 128; st > 0; st >>= 1) {
        if (threadIdx.x < st) {
            rs[threadIdx.x] += rs[threadIdx.x + st];
            rq[threadIdx.x] += rq[threadIdx.x + st];
        }
        __syncthreads();
    }
    if (threadIdx.x == 0) {
        const float mean = rs[0] * (1.0f / NCOL);
        const float var  = fmaxf(rq[0] * (1.0f / NCOL) - mean * mean, 0.f);
        const float is   = rsqrtf(var + 1e-5f);
        const float sc   = gamma[c] * is;
        scale[c] = sc;
        shift[c] = beta[c] - mean * sc;
    }
}

__global__ __launch_bounds__(256) void bn_apply2(float* __restrict__ out,
                                                 const float* __restrict__ sc,
                                                 const float* __restrict__ sh) {
    const size_t i = (size_t)blockIdx.x * 256 + threadIdx.x;
    const int p = (int)((i >> 13) & (H2C - 1));
    float v = out[i];
    v = fmaf(v, sc[p], sh[p]);
    out[i] = v >= 0.f ? v : 0.2f * v;
}

// ---------------------------------------------------------------------------
extern "C" void kernel_launch(void* const* d_in, const int* in_sizes, int n_in,
                              void* d_out, int out_size, void* d_ws, size_t ws_size,
                              hipStream_t stream) {
    const float* pos      = (const float*)d_in[0];
    const float* pos_skip = (const float*)d_in[1];
    const float* x        = (const float*)d_in[2];
    const float* x_skip   = (const float*)d_in[3];
    const float* W1       = (const float*)d_in[4];
    const float* gamma1   = (const float*)d_in[5];
    const float* beta1    = (const float*)d_in[6];
    const float* W2       = (const float*)d_in[7];
    const float* gamma2   = (const float*)d_in[8];
    const float* beta2    = (const float*)d_in[9];
    float* out = (float*)d_out;

    char* ws = (char*)d_ws;
    size_t off = 0;
    auto alloc = [&](size_t bytes) {
        void* p = ws + off;
        off = (off + bytes + 255) & ~(size_t)255;
        return p;
    };
    int*   idx   = (int*)  alloc((size_t)NCOL * 3 * sizeof(int));
    float* w     = (float*)alloc((size_t)NCOL * 3 * sizeof(float));
    u16*   xT    = (u16*)  alloc((size_t)B_ * N_ * C_ * sizeof(u16));     // 16.8 MB
    u16*   W1b   = (u16*)  alloc((size_t)H1C * CIN * sizeof(u16));
    u16*   W2b   = (u16*)  alloc((size_t)H2C * H1C * sizeof(u16));
    u16*   Feats = (u16*)  alloc((size_t)NCOL * CIN * sizeof(u16));       // 100.7 MB
    u16*   H1    = (u16*)  alloc((size_t)NCOL * H1C * sizeof(u16));       // 67.1 MB
    float* ps    = (float*)alloc(128 * 512 * sizeof(float));
    float* pq    = (float*)alloc(128 * 512 * sizeof(float));
    float* sc1   = (float*)alloc(H1C * sizeof(float));
    float* sh1   = (float*)alloc(H1C * sizeof(float));
    float* sc2   = (float*)alloc(H2C * sizeof(float));
    float* sh2   = (float*)alloc(H2C * sizeof(float));

    cvt_bf16_k<<<(H1C * CIN / 4 + 255) / 256, 256, 0, stream>>>(W1, W1b, H1C * CIN / 4);
    cvt_bf16_k<<<(H2C * H1C / 4 + 255) / 256, 256, 0, stream>>>(W2, W2b, H2C * H1C / 4);
    knn_kernel<<<dim3(M_ / 32, B_), 256, 0, stream>>>(pos, pos_skip, idx, w);
    transpose_x<<<dim3(N_ / 32, C_ / 32, B_), 256, 0, stream>>>(x, xT);
    feats_interp<<<dim3(M_ / 64, B_), 256, 0, stream>>>(xT, idx, w, Feats);
    feats_skip<<<dim3(M_ / 32, CSK / 32, B_), 256, 0, stream>>>(x_skip, Feats);
    // GEMM1: H1^T[col][o] = Feats[col][:] . W1b[o][:]   (swapped-store MFMA)
    mfma_gemm<CIN, CIN, true><<<dim3(NCOL / 128, H1C / 128), 256, 0, stream>>>(W1b, Feats, H1);
    bn1_partial<<<128, 256, 0, stream>>>(H1, ps, pq);
    bn1_final<<<1, 256, 0, stream>>>(ps, pq, gamma1, beta1, sc1, sh1);
    bn1_apply<<<(int)(((size_t)NCOL * H1C / 8) / 256), 256, 0, stream>>>(H1, sc1, sh1);
    // GEMM2: out[b][p][m] = W2b[p][:] . H1act^T[col][:]
    mfma_gemm<H1C, H1C, false><<<dim3(NCOL / 128, H2C / 128), 256, 0, stream>>>(W2b, H1, out);
    bn_stats2<<<H2C, 256, 0, stream>>>(out, gamma2, beta2, sc2, sh2);
    bn_apply2<<<(int)(((size_t)NCOL * H2C) / 256), 256, 0, stream>>>(out, sc2, sh2);
}

// Round 7
// 331.217 us; speedup vs baseline: 3.6479x; 1.3315x over previous
//
#include <hip/hip_runtime.h>
#include <stdint.h>

// Problem constants
#define B_    8
#define N_    2048
#define M_    8192
#define C_    512
#define CSK   256
#define CIN   768
#define H1C   512
#define H2C   256
#define NCOL  65536     // B_*M_
typedef unsigned short u16;
typedef __attribute__((ext_vector_type(8))) short  s16x8;
typedef __attribute__((ext_vector_type(4))) float  f32x4;

// ---- bf16 helpers (RNE) ----
__device__ inline u16 f2bf(float f) {
    unsigned u = __float_as_uint(f);
    unsigned r = (u + 0x7fffu + ((u >> 16) & 1u)) >> 16;
    return (u16)r;
}
__device__ inline float bflo(unsigned u) { return __uint_as_float(u << 16); }
__device__ inline float bfhi(unsigned u) { return __uint_as_float(u & 0xffff0000u); }

// ---------------------------------------------------------------------------
// f32 -> bf16 bulk convert
// ---------------------------------------------------------------------------
__global__ __launch_bounds__(256) void cvt_bf16_k(const float* __restrict__ in,
                                                  u16* __restrict__ out, int n4) {
    const int i = blockIdx.x * 256 + threadIdx.x;
    if (i >= n4) return;
    const float4 v = *(const float4*)(in + (size_t)i * 4);
    u16 o[4] = {f2bf(v.x), f2bf(v.y), f2bf(v.z), f2bf(v.w)};
    *(uint2*)(out + (size_t)i * 4) = *(uint2*)o;
}

// ---------------------------------------------------------------------------
// 3-NN: 8 lanes/query, interleaved bank-conflict-free partition, branchless
// insert (round-6 version, validated).
// ---------------------------------------------------------------------------
__device__ inline void ins3(float d, int n,
                            float& d0, int& i0, float& d1, int& i1,
                            float& d2, int& i2) {
    const bool lt0 = d < d0, lt1 = d < d1, lt2 = d < d2;
    const float nd2 = lt1 ? d1 : (lt2 ? d : d2);
    const int   ni2 = lt1 ? i1 : (lt2 ? n : i2);
    const float nd1 = lt0 ? d0 : (lt1 ? d : d1);
    const int   ni1 = lt0 ? i0 : (lt1 ? n : i1);
    const float nd0 = lt0 ? d : d0;
    const int   ni0 = lt0 ? n : i0;
    d0 = nd0; d1 = nd1; d2 = nd2; i0 = ni0; i1 = ni1; i2 = ni2;
}

__global__ __launch_bounds__(256) void knn_kernel(const float* __restrict__ pos,
                                                  const float* __restrict__ pos_skip,
                                                  int* __restrict__ idx_out,
                                                  float* __restrict__ w_out) {
    __shared__ float rpx[N_], rpy[N_], rpz[N_];
    const int b = blockIdx.y;
    const int tid = threadIdx.x;
    for (int t = tid; t < N_ * 3; t += 256) {
        const float v = pos[(size_t)b * N_ * 3 + t];
        const int n = t / 3, k = t - n * 3;
        if (k == 0) rpx[n] = v; else if (k == 1) rpy[n] = v; else rpz[n] = v;
    }
    __syncthreads();

    const int q = tid >> 3;
    const int part = tid & 7;
    const int m = blockIdx.x * 32 + q;
    const size_t qoff = ((size_t)b * M_ + m) * 3;
    const float qx = pos_skip[qoff], qy = pos_skip[qoff + 1], qz = pos_skip[qoff + 2];

    float d0 = 1e30f, d1 = 1e30f, d2 = 1e30f;
    int i0 = 0, i1 = 0, i2 = 0;
#pragma unroll 4
    for (int i = 0; i < 64; ++i) {
        const int n = part * 4 + i * 32;
        const float4 xx = *(const float4*)&rpx[n];
        const float4 yy = *(const float4*)&rpy[n];
        const float4 zz = *(const float4*)&rpz[n];
        float dd[4];
        {
            const float dx = qx - xx.x, dy = qy - yy.x, dz = qz - zz.x;
            dd[0] = dx * dx + dy * dy + dz * dz;
        }
        {
            const float dx = qx - xx.y, dy = qy - yy.y, dz = qz - zz.y;
            dd[1] = dx * dx + dy * dy + dz * dz;
        }
        {
            const float dx = qx - xx.z, dy = qy - yy.z, dz = qz - zz.z;
            dd[2] = dx * dx + dy * dy + dz * dz;
        }
        {
            const float dx = qx - xx.w, dy = qy - yy.w, dz = qz - zz.w;
            dd[3] = dx * dx + dy * dy + dz * dz;
        }
        ins3(dd[0], n + 0, d0, i0, d1, i1, d2, i2);
        ins3(dd[1], n + 1, d0, i0, d1, i1, d2, i2);
        ins3(dd[2], n + 2, d0, i0, d1, i1, d2, i2);
        ins3(dd[3], n + 3, d0, i0, d1, i1, d2, i2);
    }

#pragma unroll
    for (int xm = 1; xm <= 4; xm <<= 1) {
        const float od0 = __shfl_xor(d0, xm), od1 = __shfl_xor(d1, xm), od2 = __shfl_xor(d2, xm);
        const int   oi0 = __shfl_xor(i0, xm), oi1 = __shfl_xor(i1, xm), oi2 = __shfl_xor(i2, xm);
        ins3(od0, oi0, d0, i0, d1, i1, d2, i2);
        ins3(od1, oi1, d0, i0, d1, i1, d2, i2);
        ins3(od2, oi2, d0, i0, d1, i1, d2, i2);
    }

    if (part == 0) {
        const float r0 = 1.0f / (sqrtf(d0) + 1e-8f);
        const float r1 = 1.0f / (sqrtf(d1) + 1e-8f);
        const float r2 = 1.0f / (sqrtf(d2) + 1e-8f);
        const float inv = 1.0f / (r0 + r1 + r2);
        const size_t o = ((size_t)b * M_ + m) * 3;
        idx_out[o] = i0; idx_out[o + 1] = i1; idx_out[o + 2] = i2;
        w_out[o] = r0 * inv; w_out[o + 1] = r1 * inv; w_out[o + 2] = r2 * inv;
    }
}

// ---------------------------------------------------------------------------
// x [b][c][n] f32 -> xT [b][n][c] bf16
// ---------------------------------------------------------------------------
__global__ __launch_bounds__(256) void transpose_x(const float* __restrict__ x,
                                                   u16* __restrict__ xT) {
    __shared__ float t[32][33];
    const int tx = threadIdx.x & 31, ty = threadIdx.x >> 5;
    const int n0 = blockIdx.x * 32, c0 = blockIdx.y * 32, b = blockIdx.z;
#pragma unroll
    for (int r = 0; r < 4; ++r) {
        const int c = c0 + ty + r * 8;
        t[ty + r * 8][tx] = x[((size_t)b * C_ + c) * N_ + n0 + tx];
    }
    __syncthreads();
#pragma unroll
    for (int r = 0; r < 4; ++r) {
        const int n = n0 + ty + r * 8;
        xT[((size_t)b * N_ + n) * C_ + c0 + tx] = f2bf(t[tx][ty + r * 8]);
    }
}

// ---------------------------------------------------------------------------
// x_skip -> Feats[:, 512:768]
// ---------------------------------------------------------------------------
__global__ __launch_bounds__(256) void feats_skip(const float* __restrict__ xs,
                                                  u16* __restrict__ Feats) {
    __shared__ float t[32][33];
    const int tx = threadIdx.x & 31, ty = threadIdx.x >> 5;
    const int m0 = blockIdx.x * 32, c0 = blockIdx.y * 32, b = blockIdx.z;
#pragma unroll
    for (int r = 0; r < 4; ++r) {
        const int c = c0 + ty + r * 8;
        t[ty + r * 8][tx] = xs[((size_t)b * CSK + c) * M_ + m0 + tx];
    }
    __syncthreads();
#pragma unroll
    for (int r = 0; r < 4; ++r) {
        const int m = m0 + ty + r * 8;
        Feats[((size_t)b * M_ + m) * CIN + C_ + c0 + tx] = f2bf(t[tx][ty + r * 8]);
    }
}

// ---------------------------------------------------------------------------
// 3-NN interpolation -> Feats[:, 0:512]
// ---------------------------------------------------------------------------
__device__ inline unsigned interp_pk(unsigned a, unsigned b, unsigned c,
                                     float w0, float w1, float w2) {
    const float lo = w0 * bflo(a) + w1 * bflo(b) + w2 * bflo(c);
    const float hi = w0 * bfhi(a) + w1 * bfhi(b) + w2 * bfhi(c);
    return (unsigned)f2bf(lo) | ((unsigned)f2bf(hi) << 16);
}
__global__ __launch_bounds__(256) void feats_interp(const u16* __restrict__ xT,
                                                    const int* __restrict__ idx,
                                                    const float* __restrict__ w,
                                                    u16* __restrict__ Feats) {
    const int b = blockIdx.y;
    const int lane = threadIdx.x & 63, wv = threadIdx.x >> 6;
    for (int t = 0; t < 16; ++t) {
        const int m = blockIdx.x * 64 + wv * 16 + t;
        const size_t col = (size_t)b * M_ + m;
        const int i0 = idx[col * 3], i1 = idx[col * 3 + 1], i2 = idx[col * 3 + 2];
        const float w0 = w[col * 3], w1 = w[col * 3 + 1], w2 = w[col * 3 + 2];
        const uint4 a = *(const uint4*)(xT + ((size_t)b * N_ + i0) * C_ + lane * 8);
        const uint4 c = *(const uint4*)(xT + ((size_t)b * N_ + i1) * C_ + lane * 8);
        const uint4 d = *(const uint4*)(xT + ((size_t)b * N_ + i2) * C_ + lane * 8);
        uint4 r;
        r.x = interp_pk(a.x, c.x, d.x, w0, w1, w2);
        r.y = interp_pk(a.y, c.y, d.y, w0, w1, w2);
        r.z = interp_pk(a.z, c.z, d.z, w0, w1, w2);
        r.w = interp_pk(a.w, c.w, d.w, w0, w1, w2);
        *(uint4*)(Feats + col * CIN + lane * 8) = r;
    }
}

// ---------------------------------------------------------------------------
// GEMM1: H1^T[col][o] = Feats[col][:] . W1b[o][:], m97 structure 128x128,
// + fused BN1 partial sums (deterministic, per col-block) into ps1/pq1.
// A = W1b [512][768], B = Feats [NCOL][768]. grid (NCOL/128, H1C/128)=(512,4)
// ---------------------------------------------------------------------------
__device__ inline void stage_tile(u16* lds, const u16* gbase, int ld,
                                  int lane, int wv) {
#pragma unroll
    for (int jj = 0; jj < 2; ++jj) {
        const int chunk = jj * 4 + wv;
        const int row = chunk * 16 + (lane >> 2);
        const int bir = (lane & 3) * 16;
        const char* g = (const char*)gbase + (size_t)row * (ld * 2) + bir;
        __builtin_amdgcn_global_load_lds(
            (const __attribute__((address_space(1))) void*)g,
            (__attribute__((address_space(3))) void*)((char*)lds + chunk * 1024),
            16, 0, 0);
    }
}

__global__ __launch_bounds__(256) void gemm1(const u16* __restrict__ A,
                                             const u16* __restrict__ Bm,
                                             u16* __restrict__ H1,
                                             float* __restrict__ ps1,
                                             float* __restrict__ pq1) {
    __shared__ __attribute__((aligned(16))) u16 As[128 * 32];
    __shared__ __attribute__((aligned(16))) u16 Bs[128 * 32];
    __shared__ float lsum[2][128], lsq[2][128];
    const int tid = threadIdx.x;
    const int lane = tid & 63, wv = tid >> 6;
    const int wr = wv >> 1, wc = wv & 1;
    const int l15 = lane & 15, l4 = lane >> 4;
    const int rowM0 = blockIdx.y * 128, colN0 = blockIdx.x * 128;
    f32x4 acc[4][4] = {};
    const u16* Ab = A  + (size_t)rowM0 * CIN;
    const u16* Bb = Bm + (size_t)colN0 * CIN;

    for (int k0 = 0; k0 < CIN; k0 += 32) {
        stage_tile(As, Ab + k0, CIN, lane, wv);
        stage_tile(Bs, Bb + k0, CIN, lane, wv);
        __syncthreads();
        s16x8 af[4], bfr[4];
#pragma unroll
        for (int i = 0; i < 4; ++i)
            af[i] = *(const s16x8*)&As[(wr * 64 + i * 16 + l15) * 32 + l4 * 8];
#pragma unroll
        for (int j = 0; j < 4; ++j)
            bfr[j] = *(const s16x8*)&Bs[(wc * 64 + j * 16 + l15) * 32 + l4 * 8];
#pragma unroll
        for (int i = 0; i < 4; ++i)
#pragma unroll
            for (int j = 0; j < 4; ++j)
                acc[i][j] = __builtin_amdgcn_mfma_f32_16x16x32_bf16(bfr[j], af[i], acc[i][j], 0, 0, 0);
        __syncthreads();
    }

    // store H1^T (bf16) ; D row (lane>>4)*4+reg = col, D col l15 = o
#pragma unroll
    for (int i = 0; i < 4; ++i) {
        const int o = rowM0 + wr * 64 + i * 16 + l15;
#pragma unroll
        for (int j = 0; j < 4; ++j) {
            const int colb = colN0 + wc * 64 + j * 16 + l4 * 4;
#pragma unroll
            for (int r = 0; r < 4; ++r)
                H1[(size_t)(colb + r) * H1C + o] = f2bf(acc[i][j][r]);
        }
    }

    // BN1 partials over this block's 128 cols (f32, deterministic)
#pragma unroll
    for (int i = 0; i < 4; ++i) {
        float s = 0.f, q = 0.f;
#pragma unroll
        for (int j = 0; j < 4; ++j)
#pragma unroll
            for (int r = 0; r < 4; ++r) {
                const float v = acc[i][j][r];
                s += v; q += v * v;
            }
        s += __shfl_xor(s, 16); q += __shfl_xor(q, 16);
        s += __shfl_xor(s, 32); q += __shfl_xor(q, 32);
        if ((lane & 48) == 0) {
            lsum[wc][wr * 64 + i * 16 + l15] = s;
            lsq [wc][wr * 64 + i * 16 + l15] = q;
        }
    }
    __syncthreads();
    if (tid < 128) {
        const float S = lsum[0][tid] + lsum[1][tid];
        const float Q = lsq[0][tid] + lsq[1][tid];
        ps1[(size_t)(rowM0 + tid) * 512 + blockIdx.x] = S;
        pq1[(size_t)(rowM0 + tid) * 512 + blockIdx.x] = Q;
    }
}

// ---------------------------------------------------------------------------
// BN1 final: reduce 512 col-block partials per channel -> scale/shift
// ---------------------------------------------------------------------------
__global__ __launch_bounds__(256) void bn1_final(const float* __restrict__ ps,
                                                 const float* __restrict__ pq,
                                                 const float* __restrict__ gamma,
                                                 const float* __restrict__ beta,
                                                 float* __restrict__ sc,
                                                 float* __restrict__ sh) {
    const int o = blockIdx.x;
    const int t = threadIdx.x;
    float S = ps[(size_t)o * 512 + t] + ps[(size_t)o * 512 + 256 + t];
    float Q = pq[(size_t)o * 512 + t] + pq[(size_t)o * 512 + 256 + t];
    __shared__ float rs[256], rq[256];
    rs[t] = S; rq[t] = Q;
    __syncthreads();
    for (int st = 128; st > 0; st >>= 1) {
        if (t < st) { rs[t] += rs[t + st]; rq[t] += rq[t + st]; }
        __syncthreads();
    }
    if (t == 0) {
        const float mean = rs[0] * (1.0f / NCOL);
        const float var  = fmaxf(rq[0] * (1.0f / NCOL) - mean * mean, 0.f);
        const float is   = rsqrtf(var + 1e-5f);
        const float s    = gamma[o] * is;
        sc[o] = s;
        sh[o] = beta[o] - mean * s;
    }
}

// ---------------------------------------------------------------------------
// In-place BN1 affine + leaky on H1^T (bf16)
// ---------------------------------------------------------------------------
__global__ __launch_bounds__(256) void bn1_apply(u16* __restrict__ H1,
                                                 const float* __restrict__ sc,
                                                 const float* __restrict__ sh) {
    const size_t g = (size_t)blockIdx.x * 256 + threadIdx.x;
    const int og = (int)(g & 63) * 8;
    const size_t col = g >> 6;
    u16* p = H1 + col * H1C + og;
    uint4 v = *(const uint4*)p;
    unsigned u[4] = {v.x, v.y, v.z, v.w};
    const float4 s0 = *(const float4*)(sc + og), s1 = *(const float4*)(sc + og + 4);
    const float4 h0 = *(const float4*)(sh + og), h1 = *(const float4*)(sh + og + 4);
    const float scv[8] = {s0.x, s0.y, s0.z, s0.w, s1.x, s1.y, s1.z, s1.w};
    const float shv[8] = {h0.x, h0.y, h0.z, h0.w, h1.x, h1.y, h1.z, h1.w};
    unsigned r[4];
#pragma unroll
    for (int e = 0; e < 4; ++e) {
        float f0 = fmaf(bflo(u[e]), scv[e * 2], shv[e * 2]);
        float f1 = fmaf(bfhi(u[e]), scv[e * 2 + 1], shv[e * 2 + 1]);
        f0 = f0 >= 0.f ? f0 : 0.2f * f0;
        f1 = f1 >= 0.f ? f1 : 0.2f * f1;
        r[e] = (unsigned)f2bf(f0) | ((unsigned)f2bf(f1) << 16);
    }
    *(uint4*)p = make_uint4(r[0], r[1], r[2], r[3]);
}

// ---------------------------------------------------------------------------
// GEMM2: out[b][p][m] = W2b[p][:] . H1act^T[col][:]
// 512 threads (8 waves), tile 256p x 256col, K=512, BK=32, double-buffered
// 2-phase staging; float4 stores along m; fused BN2 partials -> ps2/pq2.
// grid NCOL/256 = 256 blocks.
// ---------------------------------------------------------------------------
__device__ inline void stage2(char* ldsbase, const u16* gsrc, int k0,
                              int lane, int wv) {
#pragma unroll
    for (int h = 0; h < 2; ++h) {
        const int p_loc = h * 128 + wv * 16 + (lane >> 2);
        const u16* g = gsrc + (size_t)p_loc * H1C + k0 + (lane & 3) * 8;
        __builtin_amdgcn_global_load_lds(
            (const __attribute__((address_space(1))) void*)g,
            (__attribute__((address_space(3))) void*)(ldsbase + (h * 512 + wv * 64) * 16),
            16, 0, 0);
    }
}

__global__ __launch_bounds__(512, 2) void gemm2(const u16* __restrict__ W2b,
                                                const u16* __restrict__ H1,
                                                float* __restrict__ out,
                                                float* __restrict__ ps2,
                                                float* __restrict__ pq2) {
    __shared__ __attribute__((aligned(16))) u16 As[2][256 * 32];
    __shared__ __attribute__((aligned(16))) u16 Bs[2][256 * 32];
    __shared__ float lsum[4][256], lsq[4][256];
    const int tid = threadIdx.x;
    const int lane = tid & 63, wv = tid >> 6;
    const int pgrp = wv & 1, cgrp = wv >> 1;      // 2 p-halves x 4 col-quarters
    const int l15 = lane & 15, l4 = lane >> 4;
    const int col0 = blockIdx.x * 256;
    const u16* Hb = H1 + (size_t)col0 * H1C;
    f32x4 acc[4][8] = {};

    stage2((char*)As[0], W2b, 0, lane, wv);
    stage2((char*)Bs[0], Hb, 0, lane, wv);
    __syncthreads();

    int cur = 0;
    for (int step = 0; step < 16; ++step) {
        if (step < 15) {
            stage2((char*)As[cur ^ 1], W2b, (step + 1) * 32, lane, wv);
            stage2((char*)Bs[cur ^ 1], Hb, (step + 1) * 32, lane, wv);
        }
        const u16* Ac = As[cur];
        const u16* Bc = Bs[cur];
        s16x8 af[8], bfr[4];
#pragma unroll
        for (int pf = 0; pf < 8; ++pf)
            af[pf] = *(const s16x8*)&Ac[(pgrp * 128 + pf * 16 + l15) * 32 + l4 * 8];
#pragma unroll
        for (int cf = 0; cf < 4; ++cf)
            bfr[cf] = *(const s16x8*)&Bc[(cgrp * 64 + cf * 16 + l15) * 32 + l4 * 8];
#pragma unroll
        for (int cf = 0; cf < 4; ++cf)
#pragma unroll
            for (int pf = 0; pf < 8; ++pf)
                acc[cf][pf] = __builtin_amdgcn_mfma_f32_16x16x32_bf16(bfr[cf], af[pf], acc[cf][pf], 0, 0, 0);
        __syncthreads();   // drains stage of next buffer + all ds_reads
        cur ^= 1;
    }

    // store: D row = m (l4*4+r), D col = p (l15)  -> float4 along m
    const int bidx = col0 >> 13;
    const int mb   = col0 & (M_ - 1);
#pragma unroll
    for (int cf = 0; cf < 4; ++cf) {
#pragma unroll
        for (int pf = 0; pf < 8; ++pf) {
            const int p  = pgrp * 128 + pf * 16 + l15;
            const int mm = mb + cgrp * 64 + cf * 16 + l4 * 4;
            *(f32x4*)(out + (size_t)bidx * (H2C * M_) + (size_t)p * M_ + mm) = acc[cf][pf];
        }
    }

    // BN2 partials over this block's 256 cols (raw pre-BN2 values)
#pragma unroll
    for (int pf = 0; pf < 8; ++pf) {
        float s = 0.f, q = 0.f;
#pragma unroll
        for (int cf = 0; cf < 4; ++cf)
#pragma unroll
            for (int r = 0; r < 4; ++r) {
                const float v = acc[cf][pf][r];
                s += v; q += v * v;
            }
        s += __shfl_xor(s, 16); q += __shfl_xor(q, 16);
        s += __shfl_xor(s, 32); q += __shfl_xor(q, 32);
        if ((lane & 48) == 0) {
            lsum[cgrp][pgrp * 128 + pf * 16 + l15] = s;
            lsq [cgrp][pgrp * 128 + pf * 16 + l15] = q;
        }
    }
    __syncthreads();
    if (tid < 256) {
        const float S = lsum[0][tid] + lsum[1][tid] + lsum[2][tid] + lsum[3][tid];
        const float Q = lsq[0][tid] + lsq[1][tid] + lsq[2][tid] + lsq[3][tid];
        ps2[(size_t)tid * 256 + blockIdx.x] = S;
        pq2[(size_t)tid * 256 + blockIdx.x] = Q;
    }
}

// ---------------------------------------------------------------------------
// BN2 final: reduce 256 col-block partials per channel
// ---------------------------------------------------------------------------
__global__ __launch_bounds__(256) void bn2_final(const float* __restrict__ ps,
                                                 const float* __restrict__ pq,
                                                 const float* __restrict__ gamma,
                                                 const float* __restrict__ beta,
                                                 float* __restrict__ sc,
                                                 float* __restrict__ sh) {
    const int p = blockIdx.x;
    const int t = threadIdx.x;
    float S = ps[(size_t)p * 256 + t];
    float Q = pq[(size_t)p * 256 + t];
    __shared__ float rs[256], rq[256];
    rs[t] = S; rq[t] = Q;
    __syncthreads();
    for (int st = 128; st > 0; st >>= 1) {
        if (t < st) { rs[t] += rs[t + st]; rq[t] += rq[t + st]; }
        __syncthreads();
    }
    if (t == 0) {
        const float mean = rs[0] * (1.0f / NCOL);
        const float var  = fmaxf(rq[0] * (1.0f / NCOL) - mean * mean, 0.f);
        const float is   = rsqrtf(var + 1e-5f);
        const float s    = gamma[p] * is;
        sc[p] = s;
        sh[p] = beta[p] - mean * s;
    }
}

// ---------------------------------------------------------------------------
// In-place BN2 affine + leaky on d_out
// ---------------------------------------------------------------------------
__global__ __launch_bounds__(256) void bn_apply2(float* __restrict__ out,
                                                 const float* __restrict__ sc,
                                                 const float* __restrict__ sh) {
    const size_t i = (size_t)blockIdx.x * 256 + threadIdx.x;
    const int p = (int)((i >> 13) & (H2C - 1));
    float v = out[i];
    v = fmaf(v, sc[p], sh[p]);
    out[i] = v >= 0.f ? v : 0.2f * v;
}

// ---------------------------------------------------------------------------
extern "C" void kernel_launch(void* const* d_in, const int* in_sizes, int n_in,
                              void* d_out, int out_size, void* d_ws, size_t ws_size,
                              hipStream_t stream) {
    const float* pos      = (const float*)d_in[0];
    const float* pos_skip = (const float*)d_in[1];
    const float* x        = (const float*)d_in[2];
    const float* x_skip   = (const float*)d_in[3];
    const float* W1       = (const float*)d_in[4];
    const float* gamma1   = (const float*)d_in[5];
    const float* beta1    = (const float*)d_in[6];
    const float* W2       = (const float*)d_in[7];
    const float* gamma2   = (const float*)d_in[8];
    const float* beta2    = (const float*)d_in[9];
    float* out = (float*)d_out;

    char* ws = (char*)d_ws;
    size_t off = 0;
    auto alloc = [&](size_t bytes) {
        void* p = ws + off;
        off = (off + bytes + 255) & ~(size_t)255;
        return p;
    };
    int*   idx   = (int*)  alloc((size_t)NCOL * 3 * sizeof(int));
    float* w     = (float*)alloc((size_t)NCOL * 3 * sizeof(float));
    u16*   xT    = (u16*)  alloc((size_t)B_ * N_ * C_ * sizeof(u16));
    u16*   W1b   = (u16*)  alloc((size_t)H1C * CIN * sizeof(u16));
    u16*   W2b   = (u16*)  alloc((size_t)H2C * H1C * sizeof(u16));
    u16*   Feats = (u16*)  alloc((size_t)NCOL * CIN * sizeof(u16));
    u16*   H1    = (u16*)  alloc((size_t)NCOL * H1C * sizeof(u16));
    float* ps1   = (float*)alloc((size_t)H1C * 512 * sizeof(float));
    float* pq1   = (float*)alloc((size_t)H1C * 512 * sizeof(float));
    float* ps2   = (float*)alloc((size_t)H2C * 256 * sizeof(float));
    float* pq2   = (float*)alloc((size_t)H2C * 256 * sizeof(float));
    float* sc1   = (float*)alloc(H1C * sizeof(float));
    float* sh1   = (float*)alloc(H1C * sizeof(float));
    float* sc2   = (float*)alloc(H2C * sizeof(float));
    float* sh2   = (float*)alloc(H2C * sizeof(float));

    cvt_bf16_k<<<(H1C * CIN / 4 + 255) / 256, 256, 0, stream>>>(W1, W1b, H1C * CIN / 4);
    cvt_bf16_k<<<(H2C * H1C / 4 + 255) / 256, 256, 0, stream>>>(W2, W2b, H2C * H1C / 4);
    knn_kernel<<<dim3(M_ / 32, B_), 256, 0, stream>>>(pos, pos_skip, idx, w);
    transpose_x<<<dim3(N_ / 32, C_ / 32, B_), 256, 0, stream>>>(x, xT);
    feats_interp<<<dim3(M_ / 64, B_), 256, 0, stream>>>(xT, idx, w, Feats);
    feats_skip<<<dim3(M_ / 32, CSK / 32, B_), 256, 0, stream>>>(x_skip, Feats);
    gemm1<<<dim3(NCOL / 128, H1C / 128), 256, 0, stream>>>(W1b, Feats, H1, ps1, pq1);
    bn1_final<<<H1C, 256, 0, stream>>>(ps1, pq1, gamma1, beta1, sc1, sh1);
    bn1_apply<<<(int)(((size_t)NCOL * H1C / 8) / 256), 256, 0, stream>>>(H1, sc1, sh1);
    gemm2<<<NCOL / 256, 512, 0, stream>>>(W2b, H1, out, ps2, pq2);
    bn2_final<<<H2C, 256, 0, stream>>>(ps2, pq2, gamma2, beta2, sc2, sh2);
    bn_apply2<<<(int)(((size_t)NCOL * H2C) / 256), 256, 0, stream>>>(out, sc2, sh2);
}

// Round 10
// 302.307 us; speedup vs baseline: 3.9968x; 1.0956x over previous
//
#include <hip/hip_runtime.h>
#include <stdint.h>

// Problem constants
#define B_    8
#define N_    2048
#define M_    8192
#define C_    512
#define CSK   256
#define CIN   768
#define H1C   512
#define H2C   256
#define NCOL  65536     // B_*M_
typedef unsigned short u16;
typedef __attribute__((ext_vector_type(8))) short  s16x8;
typedef __attribute__((ext_vector_type(4))) float  f32x4;

// ---- bf16 helpers (RNE) ----
__device__ inline u16 f2bf(float f) {
    unsigned u = __float_as_uint(f);
    unsigned r = (u + 0x7fffu + ((u >> 16) & 1u)) >> 16;
    return (u16)r;
}
__device__ inline float bflo(unsigned u) { return __uint_as_float(u << 16); }
__device__ inline float bfhi(unsigned u) { return __uint_as_float(u & 0xffff0000u); }

// ---------------------------------------------------------------------------
// f32 -> bf16 bulk convert
// ---------------------------------------------------------------------------
__global__ __launch_bounds__(256) void cvt_bf16_k(const float* __restrict__ in,
                                                  u16* __restrict__ out, int n4) {
    const int i = blockIdx.x * 256 + threadIdx.x;
    if (i >= n4) return;
    const float4 v = *(const float4*)(in + (size_t)i * 4);
    u16 o[4] = {f2bf(v.x), f2bf(v.y), f2bf(v.z), f2bf(v.w)};
    *(uint2*)(out + (size_t)i * 4) = *(uint2*)o;
}

// ---------------------------------------------------------------------------
// 3-NN (round-6 validated version)
// ---------------------------------------------------------------------------
__device__ inline void ins3(float d, int n,
                            float& d0, int& i0, float& d1, int& i1,
                            float& d2, int& i2) {
    const bool lt0 = d < d0, lt1 = d < d1, lt2 = d < d2;
    const float nd2 = lt1 ? d1 : (lt2 ? d : d2);
    const int   ni2 = lt1 ? i1 : (lt2 ? n : i2);
    const float nd1 = lt0 ? d0 : (lt1 ? d : d1);
    const int   ni1 = lt0 ? i0 : (lt1 ? n : i1);
    const float nd0 = lt0 ? d : d0;
    const int   ni0 = lt0 ? n : i0;
    d0 = nd0; d1 = nd1; d2 = nd2; i0 = ni0; i1 = ni1; i2 = ni2;
}

__global__ __launch_bounds__(256) void knn_kernel(const float* __restrict__ pos,
                                                  const float* __restrict__ pos_skip,
                                                  int* __restrict__ idx_out,
                                                  float* __restrict__ w_out) {
    __shared__ float rpx[N_], rpy[N_], rpz[N_];
    const int b = blockIdx.y;
    const int tid = threadIdx.x;
    for (int t = tid; t < N_ * 3; t += 256) {
        const float v = pos[(size_t)b * N_ * 3 + t];
        const int n = t / 3, k = t - n * 3;
        if (k == 0) rpx[n] = v; else if (k == 1) rpy[n] = v; else rpz[n] = v;
    }
    __syncthreads();

    const int q = tid >> 3;
    const int part = tid & 7;
    const int m = blockIdx.x * 32 + q;
    const size_t qoff = ((size_t)b * M_ + m) * 3;
    const float qx = pos_skip[qoff], qy = pos_skip[qoff + 1], qz = pos_skip[qoff + 2];

    float d0 = 1e30f, d1 = 1e30f, d2 = 1e30f;
    int i0 = 0, i1 = 0, i2 = 0;
#pragma unroll 4
    for (int i = 0; i < 64; ++i) {
        const int n = part * 4 + i * 32;
        const float4 xx = *(const float4*)&rpx[n];
        const float4 yy = *(const float4*)&rpy[n];
        const float4 zz = *(const float4*)&rpz[n];
        float dd[4];
        {
            const float dx = qx - xx.x, dy = qy - yy.x, dz = qz - zz.x;
            dd[0] = dx * dx + dy * dy + dz * dz;
        }
        {
            const float dx = qx - xx.y, dy = qy - yy.y, dz = qz - zz.y;
            dd[1] = dx * dx + dy * dy + dz * dz;
        }
        {
            const float dx = qx - xx.z, dy = qy - yy.z, dz = qz - zz.z;
            dd[2] = dx * dx + dy * dy + dz * dz;
        }
        {
            const float dx = qx - xx.w, dy = qy - yy.w, dz = qz - zz.w;
            dd[3] = dx * dx + dy * dy + dz * dz;
        }
        ins3(dd[0], n + 0, d0, i0, d1, i1, d2, i2);
        ins3(dd[1], n + 1, d0, i0, d1, i1, d2, i2);
        ins3(dd[2], n + 2, d0, i0, d1, i1, d2, i2);
        ins3(dd[3], n + 3, d0, i0, d1, i1, d2, i2);
    }

#pragma unroll
    for (int xm = 1; xm <= 4; xm <<= 1) {
        const float od0 = __shfl_xor(d0, xm), od1 = __shfl_xor(d1, xm), od2 = __shfl_xor(d2, xm);
        const int   oi0 = __shfl_xor(i0, xm), oi1 = __shfl_xor(i1, xm), oi2 = __shfl_xor(i2, xm);
        ins3(od0, oi0, d0, i0, d1, i1, d2, i2);
        ins3(od1, oi1, d0, i0, d1, i1, d2, i2);
        ins3(od2, oi2, d0, i0, d1, i1, d2, i2);
    }

    if (part == 0) {
        const float r0 = 1.0f / (sqrtf(d0) + 1e-8f);
        const float r1 = 1.0f / (sqrtf(d1) + 1e-8f);
        const float r2 = 1.0f / (sqrtf(d2) + 1e-8f);
        const float inv = 1.0f / (r0 + r1 + r2);
        const size_t o = ((size_t)b * M_ + m) * 3;
        idx_out[o] = i0; idx_out[o + 1] = i1; idx_out[o + 2] = i2;
        w_out[o] = r0 * inv; w_out[o + 1] = r1 * inv; w_out[o + 2] = r2 * inv;
    }
}

// ---------------------------------------------------------------------------
// x [b][c][n] f32 -> xT [b][n][c] bf16
// ---------------------------------------------------------------------------
__global__ __launch_bounds__(256) void transpose_x(const float* __restrict__ x,
                                                   u16* __restrict__ xT) {
    __shared__ float t[32][33];
    const int tx = threadIdx.x & 31, ty = threadIdx.x >> 5;
    const int n0 = blockIdx.x * 32, c0 = blockIdx.y * 32, b = blockIdx.z;
#pragma unroll
    for (int r = 0; r < 4; ++r) {
        const int c = c0 + ty + r * 8;
        t[ty + r * 8][tx] = x[((size_t)b * C_ + c) * N_ + n0 + tx];
    }
    __syncthreads();
#pragma unroll
    for (int r = 0; r < 4; ++r) {
        const int n = n0 + ty + r * 8;
        xT[((size_t)b * N_ + n) * C_ + c0 + tx] = f2bf(t[tx][ty + r * 8]);
    }
}

// ---------------------------------------------------------------------------
// x_skip -> Feats[:, 512:768]
// ---------------------------------------------------------------------------
__global__ __launch_bounds__(256) void feats_skip(const float* __restrict__ xs,
                                                  u16* __restrict__ Feats) {
    __shared__ float t[32][33];
    const int tx = threadIdx.x & 31, ty = threadIdx.x >> 5;
    const int m0 = blockIdx.x * 32, c0 = blockIdx.y * 32, b = blockIdx.z;
#pragma unroll
    for (int r = 0; r < 4; ++r) {
        const int c = c0 + ty + r * 8;
        t[ty + r * 8][tx] = xs[((size_t)b * CSK + c) * M_ + m0 + tx];
    }
    __syncthreads();
#pragma unroll
    for (int r = 0; r < 4; ++r) {
        const int m = m0 + ty + r * 8;
        Feats[((size_t)b * M_ + m) * CIN + C_ + c0 + tx] = f2bf(t[tx][ty + r * 8]);
    }
}

// ---------------------------------------------------------------------------
// 3-NN interpolation -> Feats[:, 0:512]
// ---------------------------------------------------------------------------
__device__ inline unsigned interp_pk(unsigned a, unsigned b, unsigned c,
                                     float w0, float w1, float w2) {
    const float lo = w0 * bflo(a) + w1 * bflo(b) + w2 * bflo(c);
    const float hi = w0 * bfhi(a) + w1 * bfhi(b) + w2 * bfhi(c);
    return (unsigned)f2bf(lo) | ((unsigned)f2bf(hi) << 16);
}
__global__ __launch_bounds__(256) void feats_interp(const u16* __restrict__ xT,
                                                    const int* __restrict__ idx,
                                                    const float* __restrict__ w,
                                                    u16* __restrict__ Feats) {
    const int b = blockIdx.y;
    const int lane = threadIdx.x & 63, wv = threadIdx.x >> 6;
    for (int t = 0; t < 16; ++t) {
        const int m = blockIdx.x * 64 + wv * 16 + t;
        const size_t col = (size_t)b * M_ + m;
        const int i0 = idx[col * 3], i1 = idx[col * 3 + 1], i2 = idx[col * 3 + 2];
        const float w0 = w[col * 3], w1 = w[col * 3 + 1], w2 = w[col * 3 + 2];
        const uint4 a = *(const uint4*)(xT + ((size_t)b * N_ + i0) * C_ + lane * 8);
        const uint4 c = *(const uint4*)(xT + ((size_t)b * N_ + i1) * C_ + lane * 8);
        const uint4 d = *(const uint4*)(xT + ((size_t)b * N_ + i2) * C_ + lane * 8);
        uint4 r;
        r.x = interp_pk(a.x, c.x, d.x, w0, w1, w2);
        r.y = interp_pk(a.y, c.y, d.y, w0, w1, w2);
        r.z = interp_pk(a.z, c.z, d.z, w0, w1, w2);
        r.w = interp_pk(a.w, c.w, d.w, w0, w1, w2);
        *(uint4*)(Feats + col * CIN + lane * 8) = r;
    }
}

// ---------------------------------------------------------------------------
// GEMM1: BK=64, both-sides XOR swizzle, XCD-chunked grid, fused BN1 partials.
// LDS tile [128 rows][64 k] u16 (128B rows); LDS[row][s] = G[row][s^(row&7)].
// ---------------------------------------------------------------------------
__device__ inline void stage64(u16* lds, const char* gbase, int ld2,
                               int lane, int wv) {
    const int slot = (lane & 7) ^ (lane >> 3);     // pre-swizzled source slot
#pragma unroll
    for (int jj = 0; jj < 4; ++jj) {
        const int chunk = jj * 4 + wv;             // 0..15 (1KB = 8 rows each)
        const int row = chunk * 8 + (lane >> 3);
        const char* g = gbase + (size_t)row * ld2 + slot * 16;
        __builtin_amdgcn_global_load_lds(
            (const __attribute__((address_space(1))) void*)g,
            (__attribute__((address_space(3))) void*)((char*)lds + chunk * 1024),
            16, 0, 0);
    }
}

__global__ __launch_bounds__(256) void gemm1(const u16* __restrict__ A,
                                             const u16* __restrict__ Bm,
                                             u16* __restrict__ H1,
                                             float* __restrict__ ps1,
                                             float* __restrict__ pq1) {
    __shared__ __attribute__((aligned(16))) u16 As[128 * 64];
    __shared__ __attribute__((aligned(16))) u16 Bs[128 * 64];
    __shared__ float lsum[2][128], lsq[2][128];
    const int tid = threadIdx.x;
    const int lane = tid & 63, wv = tid >> 6;
    const int wr = wv >> 1, wc = wv & 1;
    const int l15 = lane & 15, l4 = lane >> 4;
    // XCD-chunked remap: 2048 blocks -> each XCD a contiguous virtual range
    const int v = (blockIdx.x & 7) * 256 + (blockIdx.x >> 3);
    const int rowblk = v & 3, colblk = v >> 2;
    const int rowM0 = rowblk * 128, colN0 = colblk * 128;
    f32x4 acc[4][4] = {};
    const char* Ab = (const char*)(A  + (size_t)rowM0 * CIN);
    const char* Bb = (const char*)(Bm + (size_t)colN0 * CIN);

    for (int kt = 0; kt < CIN / 64; ++kt) {
        stage64(As, Ab + kt * 128, CIN * 2, lane, wv);
        stage64(Bs, Bb + kt * 128, CIN * 2, lane, wv);
        __syncthreads();
#pragma unroll
        for (int ks = 0; ks < 2; ++ks) {
            s16x8 af[4], bfr[4];
#pragma unroll
            for (int i = 0; i < 4; ++i) {
                const int R = wr * 64 + i * 16 + l15;
                const int s = ((ks << 2) | l4) ^ (R & 7);
                af[i] = *(const s16x8*)((const char*)As + R * 128 + s * 16);
            }
#pragma unroll
            for (int j = 0; j < 4; ++j) {
                const int R = wc * 64 + j * 16 + l15;
                const int s = ((ks << 2) | l4) ^ (R & 7);
                bfr[j] = *(const s16x8*)((const char*)Bs + R * 128 + s * 16);
            }
#pragma unroll
            for (int i = 0; i < 4; ++i)
#pragma unroll
                for (int j = 0; j < 4; ++j)
                    acc[i][j] = __builtin_amdgcn_mfma_f32_16x16x32_bf16(bfr[j], af[i], acc[i][j], 0, 0, 0);
        }
        __syncthreads();
    }

    // store H1^T (bf16)
#pragma unroll
    for (int i = 0; i < 4; ++i) {
        const int o = rowM0 + wr * 64 + i * 16 + l15;
#pragma unroll
        for (int j = 0; j < 4; ++j) {
            const int colb = colN0 + wc * 64 + j * 16 + l4 * 4;
#pragma unroll
            for (int r = 0; r < 4; ++r)
                H1[(size_t)(colb + r) * H1C + o] = f2bf(acc[i][j][r]);
        }
    }

    // BN1 partials (f32, deterministic)
#pragma unroll
    for (int i = 0; i < 4; ++i) {
        float s = 0.f, q = 0.f;
#pragma unroll
        for (int j = 0; j < 4; ++j)
#pragma unroll
            for (int r = 0; r < 4; ++r) {
                const float vv = acc[i][j][r];
                s += vv; q += vv * vv;
            }
        s += __shfl_xor(s, 16); q += __shfl_xor(q, 16);
        s += __shfl_xor(s, 32); q += __shfl_xor(q, 32);
        if ((lane & 48) == 0) {
            lsum[wc][wr * 64 + i * 16 + l15] = s;
            lsq [wc][wr * 64 + i * 16 + l15] = q;
        }
    }
    __syncthreads();
    if (tid < 128) {
        const float S = lsum[0][tid] + lsum[1][tid];
        const float Q = lsq[0][tid] + lsq[1][tid];
        ps1[(size_t)(rowM0 + tid) * 512 + colblk] = S;
        pq1[(size_t)(rowM0 + tid) * 512 + colblk] = Q;
    }
}

// ---------------------------------------------------------------------------
// BN1 final
// ---------------------------------------------------------------------------
__global__ __launch_bounds__(256) void bn1_final(const float* __restrict__ ps,
                                                 const float* __restrict__ pq,
                                                 const float* __restrict__ gamma,
                                                 const float* __restrict__ beta,
                                                 float* __restrict__ sc,
                                                 float* __restrict__ sh) {
    const int o = blockIdx.x;
    const int t = threadIdx.x;
    float S = ps[(size_t)o * 512 + t] + ps[(size_t)o * 512 + 256 + t];
    float Q = pq[(size_t)o * 512 + t] + pq[(size_t)o * 512 + 256 + t];
    __shared__ float rs[256], rq[256];
    rs[t] = S; rq[t] = Q;
    __syncthreads();
    for (int st = 128; st > 0; st >>= 1) {
        if (t < st) { rs[t] += rs[t + st]; rq[t] += rq[t + st]; }
        __syncthreads();
    }
    if (t == 0) {
        const float mean = rs[0] * (1.0f / NCOL);
        const float var  = fmaxf(rq[0] * (1.0f / NCOL) - mean * mean, 0.f);
        const float is   = rsqrtf(var + 1e-5f);
        const float s    = gamma[o] * is;
        sc[o] = s;
        sh[o] = beta[o] - mean * s;
    }
}

// ---------------------------------------------------------------------------
// GEMM2 with BN1 affine+leaky fused into reg-staged B (per-channel params
// indexed by k0+kb — the round-8 bug was using kb only). Fused BN2 partials.
// ---------------------------------------------------------------------------
__device__ inline void stage2A(u16* dst, const u16* W2b, int k0,
                               int lane, int wv) {
#pragma unroll
    for (int h = 0; h < 2; ++h) {
        const int p_loc = h * 128 + wv * 16 + (lane >> 2);
        const u16* g = W2b + (size_t)p_loc * H1C + k0 + (lane & 3) * 8;
        __builtin_amdgcn_global_load_lds(
            (const __attribute__((address_space(1))) void*)g,
            (__attribute__((address_space(3))) void*)((char*)dst + (h * 512 + wv * 64) * 16),
            16, 0, 0);
    }
}

__global__ __launch_bounds__(512, 2) void gemm2(const u16* __restrict__ W2b,
                                                const u16* __restrict__ H1,
                                                const float* __restrict__ sc1,
                                                const float* __restrict__ sh1,
                                                float* __restrict__ out,
                                                float* __restrict__ ps2,
                                                float* __restrict__ pq2) {
    __shared__ __attribute__((aligned(16))) u16 As[2][256 * 32];
    __shared__ __attribute__((aligned(16))) u16 Bs[2][256 * 32];
    __shared__ float lsum[4][256], lsq[4][256];
    __shared__ float scs[512], shs[512];
    const int tid = threadIdx.x;
    const int lane = tid & 63, wv = tid >> 6;
    const int pgrp = wv & 1, cgrp = wv >> 1;
    const int l15 = lane & 15, l4 = lane >> 4;
    const int col0 = blockIdx.x * 256;
    const u16* Hb = H1 + (size_t)col0 * H1C;
    const int kb = (lane & 3) * 8;
    const int prow0 = wv * 16 + (lane >> 2);
    f32x4 acc[4][8] = {};

    scs[tid] = sc1[tid];
    shs[tid] = sh1[tid];

    stage2A(As[0], W2b, 0, lane, wv);
    uint4 nb0 = *(const uint4*)(Hb + (size_t)prow0 * H1C + kb);
    uint4 nb1 = *(const uint4*)(Hb + (size_t)(prow0 + 128) * H1C + kb);
    __syncthreads();   // scs/shs visible

    // transform + write B for K-tile k0 into Bs[buf]
    auto xformB = [&](int buf, uint4 b0, uint4 b1, int k0) {
        const f32x4 s0v = *(const f32x4*)&scs[k0 + kb];
        const f32x4 s1v = *(const f32x4*)&scs[k0 + kb + 4];
        const f32x4 h0v = *(const f32x4*)&shs[k0 + kb];
        const f32x4 h1v = *(const f32x4*)&shs[k0 + kb + 4];
        const float sv[8] = {s0v[0], s0v[1], s0v[2], s0v[3], s1v[0], s1v[1], s1v[2], s1v[3]};
        const float hv[8] = {h0v[0], h0v[1], h0v[2], h0v[3], h1v[0], h1v[1], h1v[2], h1v[3]};
        uint4 bw[2] = {b0, b1};
#pragma unroll
        for (int h = 0; h < 2; ++h) {
            unsigned uu[4] = {bw[h].x, bw[h].y, bw[h].z, bw[h].w};
            unsigned rr[4];
#pragma unroll
            for (int e = 0; e < 4; ++e) {
                float f0 = fmaf(bflo(uu[e]), sv[e * 2], hv[e * 2]);
                float f1 = fmaf(bfhi(uu[e]), sv[e * 2 + 1], hv[e * 2 + 1]);
                f0 = f0 >= 0.f ? f0 : 0.2f * f0;
                f1 = f1 >= 0.f ? f1 : 0.2f * f1;
                rr[e] = (unsigned)f2bf(f0) | ((unsigned)f2bf(f1) << 16);
            }
            *(uint4*)&Bs[buf][(size_t)(h * 512 + wv * 64 + lane) * 8] = make_uint4(rr[0], rr[1], rr[2], rr[3]);
        }
    };

    xformB(0, nb0, nb1, 0);
    __syncthreads();

    int cur = 0;
    for (int step = 0; step < 16; ++step) {
        if (step < 15) {
            const int k0 = (step + 1) * 32;
            stage2A(As[cur ^ 1], W2b, k0, lane, wv);
            nb0 = *(const uint4*)(Hb + (size_t)prow0 * H1C + k0 + kb);
            nb1 = *(const uint4*)(Hb + (size_t)(prow0 + 128) * H1C + k0 + kb);
        }
        const u16* Ac = As[cur];
        const u16* Bc = Bs[cur];
        s16x8 af[8], bfr[4];
#pragma unroll
        for (int pf = 0; pf < 8; ++pf)
            af[pf] = *(const s16x8*)&Ac[(pgrp * 128 + pf * 16 + l15) * 32 + l4 * 8];
#pragma unroll
        for (int cf = 0; cf < 4; ++cf)
            bfr[cf] = *(const s16x8*)&Bc[(cgrp * 64 + cf * 16 + l15) * 32 + l4 * 8];
#pragma unroll
        for (int cf = 0; cf < 4; ++cf)
#pragma unroll
            for (int pf = 0; pf < 8; ++pf)
                acc[cf][pf] = __builtin_amdgcn_mfma_f32_16x16x32_bf16(bfr[cf], af[pf], acc[cf][pf], 0, 0, 0);
        if (step < 15) {
            xformB(cur ^ 1, nb0, nb1, (step + 1) * 32);
        }
        __syncthreads();
        cur ^= 1;
    }

    const int bidx = col0 >> 13;
    const int mb   = col0 & (M_ - 1);
#pragma unroll
    for (int cf = 0; cf < 4; ++cf) {
#pragma unroll
        for (int pf = 0; pf < 8; ++pf) {
            const int p  = pgrp * 128 + pf * 16 + l15;
            const int mm = mb + cgrp * 64 + cf * 16 + l4 * 4;
            *(f32x4*)(out + (size_t)bidx * (H2C * M_) + (size_t)p * M_ + mm) = acc[cf][pf];
        }
    }

#pragma unroll
    for (int pf = 0; pf < 8; ++pf) {
        float s = 0.f, q = 0.f;
#pragma unroll
        for (int cf = 0; cf < 4; ++cf)
#pragma unroll
            for (int r = 0; r < 4; ++r) {
                const float vv = acc[cf][pf][r];
                s += vv; q += vv * vv;
            }
        s += __shfl_xor(s, 16); q += __shfl_xor(q, 16);
        s += __shfl_xor(s, 32); q += __shfl_xor(q, 32);
        if ((lane & 48) == 0) {
            lsum[cgrp][pgrp * 128 + pf * 16 + l15] = s;
            lsq [cgrp][pgrp * 128 + pf * 16 + l15] = q;
        }
    }
    __syncthreads();
    if (tid < 256) {
        const float S = lsum[0][tid] + lsum[1][tid] + lsum[2][tid] + lsum[3][tid];
        const float Q = lsq[0][tid] + lsq[1][tid] + lsq[2][tid] + lsq[3][tid];
        ps2[(size_t)tid * 256 + blockIdx.x] = S;
        pq2[(size_t)tid * 256 + blockIdx.x] = Q;
    }
}

// ---------------------------------------------------------------------------
// BN2 final
// ---------------------------------------------------------------------------
__global__ __launch_bounds__(256) void bn2_final(const float* __restrict__ ps,
                                                 const float* __restrict__ pq,
                                                 const float* __restrict__ gamma,
                                                 const float* __restrict__ beta,
                                                 float* __restrict__ sc,
                                                 float* __restrict__ sh) {
    const int p = blockIdx.x;
    const int t = threadIdx.x;
    float S = ps[(size_t)p * 256 + t];
    float Q = pq[(size_t)p * 256 + t];
    __shared__ float rs[256], rq[256];
    rs[t] = S; rq[t] = Q;
    __syncthreads();
    for (int st = 128; st > 0; st >>= 1) {
        if (t < st) { rs[t] += rs[t + st]; rq[t] += rq[t + st]; }
        __syncthreads();
    }
    if (t == 0) {
        const float mean = rs[0] * (1.0f / NCOL);
        const float var  = fmaxf(rq[0] * (1.0f / NCOL) - mean * mean, 0.f);
        const float is   = rsqrtf(var + 1e-5f);
        const float s    = gamma[p] * is;
        sc[p] = s;
        sh[p] = beta[p] - mean * s;
    }
}

// ---------------------------------------------------------------------------
// In-place BN2 affine + leaky on d_out
// ---------------------------------------------------------------------------
__global__ __launch_bounds__(256) void bn_apply2(float* __restrict__ out,
                                                 const float* __restrict__ sc,
                                                 const float* __restrict__ sh) {
    const size_t i = (size_t)blockIdx.x * 256 + threadIdx.x;
    const int p = (int)((i >> 13) & (H2C - 1));
    float v = out[i];
    v = fmaf(v, sc[p], sh[p]);
    out[i] = v >= 0.f ? v : 0.2f * v;
}

// ---------------------------------------------------------------------------
extern "C" void kernel_launch(void* const* d_in, const int* in_sizes, int n_in,
                              void* d_out, int out_size, void* d_ws, size_t ws_size,
                              hipStream_t stream) {
    const float* pos      = (const float*)d_in[0];
    const float* pos_skip = (const float*)d_in[1];
    const float* x        = (const float*)d_in[2];
    const float* x_skip   = (const float*)d_in[3];
    const float* W1       = (const float*)d_in[4];
    const float* gamma1   = (const float*)d_in[5];
    const float* beta1    = (const float*)d_in[6];
    const float* W2       = (const float*)d_in[7];
    const float* gamma2   = (const float*)d_in[8];
    const float* beta2    = (const float*)d_in[9];
    float* out = (float*)d_out;

    char* ws = (char*)d_ws;
    size_t off = 0;
    auto alloc = [&](size_t bytes) {
        void* p = ws + off;
        off = (off + bytes + 255) & ~(size_t)255;
        return p;
    };
    int*   idx   = (int*)  alloc((size_t)NCOL * 3 * sizeof(int));
    float* w     = (float*)alloc((size_t)NCOL * 3 * sizeof(float));
    u16*   xT    = (u16*)  alloc((size_t)B_ * N_ * C_ * sizeof(u16));
    u16*   W1b   = (u16*)  alloc((size_t)H1C * CIN * sizeof(u16));
    u16*   W2b   = (u16*)  alloc((size_t)H2C * H1C * sizeof(u16));
    u16*   Feats = (u16*)  alloc((size_t)NCOL * CIN * sizeof(u16));
    u16*   H1    = (u16*)  alloc((size_t)NCOL * H1C * sizeof(u16));
    float* ps1   = (float*)alloc((size_t)H1C * 512 * sizeof(float));
    float* pq1   = (float*)alloc((size_t)H1C * 512 * sizeof(float));
    float* ps2   = (float*)alloc((size_t)H2C * 256 * sizeof(float));
    float* pq2   = (float*)alloc((size_t)H2C * 256 * sizeof(float));
    float* sc1   = (float*)alloc(H1C * sizeof(float));
    float* sh1   = (float*)alloc(H1C * sizeof(float));
    float* sc2   = (float*)alloc(H2C * sizeof(float));
    float* sh2   = (float*)alloc(H2C * sizeof(float));

    cvt_bf16_k<<<(H1C * CIN / 4 + 255) / 256, 256, 0, stream>>>(W1, W1b, H1C * CIN / 4);
    cvt_bf16_k<<<(H2C * H1C / 4 + 255) / 256, 256, 0, stream>>>(W2, W2b, H2C * H1C / 4);
    knn_kernel<<<dim3(M_ / 32, B_), 256, 0, stream>>>(pos, pos_skip, idx, w);
    transpose_x<<<dim3(N_ / 32, C_ / 32, B_), 256, 0, stream>>>(x, xT);
    feats_interp<<<dim3(M_ / 64, B_), 256, 0, stream>>>(xT, idx, w, Feats);
    feats_skip<<<dim3(M_ / 32, CSK / 32, B_), 256, 0, stream>>>(x_skip, Feats);
    gemm1<<<2048, 256, 0, stream>>>(W1b, Feats, H1, ps1, pq1);
    bn1_final<<<H1C, 256, 0, stream>>>(ps1, pq1, gamma1, beta1, sc1, sh1);
    gemm2<<<NCOL / 256, 512, 0, stream>>>(W2b, H1, sc1, sh1, out, ps2, pq2);
    bn2_final<<<H2C, 256, 0, stream>>>(ps2, pq2, gamma2, beta2, sc2, sh2);
    bn_apply2<<<(int)(((size_t)NCOL * H2C) / 256), 256, 0, stream>>>(out, sc2, sh2);
}

// Round 12
// 299.599 us; speedup vs baseline: 4.0329x; 1.0090x over previous
//
#include <hip/hip_runtime.h>
#include <stdint.h>

// Problem constants
#define B_    8
#define N_    2048
#define M_    8192
#define C_    512
#define CSK   256
#define CIN   768
#define H1C   512
#define H2C   256
#define NCOL  65536     // B_*M_
typedef unsigned short u16;
typedef __attribute__((ext_vector_type(8))) short  s16x8;
typedef __attribute__((ext_vector_type(4))) float  f32x4;

// ---- bf16 helpers (RNE) ----
__device__ inline u16 f2bf(float f) {
    unsigned u = __float_as_uint(f);
    unsigned r = (u + 0x7fffu + ((u >> 16) & 1u)) >> 16;
    return (u16)r;
}
__device__ inline float bflo(unsigned u) { return __uint_as_float(u << 16); }
__device__ inline float bfhi(unsigned u) { return __uint_as_float(u & 0xffff0000u); }

// ---------------------------------------------------------------------------
// f32 -> bf16 bulk convert
// ---------------------------------------------------------------------------
__global__ __launch_bounds__(256) void cvt_bf16_k(const float* __restrict__ in,
                                                  u16* __restrict__ out, int n4) {
    const int i = blockIdx.x * 256 + threadIdx.x;
    if (i >= n4) return;
    const float4 v = *(const float4*)(in + (size_t)i * 4);
    u16 o[4] = {f2bf(v.x), f2bf(v.y), f2bf(v.z), f2bf(v.w)};
    *(uint2*)(out + (size_t)i * 4) = *(uint2*)o;
}

// ---------------------------------------------------------------------------
// 3-NN: EXACT f32 ordering (round-11's packed-key truncation flipped
// neighbor selection — rank-sensitive gathers need exact compares).
// Distance surrogate: s = r^2 - 2 q.r  (3 FMA; ordering == d^2 ordering,
// d^2 = s + |q|^2 recovered+clamped only for the 3 winners).
// 8 lanes/query, interleaved conflict-free partition, branchless insert.
// ---------------------------------------------------------------------------
__device__ inline void ins3(float d, int n,
                            float& d0, int& i0, float& d1, int& i1,
                            float& d2, int& i2) {
    const bool lt0 = d < d0, lt1 = d < d1, lt2 = d < d2;
    const float nd2 = lt1 ? d1 : (lt2 ? d : d2);
    const int   ni2 = lt1 ? i1 : (lt2 ? n : i2);
    const float nd1 = lt0 ? d0 : (lt1 ? d : d1);
    const int   ni1 = lt0 ? i0 : (lt1 ? n : i1);
    const float nd0 = lt0 ? d : d0;
    const int   ni0 = lt0 ? n : i0;
    d0 = nd0; d1 = nd1; d2 = nd2; i0 = ni0; i1 = ni1; i2 = ni2;
}

__global__ __launch_bounds__(256) void knn_kernel(const float* __restrict__ pos,
                                                  const float* __restrict__ pos_skip,
                                                  int* __restrict__ idx_out,
                                                  float* __restrict__ w_out) {
    __shared__ float rpx[N_], rpy[N_], rpz[N_], rr2[N_];
    const int b = blockIdx.y;
    const int tid = threadIdx.x;
    for (int t = tid; t < N_ * 3; t += 256) {
        const float v = pos[(size_t)b * N_ * 3 + t];
        const int n = t / 3, k = t - n * 3;
        if (k == 0) rpx[n] = v; else if (k == 1) rpy[n] = v; else rpz[n] = v;
    }
    __syncthreads();
    for (int n = tid; n < N_; n += 256)
        rr2[n] = rpx[n] * rpx[n] + rpy[n] * rpy[n] + rpz[n] * rpz[n];
    __syncthreads();

    const int q = tid >> 3;          // query slot (0..31)
    const int part = tid & 7;        // ref sub-stream
    const int m = blockIdx.x * 32 + q;
    const size_t qoff = ((size_t)b * M_ + m) * 3;
    const float qx = pos_skip[qoff], qy = pos_skip[qoff + 1], qz = pos_skip[qoff + 2];
    const float q2x = -2.0f * qx, q2y = -2.0f * qy, q2z = -2.0f * qz;
    const float qq = qx * qx + qy * qy + qz * qz;

    float d0 = 1e30f, d1 = 1e30f, d2 = 1e30f;
    int i0 = 0, i1 = 0, i2 = 0;
#pragma unroll 4
    for (int i = 0; i < 64; ++i) {
        const int n = part * 4 + i * 32;
        const float4 xx = *(const float4*)&rpx[n];
        const float4 yy = *(const float4*)&rpy[n];
        const float4 zz = *(const float4*)&rpz[n];
        const float4 ww = *(const float4*)&rr2[n];
        const float s0 = fmaf(xx.x, q2x, fmaf(yy.x, q2y, fmaf(zz.x, q2z, ww.x)));
        const float s1 = fmaf(xx.y, q2x, fmaf(yy.y, q2y, fmaf(zz.y, q2z, ww.y)));
        const float s2 = fmaf(xx.z, q2x, fmaf(yy.z, q2y, fmaf(zz.z, q2z, ww.z)));
        const float s3 = fmaf(xx.w, q2x, fmaf(yy.w, q2y, fmaf(zz.w, q2z, ww.w)));
        ins3(s0, n + 0, d0, i0, d1, i1, d2, i2);
        ins3(s1, n + 1, d0, i0, d1, i1, d2, i2);
        ins3(s2, n + 2, d0, i0, d1, i1, d2, i2);
        ins3(s3, n + 3, d0, i0, d1, i1, d2, i2);
    }

    // merge top-3 across the 8 lanes of this query (xor 1, 2, 4)
#pragma unroll
    for (int xm = 1; xm <= 4; xm <<= 1) {
        const float od0 = __shfl_xor(d0, xm), od1 = __shfl_xor(d1, xm), od2 = __shfl_xor(d2, xm);
        const int   oi0 = __shfl_xor(i0, xm), oi1 = __shfl_xor(i1, xm), oi2 = __shfl_xor(i2, xm);
        ins3(od0, oi0, d0, i0, d1, i1, d2, i2);
        ins3(od1, oi1, d0, i0, d1, i1, d2, i2);
        ins3(od2, oi2, d0, i0, d1, i1, d2, i2);
    }

    if (part == 0) {
        const float dd0 = fmaxf(d0 + qq, 0.f);
        const float dd1 = fmaxf(d1 + qq, 0.f);
        const float dd2 = fmaxf(d2 + qq, 0.f);
        const float r0 = 1.0f / (sqrtf(dd0) + 1e-8f);
        const float r1 = 1.0f / (sqrtf(dd1) + 1e-8f);
        const float r2 = 1.0f / (sqrtf(dd2) + 1e-8f);
        const float inv = 1.0f / (r0 + r1 + r2);
        const size_t o = ((size_t)b * M_ + m) * 3;
        idx_out[o] = i0; idx_out[o + 1] = i1; idx_out[o + 2] = i2;
        w_out[o] = r0 * inv; w_out[o + 1] = r1 * inv; w_out[o + 2] = r2 * inv;
    }
}

// ---------------------------------------------------------------------------
// x [b][c][n] f32 -> xT [b][n][c] bf16
// ---------------------------------------------------------------------------
__global__ __launch_bounds__(256) void transpose_x(const float* __restrict__ x,
                                                   u16* __restrict__ xT) {
    __shared__ float t[32][33];
    const int tx = threadIdx.x & 31, ty = threadIdx.x >> 5;
    const int n0 = blockIdx.x * 32, c0 = blockIdx.y * 32, b = blockIdx.z;
#pragma unroll
    for (int r = 0; r < 4; ++r) {
        const int c = c0 + ty + r * 8;
        t[ty + r * 8][tx] = x[((size_t)b * C_ + c) * N_ + n0 + tx];
    }
    __syncthreads();
#pragma unroll
    for (int r = 0; r < 4; ++r) {
        const int n = n0 + ty + r * 8;
        xT[((size_t)b * N_ + n) * C_ + c0 + tx] = f2bf(t[tx][ty + r * 8]);
    }
}

// ---------------------------------------------------------------------------
// x_skip -> Feats[:, 512:768]
// ---------------------------------------------------------------------------
__global__ __launch_bounds__(256) void feats_skip(const float* __restrict__ xs,
                                                  u16* __restrict__ Feats) {
    __shared__ float t[32][33];
    const int tx = threadIdx.x & 31, ty = threadIdx.x >> 5;
    const int m0 = blockIdx.x * 32, c0 = blockIdx.y * 32, b = blockIdx.z;
#pragma unroll
    for (int r = 0; r < 4; ++r) {
        const int c = c0 + ty + r * 8;
        t[ty + r * 8][tx] = xs[((size_t)b * CSK + c) * M_ + m0 + tx];
    }
    __syncthreads();
#pragma unroll
    for (int r = 0; r < 4; ++r) {
        const int m = m0 + ty + r * 8;
        Feats[((size_t)b * M_ + m) * CIN + C_ + c0 + tx] = f2bf(t[tx][ty + r * 8]);
    }
}

// ---------------------------------------------------------------------------
// 3-NN interpolation -> Feats[:, 0:512]
// ---------------------------------------------------------------------------
__device__ inline unsigned interp_pk(unsigned a, unsigned b, unsigned c,
                                     float w0, float w1, float w2) {
    const float lo = w0 * bflo(a) + w1 * bflo(b) + w2 * bflo(c);
    const float hi = w0 * bfhi(a) + w1 * bfhi(b) + w2 * bfhi(c);
    return (unsigned)f2bf(lo) | ((unsigned)f2bf(hi) << 16);
}
__global__ __launch_bounds__(256) void feats_interp(const u16* __restrict__ xT,
                                                    const int* __restrict__ idx,
                                                    const float* __restrict__ w,
                                                    u16* __restrict__ Feats) {
    const int b = blockIdx.y;
    const int lane = threadIdx.x & 63, wv = threadIdx.x >> 6;
    for (int t = 0; t < 16; ++t) {
        const int m = blockIdx.x * 64 + wv * 16 + t;
        const size_t col = (size_t)b * M_ + m;
        const int i0 = idx[col * 3], i1 = idx[col * 3 + 1], i2 = idx[col * 3 + 2];
        const float w0 = w[col * 3], w1 = w[col * 3 + 1], w2 = w[col * 3 + 2];
        const uint4 a = *(const uint4*)(xT + ((size_t)b * N_ + i0) * C_ + lane * 8);
        const uint4 c = *(const uint4*)(xT + ((size_t)b * N_ + i1) * C_ + lane * 8);
        const uint4 d = *(const uint4*)(xT + ((size_t)b * N_ + i2) * C_ + lane * 8);
        uint4 r;
        r.x = interp_pk(a.x, c.x, d.x, w0, w1, w2);
        r.y = interp_pk(a.y, c.y, d.y, w0, w1, w2);
        r.z = interp_pk(a.z, c.z, d.z, w0, w1, w2);
        r.w = interp_pk(a.w, c.w, d.w, w0, w1, w2);
        *(uint4*)(Feats + col * CIN + lane * 8) = r;
    }
}

// ---------------------------------------------------------------------------
// GEMM1: BK=64, both-sides XOR swizzle, XCD-chunked grid, fused BN1 partials.
// LDS tile [128 rows][64 k] u16 (128B rows); LDS[row][s] = G[row][s^(row&7)].
// ---------------------------------------------------------------------------
__device__ inline void stage64(u16* lds, const char* gbase, int ld2,
                               int lane, int wv) {
    const int slot = (lane & 7) ^ (lane >> 3);     // pre-swizzled source slot
#pragma unroll
    for (int jj = 0; jj < 4; ++jj) {
        const int chunk = jj * 4 + wv;             // 0..15 (1KB = 8 rows each)
        const int row = chunk * 8 + (lane >> 3);
        const char* g = gbase + (size_t)row * ld2 + slot * 16;
        __builtin_amdgcn_global_load_lds(
            (const __attribute__((address_space(1))) void*)g,
            (__attribute__((address_space(3))) void*)((char*)lds + chunk * 1024),
            16, 0, 0);
    }
}

__global__ __launch_bounds__(256) void gemm1(const u16* __restrict__ A,
                                             const u16* __restrict__ Bm,
                                             u16* __restrict__ H1,
                                             float* __restrict__ ps1,
                                             float* __restrict__ pq1) {
    __shared__ __attribute__((aligned(16))) u16 As[128 * 64];
    __shared__ __attribute__((aligned(16))) u16 Bs[128 * 64];
    __shared__ float lsum[2][128], lsq[2][128];
    const int tid = threadIdx.x;
    const int lane = tid & 63, wv = tid >> 6;
    const int wr = wv >> 1, wc = wv & 1;
    const int l15 = lane & 15, l4 = lane >> 4;
    // XCD-chunked remap: 2048 blocks -> each XCD a contiguous virtual range
    const int v = (blockIdx.x & 7) * 256 + (blockIdx.x >> 3);
    const int rowblk = v & 3, colblk = v >> 2;
    const int rowM0 = rowblk * 128, colN0 = colblk * 128;
    f32x4 acc[4][4] = {};
    const char* Ab = (const char*)(A  + (size_t)rowM0 * CIN);
    const char* Bb = (const char*)(Bm + (size_t)colN0 * CIN);

    for (int kt = 0; kt < CIN / 64; ++kt) {
        stage64(As, Ab + kt * 128, CIN * 2, lane, wv);
        stage64(Bs, Bb + kt * 128, CIN * 2, lane, wv);
        __syncthreads();
#pragma unroll
        for (int ks = 0; ks < 2; ++ks) {
            s16x8 af[4], bfr[4];
#pragma unroll
            for (int i = 0; i < 4; ++i) {
                const int R = wr * 64 + i * 16 + l15;
                const int s = ((ks << 2) | l4) ^ (R & 7);
                af[i] = *(const s16x8*)((const char*)As + R * 128 + s * 16);
            }
#pragma unroll
            for (int j = 0; j < 4; ++j) {
                const int R = wc * 64 + j * 16 + l15;
                const int s = ((ks << 2) | l4) ^ (R & 7);
                bfr[j] = *(const s16x8*)((const char*)Bs + R * 128 + s * 16);
            }
#pragma unroll
            for (int i = 0; i < 4; ++i)
#pragma unroll
                for (int j = 0; j < 4; ++j)
                    acc[i][j] = __builtin_amdgcn_mfma_f32_16x16x32_bf16(bfr[j], af[i], acc[i][j], 0, 0, 0);
        }
        __syncthreads();
    }

    // store H1^T (bf16)
#pragma unroll
    for (int i = 0; i < 4; ++i) {
        const int o = rowM0 + wr * 64 + i * 16 + l15;
#pragma unroll
        for (int j = 0; j < 4; ++j) {
            const int colb = colN0 + wc * 64 + j * 16 + l4 * 4;
#pragma unroll
            for (int r = 0; r < 4; ++r)
                H1[(size_t)(colb + r) * H1C + o] = f2bf(acc[i][j][r]);
        }
    }

    // BN1 partials (f32, deterministic)
#pragma unroll
    for (int i = 0; i < 4; ++i) {
        float s = 0.f, q = 0.f;
#pragma unroll
        for (int j = 0; j < 4; ++j)
#pragma unroll
            for (int r = 0; r < 4; ++r) {
                const float vv = acc[i][j][r];
                s += vv; q += vv * vv;
            }
        s += __shfl_xor(s, 16); q += __shfl_xor(q, 16);
        s += __shfl_xor(s, 32); q += __shfl_xor(q, 32);
        if ((lane & 48) == 0) {
            lsum[wc][wr * 64 + i * 16 + l15] = s;
            lsq [wc][wr * 64 + i * 16 + l15] = q;
        }
    }
    __syncthreads();
    if (tid < 128) {
        const float S = lsum[0][tid] + lsum[1][tid];
        const float Q = lsq[0][tid] + lsq[1][tid];
        ps1[(size_t)(rowM0 + tid) * 512 + colblk] = S;
        pq1[(size_t)(rowM0 + tid) * 512 + colblk] = Q;
    }
}

// ---------------------------------------------------------------------------
// BN1 final
// ---------------------------------------------------------------------------
__global__ __launch_bounds__(256) void bn1_final(const float* __restrict__ ps,
                                                 const float* __restrict__ pq,
                                                 const float* __restrict__ gamma,
                                                 const float* __restrict__ beta,
                                                 float* __restrict__ sc,
                                                 float* __restrict__ sh) {
    const int o = blockIdx.x;
    const int t = threadIdx.x;
    float S = ps[(size_t)o * 512 + t] + ps[(size_t)o * 512 + 256 + t];
    float Q = pq[(size_t)o * 512 + t] + pq[(size_t)o * 512 + 256 + t];
    __shared__ float rs[256], rq[256];
    rs[t] = S; rq[t] = Q;
    __syncthreads();
    for (int st = 128; st > 0; st >>= 1) {
        if (t < st) { rs[t] += rs[t + st]; rq[t] += rq[t + st]; }
        __syncthreads();
    }
    if (t == 0) {
        const float mean = rs[0] * (1.0f / NCOL);
        const float var  = fmaxf(rq[0] * (1.0f / NCOL) - mean * mean, 0.f);
        const float is   = rsqrtf(var + 1e-5f);
        const float s    = gamma[o] * is;
        sc[o] = s;
        sh[o] = beta[o] - mean * s;
    }
}

// ---------------------------------------------------------------------------
// GEMM2 with BN1 affine+leaky fused into reg-staged B (per-channel params
// indexed by k0+kb). Fused BN2 partials.
// ---------------------------------------------------------------------------
__device__ inline void stage2A(u16* dst, const u16* W2b, int k0,
                               int lane, int wv) {
#pragma unroll
    for (int h = 0; h < 2; ++h) {
        const int p_loc = h * 128 + wv * 16 + (lane >> 2);
        const u16* g = W2b + (size_t)p_loc * H1C + k0 + (lane & 3) * 8;
        __builtin_amdgcn_global_load_lds(
            (const __attribute__((address_space(1))) void*)g,
            (__attribute__((address_space(3))) void*)((char*)dst + (h * 512 + wv * 64) * 16),
            16, 0, 0);
    }
}

__global__ __launch_bounds__(512, 2) void gemm2(const u16* __restrict__ W2b,
                                                const u16* __restrict__ H1,
                                                const float* __restrict__ sc1,
                                                const float* __restrict__ sh1,
                                                float* __restrict__ out,
                                                float* __restrict__ ps2,
                                                float* __restrict__ pq2) {
    __shared__ __attribute__((aligned(16))) u16 As[2][256 * 32];
    __shared__ __attribute__((aligned(16))) u16 Bs[2][256 * 32];
    __shared__ float lsum[4][256], lsq[4][256];
    __shared__ float scs[512], shs[512];
    const int tid = threadIdx.x;
    const int lane = tid & 63, wv = tid >> 6;
    const int pgrp = wv & 1, cgrp = wv >> 1;
    const int l15 = lane & 15, l4 = lane >> 4;
    const int col0 = blockIdx.x * 256;
    const u16* Hb = H1 + (size_t)col0 * H1C;
    const int kb = (lane & 3) * 8;
    const int prow0 = wv * 16 + (lane >> 2);
    f32x4 acc[4][8] = {};

    scs[tid] = sc1[tid];
    shs[tid] = sh1[tid];

    stage2A(As[0], W2b, 0, lane, wv);
    uint4 nb0 = *(const uint4*)(Hb + (size_t)prow0 * H1C + kb);
    uint4 nb1 = *(const uint4*)(Hb + (size_t)(prow0 + 128) * H1C + kb);
    __syncthreads();   // scs/shs visible

    // transform + write B for K-tile k0 into Bs[buf]
    auto xformB = [&](int buf, uint4 b0, uint4 b1, int k0) {
        const f32x4 s0v = *(const f32x4*)&scs[k0 + kb];
        const f32x4 s1v = *(const f32x4*)&scs[k0 + kb + 4];
        const f32x4 h0v = *(const f32x4*)&shs[k0 + kb];
        const f32x4 h1v = *(const f32x4*)&shs[k0 + kb + 4];
        const float sv[8] = {s0v[0], s0v[1], s0v[2], s0v[3], s1v[0], s1v[1], s1v[2], s1v[3]};
        const float hv[8] = {h0v[0], h0v[1], h0v[2], h0v[3], h1v[0], h1v[1], h1v[2], h1v[3]};
        uint4 bw[2] = {b0, b1};
#pragma unroll
        for (int h = 0; h < 2; ++h) {
            unsigned uu[4] = {bw[h].x, bw[h].y, bw[h].z, bw[h].w};
            unsigned rr[4];
#pragma unroll
            for (int e = 0; e < 4; ++e) {
                float f0 = fmaf(bflo(uu[e]), sv[e * 2], hv[e * 2]);
                float f1 = fmaf(bfhi(uu[e]), sv[e * 2 + 1], hv[e * 2 + 1]);
                f0 = f0 >= 0.f ? f0 : 0.2f * f0;
                f1 = f1 >= 0.f ? f1 : 0.2f * f1;
                rr[e] = (unsigned)f2bf(f0) | ((unsigned)f2bf(f1) << 16);
            }
            *(uint4*)&Bs[buf][(size_t)(h * 512 + wv * 64 + lane) * 8] = make_uint4(rr[0], rr[1], rr[2], rr[3]);
        }
    };

    xformB(0, nb0, nb1, 0);
    __syncthreads();

    int cur = 0;
    for (int step = 0; step < 16; ++step) {
        if (step < 15) {
            const int k0 = (step + 1) * 32;
            stage2A(As[cur ^ 1], W2b, k0, lane, wv);
            nb0 = *(const uint4*)(Hb + (size_t)prow0 * H1C + k0 + kb);
            nb1 = *(const uint4*)(Hb + (size_t)(prow0 + 128) * H1C + k0 + kb);
        }
        const u16* Ac = As[cur];
        const u16* Bc = Bs[cur];
        s16x8 af[8], bfr[4];
#pragma unroll
        for (int pf = 0; pf < 8; ++pf)
            af[pf] = *(const s16x8*)&Ac[(pgrp * 128 + pf * 16 + l15) * 32 + l4 * 8];
#pragma unroll
        for (int cf = 0; cf < 4; ++cf)
            bfr[cf] = *(const s16x8*)&Bc[(cgrp * 64 + cf * 16 + l15) * 32 + l4 * 8];
#pragma unroll
        for (int cf = 0; cf < 4; ++cf)
#pragma unroll
            for (int pf = 0; pf < 8; ++pf)
                acc[cf][pf] = __builtin_amdgcn_mfma_f32_16x16x32_bf16(bfr[cf], af[pf], acc[cf][pf], 0, 0, 0);
        if (step < 15) {
            xformB(cur ^ 1, nb0, nb1, (step + 1) * 32);
        }
        __syncthreads();
        cur ^= 1;
    }

    const int bidx = col0 >> 13;
    const int mb   = col0 & (M_ - 1);
#pragma unroll
    for (int cf = 0; cf < 4; ++cf) {
#pragma unroll
        for (int pf = 0; pf < 8; ++pf) {
            const int p  = pgrp * 128 + pf * 16 + l15;
            const int mm = mb + cgrp * 64 + cf * 16 + l4 * 4;
            *(f32x4*)(out + (size_t)bidx * (H2C * M_) + (size_t)p * M_ + mm) = acc[cf][pf];
        }
    }

#pragma unroll
    for (int pf = 0; pf < 8; ++pf) {
        float s = 0.f, q = 0.f;
#pragma unroll
        for (int cf = 0; cf < 4; ++cf)
#pragma unroll
            for (int r = 0; r < 4; ++r) {
                const float vv = acc[cf][pf][r];
                s += vv; q += vv * vv;
            }
        s += __shfl_xor(s, 16); q += __shfl_xor(q, 16);
        s += __shfl_xor(s, 32); q += __shfl_xor(q, 32);
        if ((lane & 48) == 0) {
            lsum[cgrp][pgrp * 128 + pf * 16 + l15] = s;
            lsq [cgrp][pgrp * 128 + pf * 16 + l15] = q;
        }
    }
    __syncthreads();
    if (tid < 256) {
        const float S = lsum[0][tid] + lsum[1][tid] + lsum[2][tid] + lsum[3][tid];
        const float Q = lsq[0][tid] + lsq[1][tid] + lsq[2][tid] + lsq[3][tid];
        ps2[(size_t)tid * 256 + blockIdx.x] = S;
        pq2[(size_t)tid * 256 + blockIdx.x] = Q;
    }
}

// ---------------------------------------------------------------------------
// BN2 final
// ---------------------------------------------------------------------------
__global__ __launch_bounds__(256) void bn2_final(const float* __restrict__ ps,
                                                 const float* __restrict__ pq,
                                                 const float* __restrict__ gamma,
                                                 const float* __restrict__ beta,
                                                 float* __restrict__ sc,
                                                 float* __restrict__ sh) {
    const int p = blockIdx.x;
    const int t = threadIdx.x;
    float S = ps[(size_t)p * 256 + t];
    float Q = pq[(size_t)p * 256 + t];
    __shared__ float rs[256], rq[256];
    rs[t] = S; rq[t] = Q;
    __syncthreads();
    for (int st = 128; st > 0; st >>= 1) {
        if (t < st) { rs[t] += rs[t + st]; rq[t] += rq[t + st]; }
        __syncthreads();
    }
    if (t == 0) {
        const float mean = rs[0] * (1.0f / NCOL);
        const float var  = fmaxf(rq[0] * (1.0f / NCOL) - mean * mean, 0.f);
        const float is   = rsqrtf(var + 1e-5f);
        const float s    = gamma[p] * is;
        sc[p] = s;
        sh[p] = beta[p] - mean * s;
    }
}

// ---------------------------------------------------------------------------
// In-place BN2 affine + leaky on d_out
// ---------------------------------------------------------------------------
__global__ __launch_bounds__(256) void bn_apply2(float* __restrict__ out,
                                                 const float* __restrict__ sc,
                                                 const float* __restrict__ sh) {
    const size_t i = (size_t)blockIdx.x * 256 + threadIdx.x;
    const int p = (int)((i >> 13) & (H2C - 1));
    float v = out[i];
    v = fmaf(v, sc[p], sh[p]);
    out[i] = v >= 0.f ? v : 0.2f * v;
}

// ---------------------------------------------------------------------------
extern "C" void kernel_launch(void* const* d_in, const int* in_sizes, int n_in,
                              void* d_out, int out_size, void* d_ws, size_t ws_size,
                              hipStream_t stream) {
    const float* pos      = (const float*)d_in[0];
    const float* pos_skip = (const float*)d_in[1];
    const float* x        = (const float*)d_in[2];
    const float* x_skip   = (const float*)d_in[3];
    const float* W1       = (const float*)d_in[4];
    const float* gamma1   = (const float*)d_in[5];
    const float* beta1    = (const float*)d_in[6];
    const float* W2       = (const float*)d_in[7];
    const float* gamma2   = (const float*)d_in[8];
    const float* beta2    = (const float*)d_in[9];
    float* out = (float*)d_out;

    char* ws = (char*)d_ws;
    size_t off = 0;
    auto alloc = [&](size_t bytes) {
        void* p = ws + off;
        off = (off + bytes + 255) & ~(size_t)255;
        return p;
    };
    int*   idx   = (int*)  alloc((size_t)NCOL * 3 * sizeof(int));
    float* w     = (float*)alloc((size_t)NCOL * 3 * sizeof(float));
    u16*   xT    = (u16*)  alloc((size_t)B_ * N_ * C_ * sizeof(u16));
    u16*   W1b   = (u16*)  alloc((size_t)H1C * CIN * sizeof(u16));
    u16*   W2b   = (u16*)  alloc((size_t)H2C * H1C * sizeof(u16));
    u16*   Feats = (u16*)  alloc((size_t)NCOL * CIN * sizeof(u16));
    u16*   H1    = (u16*)  alloc((size_t)NCOL * H1C * sizeof(u16));
    float* ps1   = (float*)alloc((size_t)H1C * 512 * sizeof(float));
    float* pq1   = (float*)alloc((size_t)H1C * 512 * sizeof(float));
    float* ps2   = (float*)alloc((size_t)H2C * 256 * sizeof(float));
    float* pq2   = (float*)alloc((size_t)H2C * 256 * sizeof(float));
    float* sc1   = (float*)alloc(H1C * sizeof(float));
    float* sh1   = (float*)alloc(H1C * sizeof(float));
    float* sc2   = (float*)alloc(H2C * sizeof(float));
    float* sh2   = (float*)alloc(H2C * sizeof(float));

    cvt_bf16_k<<<(H1C * CIN / 4 + 255) / 256, 256, 0, stream>>>(W1, W1b, H1C * CIN / 4);
    cvt_bf16_k<<<(H2C * H1C / 4 + 255) / 256, 256, 0, stream>>>(W2, W2b, H2C * H1C / 4);
    knn_kernel<<<dim3(M_ / 32, B_), 256, 0, stream>>>(pos, pos_skip, idx, w);
    transpose_x<<<dim3(N_ / 32, C_ / 32, B_), 256, 0, stream>>>(x, xT);
    feats_interp<<<dim3(M_ / 64, B_), 256, 0, stream>>>(xT, idx, w, Feats);
    feats_skip<<<dim3(M_ / 32, CSK / 32, B_), 256, 0, stream>>>(x_skip, Feats);
    gemm1<<<2048, 256, 0, stream>>>(W1b, Feats, H1, ps1, pq1);
    bn1_final<<<H1C, 256, 0, stream>>>(ps1, pq1, gamma1, beta1, sc1, sh1);
    gemm2<<<NCOL / 256, 512, 0, stream>>>(W2b, H1, sc1, sh1, out, ps2, pq2);
    bn2_final<<<H2C, 256, 0, stream>>>(ps2, pq2, gamma2, beta2, sc2, sh2);
    bn_apply2<<<(int)(((size_t)NCOL * H2C) / 256), 256, 0, stream>>>(out, sc2, sh2);
}

// Round 13
// 293.270 us; speedup vs baseline: 4.1200x; 1.0216x over previous
//
#include <hip/hip_runtime.h>
#include <stdint.h>

// Problem constants
#define B_    8
#define N_    2048
#define M_    8192
#define C_    512
#define CSK   256
#define CIN   768
#define H1C   512
#define H2C   256
#define NCOL  65536     // B_*M_
typedef unsigned short u16;
typedef __attribute__((ext_vector_type(8))) short  s16x8;
typedef __attribute__((ext_vector_type(4))) float  f32x4;

// ---- bf16 helpers (RNE) ----
__device__ inline u16 f2bf(float f) {
    unsigned u = __float_as_uint(f);
    unsigned r = (u + 0x7fffu + ((u >> 16) & 1u)) >> 16;
    return (u16)r;
}
__device__ inline float bflo(unsigned u) { return __uint_as_float(u << 16); }
__device__ inline float bfhi(unsigned u) { return __uint_as_float(u & 0xffff0000u); }

// ---------------------------------------------------------------------------
// f32 -> bf16 bulk convert
// ---------------------------------------------------------------------------
__global__ __launch_bounds__(256) void cvt_bf16_k(const float* __restrict__ in,
                                                  u16* __restrict__ out, int n4) {
    const int i = blockIdx.x * 256 + threadIdx.x;
    if (i >= n4) return;
    const float4 v = *(const float4*)(in + (size_t)i * 4);
    u16 o[4] = {f2bf(v.x), f2bf(v.y), f2bf(v.z), f2bf(v.w)};
    *(uint2*)(out + (size_t)i * 4) = *(uint2*)o;
}

// ---------------------------------------------------------------------------
// 3-NN (round-12 validated: exact ordering, surrogate s = r^2 - 2 q.r)
// ---------------------------------------------------------------------------
__device__ inline void ins3(float d, int n,
                            float& d0, int& i0, float& d1, int& i1,
                            float& d2, int& i2) {
    const bool lt0 = d < d0, lt1 = d < d1, lt2 = d < d2;
    const float nd2 = lt1 ? d1 : (lt2 ? d : d2);
    const int   ni2 = lt1 ? i1 : (lt2 ? n : i2);
    const float nd1 = lt0 ? d0 : (lt1 ? d : d1);
    const int   ni1 = lt0 ? i0 : (lt1 ? n : i1);
    const float nd0 = lt0 ? d : d0;
    const int   ni0 = lt0 ? n : i0;
    d0 = nd0; d1 = nd1; d2 = nd2; i0 = ni0; i1 = ni1; i2 = ni2;
}

__global__ __launch_bounds__(256) void knn_kernel(const float* __restrict__ pos,
                                                  const float* __restrict__ pos_skip,
                                                  int* __restrict__ idx_out,
                                                  float* __restrict__ w_out) {
    __shared__ float rpx[N_], rpy[N_], rpz[N_], rr2[N_];
    const int b = blockIdx.y;
    const int tid = threadIdx.x;
    for (int t = tid; t < N_ * 3; t += 256) {
        const float v = pos[(size_t)b * N_ * 3 + t];
        const int n = t / 3, k = t - n * 3;
        if (k == 0) rpx[n] = v; else if (k == 1) rpy[n] = v; else rpz[n] = v;
    }
    __syncthreads();
    for (int n = tid; n < N_; n += 256)
        rr2[n] = rpx[n] * rpx[n] + rpy[n] * rpy[n] + rpz[n] * rpz[n];
    __syncthreads();

    const int q = tid >> 3;
    const int part = tid & 7;
    const int m = blockIdx.x * 32 + q;
    const size_t qoff = ((size_t)b * M_ + m) * 3;
    const float qx = pos_skip[qoff], qy = pos_skip[qoff + 1], qz = pos_skip[qoff + 2];
    const float q2x = -2.0f * qx, q2y = -2.0f * qy, q2z = -2.0f * qz;
    const float qq = qx * qx + qy * qy + qz * qz;

    float d0 = 1e30f, d1 = 1e30f, d2 = 1e30f;
    int i0 = 0, i1 = 0, i2 = 0;
#pragma unroll 4
    for (int i = 0; i < 64; ++i) {
        const int n = part * 4 + i * 32;
        const float4 xx = *(const float4*)&rpx[n];
        const float4 yy = *(const float4*)&rpy[n];
        const float4 zz = *(const float4*)&rpz[n];
        const float4 ww = *(const float4*)&rr2[n];
        const float s0 = fmaf(xx.x, q2x, fmaf(yy.x, q2y, fmaf(zz.x, q2z, ww.x)));
        const float s1 = fmaf(xx.y, q2x, fmaf(yy.y, q2y, fmaf(zz.y, q2z, ww.y)));
        const float s2 = fmaf(xx.z, q2x, fmaf(yy.z, q2y, fmaf(zz.z, q2z, ww.z)));
        const float s3 = fmaf(xx.w, q2x, fmaf(yy.w, q2y, fmaf(zz.w, q2z, ww.w)));
        ins3(s0, n + 0, d0, i0, d1, i1, d2, i2);
        ins3(s1, n + 1, d0, i0, d1, i1, d2, i2);
        ins3(s2, n + 2, d0, i0, d1, i1, d2, i2);
        ins3(s3, n + 3, d0, i0, d1, i1, d2, i2);
    }

#pragma unroll
    for (int xm = 1; xm <= 4; xm <<= 1) {
        const float od0 = __shfl_xor(d0, xm), od1 = __shfl_xor(d1, xm), od2 = __shfl_xor(d2, xm);
        const int   oi0 = __shfl_xor(i0, xm), oi1 = __shfl_xor(i1, xm), oi2 = __shfl_xor(i2, xm);
        ins3(od0, oi0, d0, i0, d1, i1, d2, i2);
        ins3(od1, oi1, d0, i0, d1, i1, d2, i2);
        ins3(od2, oi2, d0, i0, d1, i1, d2, i2);
    }

    if (part == 0) {
        const float dd0 = fmaxf(d0 + qq, 0.f);
        const float dd1 = fmaxf(d1 + qq, 0.f);
        const float dd2 = fmaxf(d2 + qq, 0.f);
        const float r0 = 1.0f / (sqrtf(dd0) + 1e-8f);
        const float r1 = 1.0f / (sqrtf(dd1) + 1e-8f);
        const float r2 = 1.0f / (sqrtf(dd2) + 1e-8f);
        const float inv = 1.0f / (r0 + r1 + r2);
        const size_t o = ((size_t)b * M_ + m) * 3;
        idx_out[o] = i0; idx_out[o + 1] = i1; idx_out[o + 2] = i2;
        w_out[o] = r0 * inv; w_out[o + 1] = r1 * inv; w_out[o + 2] = r2 * inv;
    }
}

// ---------------------------------------------------------------------------
// x [b][c][n] f32 -> xT [b][n][c] bf16
// ---------------------------------------------------------------------------
__global__ __launch_bounds__(256) void transpose_x(const float* __restrict__ x,
                                                   u16* __restrict__ xT) {
    __shared__ float t[32][33];
    const int tx = threadIdx.x & 31, ty = threadIdx.x >> 5;
    const int n0 = blockIdx.x * 32, c0 = blockIdx.y * 32, b = blockIdx.z;
#pragma unroll
    for (int r = 0; r < 4; ++r) {
        const int c = c0 + ty + r * 8;
        t[ty + r * 8][tx] = x[((size_t)b * C_ + c) * N_ + n0 + tx];
    }
    __syncthreads();
#pragma unroll
    for (int r = 0; r < 4; ++r) {
        const int n = n0 + ty + r * 8;
        xT[((size_t)b * N_ + n) * C_ + c0 + tx] = f2bf(t[tx][ty + r * 8]);
    }
}

// ---------------------------------------------------------------------------
// x_skip [b][c][m] f32 -> FskipT [b*M+m][256] bf16 (compact)
// ---------------------------------------------------------------------------
__global__ __launch_bounds__(256) void feats_skip(const float* __restrict__ xs,
                                                  u16* __restrict__ Fsk) {
    __shared__ float t[32][33];
    const int tx = threadIdx.x & 31, ty = threadIdx.x >> 5;
    const int m0 = blockIdx.x * 32, c0 = blockIdx.y * 32, b = blockIdx.z;
#pragma unroll
    for (int r = 0; r < 4; ++r) {
        const int c = c0 + ty + r * 8;
        t[ty + r * 8][tx] = xs[((size_t)b * CSK + c) * M_ + m0 + tx];
    }
    __syncthreads();
#pragma unroll
    for (int r = 0; r < 4; ++r) {
        const int m = m0 + ty + r * 8;
        Fsk[((size_t)b * M_ + m) * CSK + c0 + tx] = f2bf(t[tx][ty + r * 8]);
    }
}

// ---------------------------------------------------------------------------
// interp helper: one packed u32 (2 bf16) from three sources
// ---------------------------------------------------------------------------
__device__ inline unsigned interp_pk(unsigned a, unsigned b, unsigned c,
                                     float w0, float w1, float w2) {
    const float lo = w0 * bflo(a) + w1 * bflo(b) + w2 * bflo(c);
    const float hi = w0 * bfhi(a) + w1 * bfhi(b) + w2 * bfhi(c);
    return (unsigned)f2bf(lo) | ((unsigned)f2bf(hi) << 16);
}

// ---------------------------------------------------------------------------
// GEMM1 with FUSED 3-NN interpolation in B-staging.
// A (W1b) via global_load_lds (pre-swizzled source, linear LDS).
// B built in-register: k<512 -> interp of 3 xT rows; k>=512 -> FskipT copy;
// ds_write to swizzled offset (write-side swizzle == read-side XOR).
// BK=64, XCD-chunked grid, fused BN1 partials (round-12 validated frame).
// ---------------------------------------------------------------------------
__device__ inline void stage64(u16* lds, const char* gbase, int ld2,
                               int lane, int wv) {
    const int slot = (lane & 7) ^ (lane >> 3);     // pre-swizzled source slot
#pragma unroll
    for (int jj = 0; jj < 4; ++jj) {
        const int chunk = jj * 4 + wv;             // 0..15 (1KB = 8 rows each)
        const int row = chunk * 8 + (lane >> 3);
        const char* g = gbase + (size_t)row * ld2 + slot * 16;
        __builtin_amdgcn_global_load_lds(
            (const __attribute__((address_space(1))) void*)g,
            (__attribute__((address_space(3))) void*)((char*)lds + chunk * 1024),
            16, 0, 0);
    }
}

__global__ __launch_bounds__(256) void gemm1(const u16* __restrict__ W1b,
                                             const u16* __restrict__ xT,
                                             const u16* __restrict__ Fsk,
                                             const int* __restrict__ idx,
                                             const float* __restrict__ w,
                                             u16* __restrict__ H1,
                                             float* __restrict__ ps1,
                                             float* __restrict__ pq1) {
    __shared__ __attribute__((aligned(16))) u16 As[128 * 64];
    __shared__ __attribute__((aligned(16))) u16 Bs[128 * 64];
    __shared__ float lsum[2][128], lsq[2][128];
    __shared__ int   sIdx[128][3];
    __shared__ float sW[128][3];
    const int tid = threadIdx.x;
    const int lane = tid & 63, wv = tid >> 6;
    const int wr = wv >> 1, wc = wv & 1;
    const int l15 = lane & 15, l4 = lane >> 4;
    // XCD-chunked remap: 2048 blocks -> each XCD a contiguous virtual range
    const int v = (blockIdx.x & 7) * 256 + (blockIdx.x >> 3);
    const int rowblk = v & 3, colblk = v >> 2;
    const int rowM0 = rowblk * 128, colN0 = colblk * 128;
    const int b = colN0 >> 13;                 // batch of this col-block
    f32x4 acc[4][4] = {};
    const char* Ab = (const char*)(W1b + (size_t)rowM0 * CIN);
    const u16* xTb = xT + (size_t)b * N_ * C_;

    // preload idx/w for the block's 128 cols
    for (int t = tid; t < 384; t += 256) {
        const int rr = t / 3, kk = t - rr * 3;
        const size_t gi = ((size_t)colN0 + rr) * 3 + kk;
        sIdx[rr][kk] = idx[gi];
        sW[rr][kk]   = w[gi];
    }
    __syncthreads();

    const int prow = tid >> 3;                 // 0..31 (row group)
    const int slot = tid & 7;                  // 16B slot within 64-k row
    const int kk_off = slot * 8;

    for (int kt = 0; kt < CIN / 64; ++kt) {
        // A: async DMA stage
        stage64(As, Ab + kt * 128, CIN * 2, lane, wv);
        // B: reg-stage 4 pieces (rows prow, prow+32, prow+64, prow+96)
        uint4 bp[4];
        if (kt < 8) {
            const int kk = kt * 64 + kk_off;
#pragma unroll
            for (int p = 0; p < 4; ++p) {
                const int row = p * 32 + prow;
                const uint4 a = *(const uint4*)(xTb + (size_t)sIdx[row][0] * C_ + kk);
                const uint4 c = *(const uint4*)(xTb + (size_t)sIdx[row][1] * C_ + kk);
                const uint4 d = *(const uint4*)(xTb + (size_t)sIdx[row][2] * C_ + kk);
                const float w0 = sW[row][0], w1 = sW[row][1], w2 = sW[row][2];
                bp[p].x = interp_pk(a.x, c.x, d.x, w0, w1, w2);
                bp[p].y = interp_pk(a.y, c.y, d.y, w0, w1, w2);
                bp[p].z = interp_pk(a.z, c.z, d.z, w0, w1, w2);
                bp[p].w = interp_pk(a.w, c.w, d.w, w0, w1, w2);
            }
        } else {
            const int kk = (kt - 8) * 64 + kk_off;
#pragma unroll
            for (int p = 0; p < 4; ++p) {
                const int row = p * 32 + prow;
                bp[p] = *(const uint4*)(Fsk + (size_t)(colN0 + row) * CSK + kk);
            }
        }
        // ds_write to swizzled slots (read side uses the same XOR)
#pragma unroll
        for (int p = 0; p < 4; ++p) {
            const int row = p * 32 + prow;
            const int s = slot ^ (row & 7);
            *(uint4*)((char*)Bs + row * 128 + s * 16) = bp[p];
        }
        __syncthreads();
#pragma unroll
        for (int ks = 0; ks < 2; ++ks) {
            s16x8 af[4], bfr[4];
#pragma unroll
            for (int i = 0; i < 4; ++i) {
                const int R = wr * 64 + i * 16 + l15;
                const int s = ((ks << 2) | l4) ^ (R & 7);
                af[i] = *(const s16x8*)((const char*)As + R * 128 + s * 16);
            }
#pragma unroll
            for (int j = 0; j < 4; ++j) {
                const int R = wc * 64 + j * 16 + l15;
                const int s = ((ks << 2) | l4) ^ (R & 7);
                bfr[j] = *(const s16x8*)((const char*)Bs + R * 128 + s * 16);
            }
#pragma unroll
            for (int i = 0; i < 4; ++i)
#pragma unroll
                for (int j = 0; j < 4; ++j)
                    acc[i][j] = __builtin_amdgcn_mfma_f32_16x16x32_bf16(bfr[j], af[i], acc[i][j], 0, 0, 0);
        }
        __syncthreads();
    }

    // store H1^T (bf16)
#pragma unroll
    for (int i = 0; i < 4; ++i) {
        const int o = rowM0 + wr * 64 + i * 16 + l15;
#pragma unroll
        for (int j = 0; j < 4; ++j) {
            const int colb = colN0 + wc * 64 + j * 16 + l4 * 4;
#pragma unroll
            for (int r = 0; r < 4; ++r)
                H1[(size_t)(colb + r) * H1C + o] = f2bf(acc[i][j][r]);
        }
    }

    // BN1 partials (f32, deterministic)
#pragma unroll
    for (int i = 0; i < 4; ++i) {
        float s = 0.f, q = 0.f;
#pragma unroll
        for (int j = 0; j < 4; ++j)
#pragma unroll
            for (int r = 0; r < 4; ++r) {
                const float vv = acc[i][j][r];
                s += vv; q += vv * vv;
            }
        s += __shfl_xor(s, 16); q += __shfl_xor(q, 16);
        s += __shfl_xor(s, 32); q += __shfl_xor(q, 32);
        if ((lane & 48) == 0) {
            lsum[wc][wr * 64 + i * 16 + l15] = s;
            lsq [wc][wr * 64 + i * 16 + l15] = q;
        }
    }
    __syncthreads();
    if (tid < 128) {
        const float S = lsum[0][tid] + lsum[1][tid];
        const float Q = lsq[0][tid] + lsq[1][tid];
        ps1[(size_t)(rowM0 + tid) * 512 + colblk] = S;
        pq1[(size_t)(rowM0 + tid) * 512 + colblk] = Q;
    }
}

// ---------------------------------------------------------------------------
// BN1 final
// ---------------------------------------------------------------------------
__global__ __launch_bounds__(256) void bn1_final(const float* __restrict__ ps,
                                                 const float* __restrict__ pq,
                                                 const float* __restrict__ gamma,
                                                 const float* __restrict__ beta,
                                                 float* __restrict__ sc,
                                                 float* __restrict__ sh) {
    const int o = blockIdx.x;
    const int t = threadIdx.x;
    float S = ps[(size_t)o * 512 + t] + ps[(size_t)o * 512 + 256 + t];
    float Q = pq[(size_t)o * 512 + t] + pq[(size_t)o * 512 + 256 + t];
    __shared__ float rs[256], rq[256];
    rs[t] = S; rq[t] = Q;
    __syncthreads();
    for (int st = 128; st > 0; st >>= 1) {
        if (t < st) { rs[t] += rs[t + st]; rq[t] += rq[t + st]; }
        __syncthreads();
    }
    if (t == 0) {
        const float mean = rs[0] * (1.0f / NCOL);
        const float var  = fmaxf(rq[0] * (1.0f / NCOL) - mean * mean, 0.f);
        const float is   = rsqrtf(var + 1e-5f);
        const float s    = gamma[o] * is;
        sc[o] = s;
        sh[o] = beta[o] - mean * s;
    }
}

// ---------------------------------------------------------------------------
// GEMM2 with BN1 affine+leaky fused into reg-staged B (per-channel params
// at k0+kb). Fused BN2 partials. (round-12 validated)
// ---------------------------------------------------------------------------
__device__ inline void stage2A(u16* dst, const u16* W2b, int k0,
                               int lane, int wv) {
#pragma unroll
    for (int h = 0; h < 2; ++h) {
        const int p_loc = h * 128 + wv * 16 + (lane >> 2);
        const u16* g = W2b + (size_t)p_loc * H1C + k0 + (lane & 3) * 8;
        __builtin_amdgcn_global_load_lds(
            (const __attribute__((address_space(1))) void*)g,
            (__attribute__((address_space(3))) void*)((char*)dst + (h * 512 + wv * 64) * 16),
            16, 0, 0);
    }
}

__global__ __launch_bounds__(512, 2) void gemm2(const u16* __restrict__ W2b,
                                                const u16* __restrict__ H1,
                                                const float* __restrict__ sc1,
                                                const float* __restrict__ sh1,
                                                float* __restrict__ out,
                                                float* __restrict__ ps2,
                                                float* __restrict__ pq2) {
    __shared__ __attribute__((aligned(16))) u16 As[2][256 * 32];
    __shared__ __attribute__((aligned(16))) u16 Bs[2][256 * 32];
    __shared__ float lsum[4][256], lsq[4][256];
    __shared__ float scs[512], shs[512];
    const int tid = threadIdx.x;
    const int lane = tid & 63, wv = tid >> 6;
    const int pgrp = wv & 1, cgrp = wv >> 1;
    const int l15 = lane & 15, l4 = lane >> 4;
    const int col0 = blockIdx.x * 256;
    const u16* Hb = H1 + (size_t)col0 * H1C;
    const int kb = (lane & 3) * 8;
    const int prow0 = wv * 16 + (lane >> 2);
    f32x4 acc[4][8] = {};

    scs[tid] = sc1[tid];
    shs[tid] = sh1[tid];

    stage2A(As[0], W2b, 0, lane, wv);
    uint4 nb0 = *(const uint4*)(Hb + (size_t)prow0 * H1C + kb);
    uint4 nb1 = *(const uint4*)(Hb + (size_t)(prow0 + 128) * H1C + kb);
    __syncthreads();   // scs/shs visible

    auto xformB = [&](int buf, uint4 b0, uint4 b1, int k0) {
        const f32x4 s0v = *(const f32x4*)&scs[k0 + kb];
        const f32x4 s1v = *(const f32x4*)&scs[k0 + kb + 4];
        const f32x4 h0v = *(const f32x4*)&shs[k0 + kb];
        const f32x4 h1v = *(const f32x4*)&shs[k0 + kb + 4];
        const float sv[8] = {s0v[0], s0v[1], s0v[2], s0v[3], s1v[0], s1v[1], s1v[2], s1v[3]};
        const float hv[8] = {h0v[0], h0v[1], h0v[2], h0v[3], h1v[0], h1v[1], h1v[2], h1v[3]};
        uint4 bw[2] = {b0, b1};
#pragma unroll
        for (int h = 0; h < 2; ++h) {
            unsigned uu[4] = {bw[h].x, bw[h].y, bw[h].z, bw[h].w};
            unsigned rr[4];
#pragma unroll
            for (int e = 0; e < 4; ++e) {
                float f0 = fmaf(bflo(uu[e]), sv[e * 2], hv[e * 2]);
                float f1 = fmaf(bfhi(uu[e]), sv[e * 2 + 1], hv[e * 2 + 1]);
                f0 = f0 >= 0.f ? f0 : 0.2f * f0;
                f1 = f1 >= 0.f ? f1 : 0.2f * f1;
                rr[e] = (unsigned)f2bf(f0) | ((unsigned)f2bf(f1) << 16);
            }
            *(uint4*)&Bs[buf][(size_t)(h * 512 + wv * 64 + lane) * 8] = make_uint4(rr[0], rr[1], rr[2], rr[3]);
        }
    };

    xformB(0, nb0, nb1, 0);
    __syncthreads();

    int cur = 0;
    for (int step = 0; step < 16; ++step) {
        if (step < 15) {
            const int k0 = (step + 1) * 32;
            stage2A(As[cur ^ 1], W2b, k0, lane, wv);
            nb0 = *(const uint4*)(Hb + (size_t)prow0 * H1C + k0 + kb);
            nb1 = *(const uint4*)(Hb + (size_t)(prow0 + 128) * H1C + k0 + kb);
        }
        const u16* Ac = As[cur];
        const u16* Bc = Bs[cur];
        s16x8 af[8], bfr[4];
#pragma unroll
        for (int pf = 0; pf < 8; ++pf)
            af[pf] = *(const s16x8*)&Ac[(pgrp * 128 + pf * 16 + l15) * 32 + l4 * 8];
#pragma unroll
        for (int cf = 0; cf < 4; ++cf)
            bfr[cf] = *(const s16x8*)&Bc[(cgrp * 64 + cf * 16 + l15) * 32 + l4 * 8];
#pragma unroll
        for (int cf = 0; cf < 4; ++cf)
#pragma unroll
            for (int pf = 0; pf < 8; ++pf)
                acc[cf][pf] = __builtin_amdgcn_mfma_f32_16x16x32_bf16(bfr[cf], af[pf], acc[cf][pf], 0, 0, 0);
        if (step < 15) {
            xformB(cur ^ 1, nb0, nb1, (step + 1) * 32);
        }
        __syncthreads();
        cur ^= 1;
    }

    const int bidx = col0 >> 13;
    const int mb   = col0 & (M_ - 1);
#pragma unroll
    for (int cf = 0; cf < 4; ++cf) {
#pragma unroll
        for (int pf = 0; pf < 8; ++pf) {
            const int p  = pgrp * 128 + pf * 16 + l15;
            const int mm = mb + cgrp * 64 + cf * 16 + l4 * 4;
            *(f32x4*)(out + (size_t)bidx * (H2C * M_) + (size_t)p * M_ + mm) = acc[cf][pf];
        }
    }

#pragma unroll
    for (int pf = 0; pf < 8; ++pf) {
        float s = 0.f, q = 0.f;
#pragma unroll
        for (int cf = 0; cf < 4; ++cf)
#pragma unroll
            for (int r = 0; r < 4; ++r) {
                const float vv = acc[cf][pf][r];
                s += vv; q += vv * vv;
            }
        s += __shfl_xor(s, 16); q += __shfl_xor(q, 16);
        s += __shfl_xor(s, 32); q += __shfl_xor(q, 32);
        if ((lane & 48) == 0) {
            lsum[cgrp][pgrp * 128 + pf * 16 + l15] = s;
            lsq [cgrp][pgrp * 128 + pf * 16 + l15] = q;
        }
    }
    __syncthreads();
    if (tid < 256) {
        const float S = lsum[0][tid] + lsum[1][tid] + lsum[2][tid] + lsum[3][tid];
        const float Q = lsq[0][tid] + lsq[1][tid] + lsq[2][tid] + lsq[3][tid];
        ps2[(size_t)tid * 256 + blockIdx.x] = S;
        pq2[(size_t)tid * 256 + blockIdx.x] = Q;
    }
}

// ---------------------------------------------------------------------------
// BN2 final
// ---------------------------------------------------------------------------
__global__ __launch_bounds__(256) void bn2_final(const float* __restrict__ ps,
                                                 const float* __restrict__ pq,
                                                 const float* __restrict__ gamma,
                                                 const float* __restrict__ beta,
                                                 float* __restrict__ sc,
                                                 float* __restrict__ sh) {
    const int p = blockIdx.x;
    const int t = threadIdx.x;
    float S = ps[(size_t)p * 256 + t];
    float Q = pq[(size_t)p * 256 + t];
    __shared__ float rs[256], rq[256];
    rs[t] = S; rq[t] = Q;
    __syncthreads();
    for (int st = 128; st > 0; st >>= 1) {
        if (t < st) { rs[t] += rs[t + st]; rq[t] += rq[t + st]; }
        __syncthreads();
    }
    if (t == 0) {
        const float mean = rs[0] * (1.0f / NCOL);
        const float var  = fmaxf(rq[0] * (1.0f / NCOL) - mean * mean, 0.f);
        const float is   = rsqrtf(var + 1e-5f);
        const float s    = gamma[p] * is;
        sc[p] = s;
        sh[p] = beta[p] - mean * s;
    }
}

// ---------------------------------------------------------------------------
// In-place BN2 affine + leaky on d_out
// ---------------------------------------------------------------------------
__global__ __launch_bounds__(256) void bn_apply2(float* __restrict__ out,
                                                 const float* __restrict__ sc,
                                                 const float* __restrict__ sh) {
    const size_t i = (size_t)blockIdx.x * 256 + threadIdx.x;
    const int p = (int)((i >> 13) & (H2C - 1));
    float v = out[i];
    v = fmaf(v, sc[p], sh[p]);
    out[i] = v >= 0.f ? v : 0.2f * v;
}

// ---------------------------------------------------------------------------
extern "C" void kernel_launch(void* const* d_in, const int* in_sizes, int n_in,
                              void* d_out, int out_size, void* d_ws, size_t ws_size,
                              hipStream_t stream) {
    const float* pos      = (const float*)d_in[0];
    const float* pos_skip = (const float*)d_in[1];
    const float* x        = (const float*)d_in[2];
    const float* x_skip   = (const float*)d_in[3];
    const float* W1       = (const float*)d_in[4];
    const float* gamma1   = (const float*)d_in[5];
    const float* beta1    = (const float*)d_in[6];
    const float* W2       = (const float*)d_in[7];
    const float* gamma2   = (const float*)d_in[8];
    const float* beta2    = (const float*)d_in[9];
    float* out = (float*)d_out;

    char* ws = (char*)d_ws;
    size_t off = 0;
    auto alloc = [&](size_t bytes) {
        void* p = ws + off;
        off = (off + bytes + 255) & ~(size_t)255;
        return p;
    };
    int*   idx   = (int*)  alloc((size_t)NCOL * 3 * sizeof(int));
    float* w     = (float*)alloc((size_t)NCOL * 3 * sizeof(float));
    u16*   xT    = (u16*)  alloc((size_t)B_ * N_ * C_ * sizeof(u16));     // 16.8 MB
    u16*   W1b   = (u16*)  alloc((size_t)H1C * CIN * sizeof(u16));
    u16*   W2b   = (u16*)  alloc((size_t)H2C * H1C * sizeof(u16));
    u16*   Fsk   = (u16*)  alloc((size_t)NCOL * CSK * sizeof(u16));       // 33.5 MB
    u16*   H1    = (u16*)  alloc((size_t)NCOL * H1C * sizeof(u16));       // 67.1 MB
    float* ps1   = (float*)alloc((size_t)H1C * 512 * sizeof(float));
    float* pq1   = (float*)alloc((size_t)H1C * 512 * sizeof(float));
    float* ps2   = (float*)alloc((size_t)H2C * 256 * sizeof(float));
    float* pq2   = (float*)alloc((size_t)H2C * 256 * sizeof(float));
    float* sc1   = (float*)alloc(H1C * sizeof(float));
    float* sh1   = (float*)alloc(H1C * sizeof(float));
    float* sc2   = (float*)alloc(H2C * sizeof(float));
    float* sh2   = (float*)alloc(H2C * sizeof(float));

    cvt_bf16_k<<<(H1C * CIN / 4 + 255) / 256, 256, 0, stream>>>(W1, W1b, H1C * CIN / 4);
    cvt_bf16_k<<<(H2C * H1C / 4 + 255) / 256, 256, 0, stream>>>(W2, W2b, H2C * H1C / 4);
    knn_kernel<<<dim3(M_ / 32, B_), 256, 0, stream>>>(pos, pos_skip, idx, w);
    transpose_x<<<dim3(N_ / 32, C_ / 32, B_), 256, 0, stream>>>(x, xT);
    feats_skip<<<dim3(M_ / 32, CSK / 32, B_), 256, 0, stream>>>(x_skip, Fsk);
    gemm1<<<2048, 256, 0, stream>>>(W1b, xT, Fsk, idx, w, H1, ps1, pq1);
    bn1_final<<<H1C, 256, 0, stream>>>(ps1, pq1, gamma1, beta1, sc1, sh1);
    gemm2<<<NCOL / 256, 512, 0, stream>>>(W2b, H1, sc1, sh1, out, ps2, pq2);
    bn2_final<<<H2C, 256, 0, stream>>>(ps2, pq2, gamma2, beta2, sc2, sh2);
    bn_apply2<<<(int)(((size_t)NCOL * H2C) / 256), 256, 0, stream>>>(out, sc2, sh2);
}